// Round 1
// baseline (2717.351 us; speedup 1.0000x reference)
//
#include <hip/hip_runtime.h>
#include <cfloat>

// Problem constants (match reference setup_inputs)
#define Nn 50000
#define Ee 800000
#define Etot (Ee + Nn)   // edges + self loops = 850000
#define Gg 64
#define HIDc 256
#define BN_EPS 1e-5f

// ---------------------------------------------------------------------------
// small helpers
// ---------------------------------------------------------------------------
__device__ inline void atomicMaxFloat(float* addr, float val) {
    int old = __float_as_int(*addr);
    while (__int_as_float(old) < val) {
        int assumed = old;
        old = atomicCAS((int*)addr, assumed, __float_as_int(val));
        if (old == assumed) break;
    }
}

// ---------------------------------------------------------------------------
// edge_attr mean (sum, divided later)
// ---------------------------------------------------------------------------
__global__ void ea_sum_kernel(const float* __restrict__ ea, float* __restrict__ out) {
    __shared__ float sh0[256], sh1[256];
    float s0 = 0.f, s1 = 0.f;
    for (int e = blockIdx.x * blockDim.x + threadIdx.x; e < Ee; e += gridDim.x * blockDim.x) {
        s0 += ea[2 * e];
        s1 += ea[2 * e + 1];
    }
    sh0[threadIdx.x] = s0; sh1[threadIdx.x] = s1;
    __syncthreads();
    for (int off = 128; off > 0; off >>= 1) {
        if ((int)threadIdx.x < off) {
            sh0[threadIdx.x] += sh0[threadIdx.x + off];
            sh1[threadIdx.x] += sh1[threadIdx.x + off];
        }
        __syncthreads();
    }
    if (threadIdx.x == 0) { atomicAdd(&out[0], sh0[0]); atomicAdd(&out[1], sh1[0]); }
}

// ---------------------------------------------------------------------------
// M[l][d][h] = sum_c We_l[d, h*C+c] * ae_l[h, c]   (layout M[l*8 + d*H + h])
// ---------------------------------------------------------------------------
__global__ void m_kernel(const float* __restrict__ We0, const float* __restrict__ ae0,
                         const float* __restrict__ We1, const float* __restrict__ ae1,
                         const float* __restrict__ We2, const float* __restrict__ ae2,
                         float* __restrict__ M) {
    int t = threadIdx.x;
    if (t >= 18) return;
    int l = t < 8 ? 0 : (t < 16 ? 1 : 2);
    int r = t - l * 8;
    const float* We = (l == 0) ? We0 : (l == 1 ? We1 : We2);
    const float* ae = (l == 0) ? ae0 : (l == 1 ? ae1 : ae2);
    int Hl = (l < 2) ? 4 : 1;
    int Cl = 256 / Hl;
    int d = r / Hl, hh = r % Hl;
    float s = 0.f;
    for (int c = 0; c < Cl; ++c)
        s += We[d * 256 + hh * Cl + c] * ae[hh * Cl + c];
    M[l * 8 + r] = s;
}

// ---------------------------------------------------------------------------
// CSR build: histogram -> scan -> scatter
// ---------------------------------------------------------------------------
__global__ void hist_kernel(const int* __restrict__ ei, int* __restrict__ counts) {
    int e = blockIdx.x * blockDim.x + threadIdx.x;
    if (e >= Etot) return;
    int d = (e < Ee) ? ei[Ee + e] : (e - Ee);
    atomicAdd(&counts[d], 1);
}

__global__ void scan1_kernel(const int* __restrict__ in, int* __restrict__ inc,
                             int* __restrict__ bsums) {
    __shared__ int sh[256];
    int i = blockIdx.x * 256 + threadIdx.x;
    int v = (i < Nn) ? in[i] : 0;
    sh[threadIdx.x] = v;
    __syncthreads();
    for (int off = 1; off < 256; off <<= 1) {
        int t = ((int)threadIdx.x >= off) ? sh[threadIdx.x - off] : 0;
        __syncthreads();
        sh[threadIdx.x] += t;
        __syncthreads();
    }
    if (i < Nn) inc[i] = sh[threadIdx.x];
    if (threadIdx.x == 255) bsums[blockIdx.x] = sh[255];
}

__global__ void scan2_kernel(int* __restrict__ bsums, int nb) {
    if (blockIdx.x == 0 && threadIdx.x == 0) {
        int acc = 0;
        for (int i = 0; i < nb; ++i) { int v = bsums[i]; bsums[i] = acc; acc += v; }
    }
}

__global__ void scan3_kernel(const int* __restrict__ inc, const int* __restrict__ bsums,
                             int* __restrict__ row_start, int* __restrict__ cursor) {
    int i = blockIdx.x * 256 + threadIdx.x;
    if (i < Nn) {
        int v = inc[i] + bsums[blockIdx.x];
        row_start[i + 1] = v;
        cursor[i + 1] = v;
    }
    if (i == 0) { row_start[0] = 0; cursor[0] = 0; }
}

__global__ void scatter_kernel(const int* __restrict__ ei, int* __restrict__ cursor,
                               int* __restrict__ edge_list) {
    int e = blockIdx.x * blockDim.x + threadIdx.x;
    if (e >= Etot) return;
    int d = (e < Ee) ? ei[Ee + e] : (e - Ee);
    int pos = atomicAdd(&cursor[d], 1);
    edge_list[pos] = e;
}

// ---------------------------------------------------------------------------
// GEMM: out[n,256] = in[n,K] @ W[K,256] (+bias)    block = 256 thr, 16 rows
// ---------------------------------------------------------------------------
#define GEMM_ROWS 16
__global__ __launch_bounds__(256) void gemm_kernel(
        const float* __restrict__ in, const float* __restrict__ W,
        const float* __restrict__ bias, float* __restrict__ out, int n, int K) {
    __shared__ float tile[GEMM_ROWS][32];
    int col = threadIdx.x;
    int row0 = blockIdx.x * GEMM_ROWS;
    float acc[GEMM_ROWS];
#pragma unroll
    for (int r = 0; r < GEMM_ROWS; ++r) acc[r] = 0.f;
    for (int k0 = 0; k0 < K; k0 += 32) {
        int t = threadIdx.x;
#pragma unroll
        for (int i = 0; i < 2; ++i, t += 256) {
            int r = t >> 5, kk = t & 31;
            int gr = row0 + r;
            tile[r][kk] = (gr < n) ? in[(long)gr * K + k0 + kk] : 0.f;
        }
        __syncthreads();
#pragma unroll 8
        for (int kk = 0; kk < 32; ++kk) {
            float w = W[(long)(k0 + kk) * 256 + col];
#pragma unroll
            for (int r = 0; r < GEMM_ROWS; ++r)
                acc[r] += tile[r][kk] * w;
        }
        __syncthreads();
    }
    float b = bias ? bias[col] : 0.f;
#pragma unroll
    for (int r = 0; r < GEMM_ROWS; ++r) {
        int gr = row0 + r;
        if (gr < n) out[(long)gr * 256 + col] = acc[r] + b;
    }
}

// ---------------------------------------------------------------------------
// per-node attention terms: ssrc[n,h], sdst[n,h]  (one wave per node)
// ---------------------------------------------------------------------------
__global__ void attn_node_kernel(const float* __restrict__ h, const float* __restrict__ a_s,
                                 const float* __restrict__ a_d, float* __restrict__ ssrc,
                                 float* __restrict__ sdst, int H) {
    int wave = (blockIdx.x * blockDim.x + threadIdx.x) >> 6;
    int lane = threadIdx.x & 63;
    if (wave >= Nn) return;
    int C = 256 / H;
    for (int hh = 0; hh < H; ++hh) {
        float ps = 0.f, pd = 0.f;
        for (int c = lane; c < C; c += 64) {
            float v = h[(long)wave * 256 + hh * C + c];
            ps += v * a_s[hh * C + c];
            pd += v * a_d[hh * C + c];
        }
        for (int off = 32; off > 0; off >>= 1) {
            ps += __shfl_down(ps, off);
            pd += __shfl_down(pd, off);
        }
        if (lane == 0) { ssrc[wave * H + hh] = ps; sdst[wave * H + hh] = pd; }
    }
}

// ---------------------------------------------------------------------------
// per-edge attention logits (post-leaky-relu)
// ---------------------------------------------------------------------------
__global__ void logits_kernel(const int* __restrict__ ei, const float* __restrict__ ea,
                              const float* __restrict__ ea_sum,
                              const float* __restrict__ ssrc, const float* __restrict__ sdst,
                              const float* __restrict__ M, float* __restrict__ al, int H) {
    int e = blockIdx.x * blockDim.x + threadIdx.x;
    if (e >= Etot) return;
    int s, d; float e0, e1;
    if (e < Ee) {
        s = ei[e]; d = ei[Ee + e];
        e0 = ea[2 * e]; e1 = ea[2 * e + 1];
    } else {
        s = d = e - Ee;
        const float invE = 1.f / (float)Ee;
        e0 = ea_sum[0] * invE; e1 = ea_sum[1] * invE;
    }
    for (int hh = 0; hh < H; ++hh) {
        float v = ssrc[s * H + hh] + sdst[d * H + hh] + e0 * M[hh] + e1 * M[H + hh];
        al[(long)e * H + hh] = (v > 0.f) ? v : 0.2f * v;
    }
}

// ---------------------------------------------------------------------------
// softmax + aggregation + bconv + BN(eval) + ELU + residual, one block per dst
// ---------------------------------------------------------------------------
__global__ __launch_bounds__(256) void agg_kernel(
        const int* __restrict__ edge_list, const int* __restrict__ row_start,
        const int* __restrict__ ei, const float* __restrict__ hbuf,
        const float* __restrict__ al, const float* __restrict__ bconv,
        const float* __restrict__ bn_g, const float* __restrict__ bn_b,
        const float* __restrict__ bn_m, const float* __restrict__ bn_v,
        const float* __restrict__ identity, float* __restrict__ out, int H) {
    int node = blockIdx.x;
    int c = threadIdx.x;
    int C = 256 / H;
    int hh = c / C;
    int beg = row_start[node], end = row_start[node + 1];
    __shared__ float sm[4], sden[4];
    if (c < H) {
        float m = -FLT_MAX, den = 0.f;
        for (int idx = beg; idx < end; ++idx) {
            int e = edge_list[idx];
            float a = al[(long)e * H + c];
            if (a > m) { den = den * expf(m - a) + 1.f; m = a; }
            else den += expf(a - m);
        }
        sm[c] = m; sden[c] = den + 1e-16f;
    }
    __syncthreads();
    float m = sm[hh], den = sden[hh];
    float acc = 0.f;
    for (int idx = beg; idx < end; ++idx) {
        int e = edge_list[idx];
        int s = (e < Ee) ? ei[e] : (e - Ee);
        float a = al[(long)e * H + hh];
        float w = expf(a - m) / den;
        acc += w * hbuf[(long)s * 256 + c];
    }
    float v = acc + bconv[c];
    v = (v - bn_m[c]) * rsqrtf(bn_v[c] + BN_EPS) * bn_g[c] + bn_b[c];
    v = (v > 0.f) ? v : (expf(v) - 1.f);
    out[(long)node * 256 + c] = v + identity[(long)node * 256 + c];
}

// ---------------------------------------------------------------------------
// pooling
// ---------------------------------------------------------------------------
__global__ void pool_init_kernel(float* __restrict__ pmax) {
    int i = blockIdx.x * blockDim.x + threadIdx.x;
    if (i < Gg * 256) pmax[i] = -FLT_MAX;
}

__global__ __launch_bounds__(256) void pool_kernel(
        const float* __restrict__ x, const int* __restrict__ batch,
        float* __restrict__ psum, float* __restrict__ pmax, float* __restrict__ pcnt) {
    int c = threadIdx.x;
    int n0 = blockIdx.x * 256;
    if (n0 >= Nn) return;
    int n1 = min(n0 + 256, Nn);
    int cur = batch[n0];
    float s = 0.f, mx = -FLT_MAX;
    int cnt = 0;
    for (int i = n0; i < n1; ++i) {
        int g = batch[i];
        if (g != cur) {
            atomicAdd(&psum[cur * 256 + c], s);
            atomicMaxFloat(&pmax[cur * 256 + c], mx);
            if (c == 0) atomicAdd(&pcnt[cur], (float)cnt);
            cur = g; s = 0.f; mx = -FLT_MAX; cnt = 0;
        }
        float v = x[(long)i * 256 + c];
        s += v; mx = fmaxf(mx, v); ++cnt;
    }
    atomicAdd(&psum[cur * 256 + c], s);
    atomicMaxFloat(&pmax[cur * 256 + c], mx);
    if (c == 0) atomicAdd(&pcnt[cur], (float)cnt);
}

// ---------------------------------------------------------------------------
// head MLP: relu(emb @ Wp1 + bp1) @ Wp2 + bp2  -> out[g]
// ---------------------------------------------------------------------------
__global__ __launch_bounds__(256) void mlp_kernel(
        const float* __restrict__ psum, const float* __restrict__ pmax,
        const float* __restrict__ pcnt, const float* __restrict__ Wp1,
        const float* __restrict__ bp1, const float* __restrict__ Wp2,
        const float* __restrict__ bp2, float* __restrict__ out) {
    int g = blockIdx.x;
    int j = threadIdx.x;
    float inv = 1.f / fmaxf(pcnt[g], 1.f);
    float acc = bp1[j];
    for (int k = 0; k < 256; ++k)
        acc += (psum[g * 256 + k] * inv) * Wp1[k * 256 + j];
    for (int k = 0; k < 256; ++k)
        acc += pmax[g * 256 + k] * Wp1[(256 + k) * 256 + j];
    float v = fmaxf(acc, 0.f) * Wp2[j];
    __shared__ float red[256];
    red[j] = v;
    __syncthreads();
    for (int off = 128; off > 0; off >>= 1) {
        if (j < off) red[j] += red[j + off];
        __syncthreads();
    }
    if (j == 0) out[g] = red[0] + bp2[0];
}

// ---------------------------------------------------------------------------
// launch
// ---------------------------------------------------------------------------
extern "C" void kernel_launch(void* const* d_in, const int* in_sizes, int n_in,
                              void* d_out, int out_size, void* d_ws, size_t ws_size,
                              hipStream_t stream) {
    const float* x   = (const float*)d_in[0];
    const int*   ei  = (const int*)d_in[1];
    const float* ea  = (const float*)d_in[2];
    const int*   bat = (const int*)d_in[3];
    auto LP = [&](int l, int j) { return (const float*)d_in[4 + l * 10 + j]; };
    const float* Wskip = (const float*)d_in[34];
    const float* bskip = (const float*)d_in[35];
    const float* Wp1   = (const float*)d_in[36];
    const float* bp1   = (const float*)d_in[37];
    const float* Wp2   = (const float*)d_in[38];
    const float* bp2   = (const float*)d_in[39];
    float* out = (float*)d_out;

    // workspace carve-up (256B aligned)
    char* p = (char*)d_ws;
    auto alloc = [&](size_t bytes) { void* r = (void*)p; p += (bytes + 255) & ~(size_t)255; return r; };
    float* big0   = (float*)alloc((size_t)Nn * 256 * 4);   // xskip, later layer1-out
    float* big1   = (float*)alloc((size_t)Nn * 256 * 4);   // layer0-out / layer2-out (final x)
    float* hbuf   = (float*)alloc((size_t)Nn * 256 * 4);
    float* albuf  = (float*)alloc((size_t)Etot * 4 * 4);
    float* ssrc   = (float*)alloc((size_t)Nn * 4 * 4);
    float* sdst   = (float*)alloc((size_t)Nn * 4 * 4);
    int*   counts = (int*)alloc((size_t)Nn * 4);
    int*   incb   = (int*)alloc((size_t)Nn * 4);
    int*   row_start = (int*)alloc((size_t)(Nn + 1) * 4);
    int*   cursor    = (int*)alloc((size_t)(Nn + 1) * 4);
    int*   edge_list = (int*)alloc((size_t)Etot * 4);
    int*   bsums  = (int*)alloc(256 * 4);
    float* ea_s   = (float*)alloc(2 * 4);
    float* Mbuf   = (float*)alloc(32 * 4);
    float* psum   = (float*)alloc((size_t)Gg * 256 * 4);
    float* pmax   = (float*)alloc((size_t)Gg * 256 * 4);
    float* pcnt   = (float*)alloc((size_t)Gg * 4);

    const int nb = (Nn + 255) / 256;           // 196 scan blocks
    const int ebks = (Etot + 255) / 256;       // edge-parallel blocks

    // zero init
    hipMemsetAsync(counts, 0, (size_t)Nn * 4, stream);
    hipMemsetAsync(ea_s, 0, 8, stream);
    hipMemsetAsync(psum, 0, (size_t)Gg * 256 * 4, stream);
    hipMemsetAsync(pcnt, 0, (size_t)Gg * 4, stream);

    // edge-attr mean + M
    ea_sum_kernel<<<256, 256, 0, stream>>>(ea, ea_s);
    m_kernel<<<1, 64, 0, stream>>>(LP(0,3), LP(0,4), LP(1,3), LP(1,4), LP(2,3), LP(2,4), Mbuf);

    // CSR
    hist_kernel<<<ebks, 256, 0, stream>>>(ei, counts);
    scan1_kernel<<<nb, 256, 0, stream>>>(counts, incb, bsums);
    scan2_kernel<<<1, 64, 0, stream>>>(bsums, nb);
    scan3_kernel<<<nb, 256, 0, stream>>>(incb, bsums, row_start, cursor);
    scatter_kernel<<<ebks, 256, 0, stream>>>(ei, cursor, edge_list);

    // skip projection: big0 = x @ Wskip + bskip
    gemm_kernel<<<(Nn + GEMM_ROWS - 1) / GEMM_ROWS, 256, 0, stream>>>(x, Wskip, bskip, big0, Nn, 128);

    // layers
    const float* lin[3] = { x,    big1, big0 };
    const float* lid[3] = { big0, big1, big0 };
    float*       lou[3] = { big1, big0, big1 };
    const int    Kd[3]  = { 128, 256, 256 };
    const int    Hh[3]  = { 4, 4, 1 };
    for (int l = 0; l < 3; ++l) {
        gemm_kernel<<<(Nn + GEMM_ROWS - 1) / GEMM_ROWS, 256, 0, stream>>>(
            lin[l], LP(l,0), nullptr, hbuf, Nn, Kd[l]);
        attn_node_kernel<<<(Nn * 64 + 255) / 256, 256, 0, stream>>>(
            hbuf, LP(l,1), LP(l,2), ssrc, sdst, Hh[l]);
        logits_kernel<<<ebks, 256, 0, stream>>>(ei, ea, ea_s, ssrc, sdst, Mbuf + l * 8, albuf, Hh[l]);
        agg_kernel<<<Nn, 256, 0, stream>>>(edge_list, row_start, ei, hbuf, albuf,
            LP(l,5), LP(l,6), LP(l,7), LP(l,8), LP(l,9), lid[l], lou[l], Hh[l]);
    }

    // pooling + head
    pool_init_kernel<<<(Gg * 256 + 255) / 256, 256, 0, stream>>>(pmax);
    pool_kernel<<<nb, 256, 0, stream>>>(big1, bat, psum, pmax, pcnt);
    mlp_kernel<<<Gg, 256, 0, stream>>>(psum, pmax, pcnt, Wp1, bp1, Wp2, bp2, out);
}

// Round 3
// 1847.597 us; speedup vs baseline: 1.4707x; 1.4707x over previous
//
#include <hip/hip_runtime.h>
#include <cfloat>

// Problem constants (match reference setup_inputs)
#define Nn 50000
#define Ee 800000
#define Etot (Ee + Nn)   // edges + self loops = 850000
#define Gg 64
#define HIDc 256
#define BN_EPS 1e-5f

// ---------------------------------------------------------------------------
// small helpers
// ---------------------------------------------------------------------------
__device__ inline void atomicMaxFloat(float* addr, float val) {
    int old = __float_as_int(*addr);
    while (__int_as_float(old) < val) {
        int assumed = old;
        old = atomicCAS((int*)addr, assumed, __float_as_int(val));
        if (old == assumed) break;
    }
}

// ---------------------------------------------------------------------------
// edge_attr mean (sum, divided later)
// ---------------------------------------------------------------------------
__global__ void ea_sum_kernel(const float* __restrict__ ea, float* __restrict__ out) {
    __shared__ float sh0[256], sh1[256];
    float s0 = 0.f, s1 = 0.f;
    for (int e = blockIdx.x * blockDim.x + threadIdx.x; e < Ee; e += gridDim.x * blockDim.x) {
        s0 += ea[2 * e];
        s1 += ea[2 * e + 1];
    }
    sh0[threadIdx.x] = s0; sh1[threadIdx.x] = s1;
    __syncthreads();
    for (int off = 128; off > 0; off >>= 1) {
        if ((int)threadIdx.x < off) {
            sh0[threadIdx.x] += sh0[threadIdx.x + off];
            sh1[threadIdx.x] += sh1[threadIdx.x + off];
        }
        __syncthreads();
    }
    if (threadIdx.x == 0) { atomicAdd(&out[0], sh0[0]); atomicAdd(&out[1], sh1[0]); }
}

// ---------------------------------------------------------------------------
// M[l][d][h] = sum_c We_l[d, h*C+c] * ae_l[h, c]   (layout M[l*8 + d*H + h])
// ---------------------------------------------------------------------------
__global__ void m_kernel(const float* __restrict__ We0, const float* __restrict__ ae0,
                         const float* __restrict__ We1, const float* __restrict__ ae1,
                         const float* __restrict__ We2, const float* __restrict__ ae2,
                         float* __restrict__ M) {
    int t = threadIdx.x;
    if (t >= 18) return;
    int l = t < 8 ? 0 : (t < 16 ? 1 : 2);
    int r = t - l * 8;
    const float* We = (l == 0) ? We0 : (l == 1 ? We1 : We2);
    const float* ae = (l == 0) ? ae0 : (l == 1 ? ae1 : ae2);
    int Hl = (l < 2) ? 4 : 1;
    int Cl = 256 / Hl;
    int d = r / Hl, hh = r % Hl;
    float s = 0.f;
    for (int c = 0; c < Cl; ++c)
        s += We[d * 256 + hh * Cl + c] * ae[hh * Cl + c];
    M[l * 8 + r] = s;
}

// ---------------------------------------------------------------------------
// CSR build: histogram -> scan -> scatter (with src + permutation payload)
// ---------------------------------------------------------------------------
__global__ void hist_kernel(const int* __restrict__ ei, int* __restrict__ counts) {
    int e = blockIdx.x * blockDim.x + threadIdx.x;
    if (e >= Etot) return;
    int d = (e < Ee) ? ei[Ee + e] : (e - Ee);
    atomicAdd(&counts[d], 1);
}

__global__ void scan1_kernel(const int* __restrict__ in, int* __restrict__ inc,
                             int* __restrict__ bsums) {
    __shared__ int sh[256];
    int i = blockIdx.x * 256 + threadIdx.x;
    int v = (i < Nn) ? in[i] : 0;
    sh[threadIdx.x] = v;
    __syncthreads();
    for (int off = 1; off < 256; off <<= 1) {
        int t = ((int)threadIdx.x >= off) ? sh[threadIdx.x - off] : 0;
        __syncthreads();
        sh[threadIdx.x] += t;
        __syncthreads();
    }
    if (i < Nn) inc[i] = sh[threadIdx.x];
    if (threadIdx.x == 255) bsums[blockIdx.x] = sh[255];
}

__global__ void scan2_kernel(int* __restrict__ bsums, int nb) {
    if (blockIdx.x == 0 && threadIdx.x == 0) {
        int acc = 0;
        for (int i = 0; i < nb; ++i) { int v = bsums[i]; bsums[i] = acc; acc += v; }
    }
}

__global__ void scan3_kernel(const int* __restrict__ inc, const int* __restrict__ bsums,
                             int* __restrict__ row_start, int* __restrict__ cursor) {
    int i = blockIdx.x * 256 + threadIdx.x;
    if (i < Nn) {
        int v = inc[i] + bsums[blockIdx.x];
        row_start[i + 1] = v;
        cursor[i + 1] = v;
    }
    if (i == 0) { row_start[0] = 0; cursor[0] = 0; }
}

// writes CSR-ordered src list and the edge->pos permutation
__global__ void scatter_kernel(const int* __restrict__ ei, int* __restrict__ cursor,
                               int* __restrict__ src_sorted, int* __restrict__ eperm) {
    int e = blockIdx.x * blockDim.x + threadIdx.x;
    if (e >= Etot) return;
    int s, d;
    if (e < Ee) { s = ei[e]; d = ei[Ee + e]; }
    else        { s = d = e - Ee; }
    int pos = atomicAdd(&cursor[d], 1);
    src_sorted[pos] = s;
    eperm[e] = pos;
}

// ---------------------------------------------------------------------------
// GEMM: out[n,256] = in[n,K] @ W[K,256] (+bias)    block = 256 thr, 16 rows
// ---------------------------------------------------------------------------
#define GEMM_ROWS 16
__global__ __launch_bounds__(256) void gemm_kernel(
        const float* __restrict__ in, const float* __restrict__ W,
        const float* __restrict__ bias, float* __restrict__ out, int n, int K) {
    __shared__ float tile[GEMM_ROWS][32];
    int col = threadIdx.x;
    int row0 = blockIdx.x * GEMM_ROWS;
    float acc[GEMM_ROWS];
#pragma unroll
    for (int r = 0; r < GEMM_ROWS; ++r) acc[r] = 0.f;
    for (int k0 = 0; k0 < K; k0 += 32) {
        int t = threadIdx.x;
#pragma unroll
        for (int i = 0; i < 2; ++i, t += 256) {
            int r = t >> 5, kk = t & 31;
            int gr = row0 + r;
            tile[r][kk] = (gr < n) ? in[(long)gr * K + k0 + kk] : 0.f;
        }
        __syncthreads();
#pragma unroll 8
        for (int kk = 0; kk < 32; ++kk) {
            float w = W[(long)(k0 + kk) * 256 + col];
#pragma unroll
            for (int r = 0; r < GEMM_ROWS; ++r)
                acc[r] += tile[r][kk] * w;
        }
        __syncthreads();
    }
    float b = bias ? bias[col] : 0.f;
#pragma unroll
    for (int r = 0; r < GEMM_ROWS; ++r) {
        int gr = row0 + r;
        if (gr < n) out[(long)gr * 256 + col] = acc[r] + b;
    }
}

// ---------------------------------------------------------------------------
// per-node attention terms: ssrc[n,h], sdst[n,h]  (one wave per node)
// ---------------------------------------------------------------------------
__global__ void attn_node_kernel(const float* __restrict__ h, const float* __restrict__ a_s,
                                 const float* __restrict__ a_d, float* __restrict__ ssrc,
                                 float* __restrict__ sdst, int H) {
    int wave = (blockIdx.x * blockDim.x + threadIdx.x) >> 6;
    int lane = threadIdx.x & 63;
    if (wave >= Nn) return;
    int C = 256 / H;
    for (int hh = 0; hh < H; ++hh) {
        float ps = 0.f, pd = 0.f;
        for (int c = lane; c < C; c += 64) {
            float v = h[(long)wave * 256 + hh * C + c];
            ps += v * a_s[hh * C + c];
            pd += v * a_d[hh * C + c];
        }
        for (int off = 32; off > 0; off >>= 1) {
            ps += __shfl_down(ps, off);
            pd += __shfl_down(pd, off);
        }
        if (lane == 0) { ssrc[wave * H + hh] = ps; sdst[wave * H + hh] = pd; }
    }
}

// ---------------------------------------------------------------------------
// per-edge attention logits (post-leaky-relu), written in CSR order via eperm
// ---------------------------------------------------------------------------
__global__ void logits_kernel(const int* __restrict__ ei, const float* __restrict__ ea,
                              const float* __restrict__ ea_sum, const int* __restrict__ eperm,
                              const float* __restrict__ ssrc, const float* __restrict__ sdst,
                              const float* __restrict__ M, float* __restrict__ al, int H) {
    int e = blockIdx.x * blockDim.x + threadIdx.x;
    if (e >= Etot) return;
    int s, d; float e0, e1;
    if (e < Ee) {
        s = ei[e]; d = ei[Ee + e];
        e0 = ea[2 * e]; e1 = ea[2 * e + 1];
    } else {
        s = d = e - Ee;
        const float invE = 1.f / (float)Ee;
        e0 = ea_sum[0] * invE; e1 = ea_sum[1] * invE;
    }
    long pos = eperm[e];
    for (int hh = 0; hh < H; ++hh) {
        float v = ssrc[s * H + hh] + sdst[d * H + hh] + e0 * M[hh] + e1 * M[H + hh];
        al[pos * H + hh] = (v > 0.f) ? v : 0.2f * v;
    }
}

// ---------------------------------------------------------------------------
// segment softmax: one thread per (node, head); al is CSR-contiguous
// writes normalized weights w[pos*H+h]
// ---------------------------------------------------------------------------
__global__ void softmax_w_kernel(const float* __restrict__ al, const int* __restrict__ row_start,
                                 float* __restrict__ w, int H) {
    int t = blockIdx.x * blockDim.x + threadIdx.x;
    if (t >= Nn * H) return;
    int n = t / H, hh = t % H;
    int beg = row_start[n], end = row_start[n + 1];
    float m = -FLT_MAX;
    for (int i = beg; i < end; ++i) m = fmaxf(m, al[(long)i * H + hh]);
    float den = 0.f;
    for (int i = beg; i < end; ++i) den += expf(al[(long)i * H + hh] - m);
    float inv = 1.f / (den + 1e-16f);
    for (int i = beg; i < end; ++i) w[(long)i * H + hh] = expf(al[(long)i * H + hh] - m) * inv;
}

// ---------------------------------------------------------------------------
// weighted gather + bconv + BN(eval) + ELU + residual, one block per dst node
// 4-way unrolled with masked tail -> 4 independent gathers in flight
// ---------------------------------------------------------------------------
__global__ __launch_bounds__(256) void agg_kernel(
        const int* __restrict__ src_sorted, const int* __restrict__ row_start,
        const float* __restrict__ hbuf, const float* __restrict__ w,
        const float* __restrict__ bconv,
        const float* __restrict__ bn_g, const float* __restrict__ bn_b,
        const float* __restrict__ bn_m, const float* __restrict__ bn_v,
        const float* __restrict__ identity, float* __restrict__ out, int H) {
    int node = blockIdx.x;
    int c = threadIdx.x;
    int C = 256 / H;
    int hh = c / C;
    int beg = row_start[node], end = row_start[node + 1];
    float acc = 0.f;
    for (int idx = beg; idx < end; idx += 4) {
        int   s[4];
        float ww[4];
#pragma unroll
        for (int k = 0; k < 4; ++k) {
            int j = idx + k;
            bool ok = j < end;
            int jj = ok ? j : beg;
            s[k]  = src_sorted[jj];
            ww[k] = ok ? w[(long)jj * H + hh] : 0.f;
        }
        float v0 = hbuf[(long)s[0] * 256 + c];
        float v1 = hbuf[(long)s[1] * 256 + c];
        float v2 = hbuf[(long)s[2] * 256 + c];
        float v3 = hbuf[(long)s[3] * 256 + c];
        acc += ww[0] * v0;
        acc += ww[1] * v1;
        acc += ww[2] * v2;
        acc += ww[3] * v3;
    }
    float v = acc + bconv[c];
    v = (v - bn_m[c]) * rsqrtf(bn_v[c] + BN_EPS) * bn_g[c] + bn_b[c];
    v = (v > 0.f) ? v : (expf(v) - 1.f);
    out[(long)node * 256 + c] = v + identity[(long)node * 256 + c];
}

// ---------------------------------------------------------------------------
// pooling
// ---------------------------------------------------------------------------
__global__ void pool_init_kernel(float* __restrict__ pmax) {
    int i = blockIdx.x * blockDim.x + threadIdx.x;
    if (i < Gg * 256) pmax[i] = -FLT_MAX;
}

__global__ __launch_bounds__(256) void pool_kernel(
        const float* __restrict__ x, const int* __restrict__ batch,
        float* __restrict__ psum, float* __restrict__ pmax, float* __restrict__ pcnt) {
    int c = threadIdx.x;
    int n0 = blockIdx.x * 256;
    if (n0 >= Nn) return;
    int n1 = min(n0 + 256, Nn);
    int cur = batch[n0];
    float s = 0.f, mx = -FLT_MAX;
    int cnt = 0;
    for (int i = n0; i < n1; ++i) {
        int g = batch[i];
        if (g != cur) {
            atomicAdd(&psum[cur * 256 + c], s);
            atomicMaxFloat(&pmax[cur * 256 + c], mx);
            if (c == 0) atomicAdd(&pcnt[cur], (float)cnt);
            cur = g; s = 0.f; mx = -FLT_MAX; cnt = 0;
        }
        float v = x[(long)i * 256 + c];
        s += v; mx = fmaxf(mx, v); ++cnt;
    }
    atomicAdd(&psum[cur * 256 + c], s);
    atomicMaxFloat(&pmax[cur * 256 + c], mx);
    if (c == 0) atomicAdd(&pcnt[cur], (float)cnt);
}

// ---------------------------------------------------------------------------
// head MLP: relu(emb @ Wp1 + bp1) @ Wp2 + bp2  -> out[g]
// ---------------------------------------------------------------------------
__global__ __launch_bounds__(256) void mlp_kernel(
        const float* __restrict__ psum, const float* __restrict__ pmax,
        const float* __restrict__ pcnt, const float* __restrict__ Wp1,
        const float* __restrict__ bp1, const float* __restrict__ Wp2,
        const float* __restrict__ bp2, float* __restrict__ out) {
    int g = blockIdx.x;
    int j = threadIdx.x;
    float inv = 1.f / fmaxf(pcnt[g], 1.f);
    float acc = bp1[j];
    for (int k = 0; k < 256; ++k)
        acc += (psum[g * 256 + k] * inv) * Wp1[k * 256 + j];
    for (int k = 0; k < 256; ++k)
        acc += pmax[g * 256 + k] * Wp1[(256 + k) * 256 + j];
    float v = fmaxf(acc, 0.f) * Wp2[j];
    __shared__ float red[256];
    red[j] = v;
    __syncthreads();
    for (int off = 128; off > 0; off >>= 1) {
        if (j < off) red[j] += red[j + off];
        __syncthreads();
    }
    if (j == 0) out[g] = red[0] + bp2[0];
}

// ---------------------------------------------------------------------------
// launch
// ---------------------------------------------------------------------------
extern "C" void kernel_launch(void* const* d_in, const int* in_sizes, int n_in,
                              void* d_out, int out_size, void* d_ws, size_t ws_size,
                              hipStream_t stream) {
    const float* x   = (const float*)d_in[0];
    const int*   ei  = (const int*)d_in[1];
    const float* ea  = (const float*)d_in[2];
    const int*   bat = (const int*)d_in[3];
    auto LP = [&](int l, int j) { return (const float*)d_in[4 + l * 10 + j]; };
    const float* Wskip = (const float*)d_in[34];
    const float* bskip = (const float*)d_in[35];
    const float* Wp1   = (const float*)d_in[36];
    const float* bp1   = (const float*)d_in[37];
    const float* Wp2   = (const float*)d_in[38];
    const float* bp2   = (const float*)d_in[39];
    float* out = (float*)d_out;

    // workspace carve-up (256B aligned)
    char* p = (char*)d_ws;
    auto alloc = [&](size_t bytes) { void* r = (void*)p; p += (bytes + 255) & ~(size_t)255; return r; };
    float* big0   = (float*)alloc((size_t)Nn * 256 * 4);   // xskip, later layer1-out
    float* big1   = (float*)alloc((size_t)Nn * 256 * 4);   // layer0-out / layer2-out (final x)
    float* hbuf   = (float*)alloc((size_t)Nn * 256 * 4);
    float* albuf  = (float*)alloc((size_t)Etot * 4 * 4);   // CSR-ordered logits
    float* wbuf   = (float*)alloc((size_t)Etot * 4 * 4);   // CSR-ordered softmax weights
    float* ssrc   = (float*)alloc((size_t)Nn * 4 * 4);
    float* sdst   = (float*)alloc((size_t)Nn * 4 * 4);
    int*   counts = (int*)alloc((size_t)Nn * 4);
    int*   incb   = (int*)alloc((size_t)Nn * 4);
    int*   row_start = (int*)alloc((size_t)(Nn + 1) * 4);
    int*   cursor    = (int*)alloc((size_t)(Nn + 1) * 4);
    int*   src_sorted = (int*)alloc((size_t)Etot * 4);
    int*   eperm      = (int*)alloc((size_t)Etot * 4);
    int*   bsums  = (int*)alloc(256 * 4);
    float* ea_s   = (float*)alloc(2 * 4);
    float* Mbuf   = (float*)alloc(32 * 4);
    float* psum   = (float*)alloc((size_t)Gg * 256 * 4);
    float* pmax   = (float*)alloc((size_t)Gg * 256 * 4);
    float* pcnt   = (float*)alloc((size_t)Gg * 4);

    const int nb = (Nn + 255) / 256;           // scan blocks
    const int ebks = (Etot + 255) / 256;       // edge-parallel blocks

    // zero init
    hipMemsetAsync(counts, 0, (size_t)Nn * 4, stream);
    hipMemsetAsync(ea_s, 0, 8, stream);
    hipMemsetAsync(psum, 0, (size_t)Gg * 256 * 4, stream);
    hipMemsetAsync(pcnt, 0, (size_t)Gg * 4, stream);

    // edge-attr mean + M
    ea_sum_kernel<<<256, 256, 0, stream>>>(ea, ea_s);
    m_kernel<<<1, 64, 0, stream>>>(LP(0,3), LP(0,4), LP(1,3), LP(1,4), LP(2,3), LP(2,4), Mbuf);

    // CSR
    hist_kernel<<<ebks, 256, 0, stream>>>(ei, counts);
    scan1_kernel<<<nb, 256, 0, stream>>>(counts, incb, bsums);
    scan2_kernel<<<1, 64, 0, stream>>>(bsums, nb);
    scan3_kernel<<<nb, 256, 0, stream>>>(incb, bsums, row_start, cursor);
    scatter_kernel<<<ebks, 256, 0, stream>>>(ei, cursor, src_sorted, eperm);

    // skip projection: big0 = x @ Wskip + bskip
    gemm_kernel<<<(Nn + GEMM_ROWS - 1) / GEMM_ROWS, 256, 0, stream>>>(x, Wskip, bskip, big0, Nn, 128);

    // layers
    const float* lin[3] = { x,    big1, big0 };
    const float* lid[3] = { big0, big1, big0 };
    float*       lou[3] = { big1, big0, big1 };
    const int    Kd[3]  = { 128, 256, 256 };
    const int    Hh[3]  = { 4, 4, 1 };
    for (int l = 0; l < 3; ++l) {
        const int H = Hh[l];
        gemm_kernel<<<(Nn + GEMM_ROWS - 1) / GEMM_ROWS, 256, 0, stream>>>(
            lin[l], LP(l,0), nullptr, hbuf, Nn, Kd[l]);
        attn_node_kernel<<<(Nn * 64 + 255) / 256, 256, 0, stream>>>(
            hbuf, LP(l,1), LP(l,2), ssrc, sdst, H);
        logits_kernel<<<ebks, 256, 0, stream>>>(ei, ea, ea_s, eperm, ssrc, sdst,
                                                Mbuf + l * 8, albuf, H);
        softmax_w_kernel<<<(Nn * H + 255) / 256, 256, 0, stream>>>(albuf, row_start, wbuf, H);
        agg_kernel<<<Nn, 256, 0, stream>>>(src_sorted, row_start, hbuf, wbuf,
            LP(l,5), LP(l,6), LP(l,7), LP(l,8), LP(l,9), lid[l], lou[l], H);
    }

    // pooling + head
    pool_init_kernel<<<(Gg * 256 + 255) / 256, 256, 0, stream>>>(pmax);
    pool_kernel<<<nb, 256, 0, stream>>>(big1, bat, psum, pmax, pcnt);
    mlp_kernel<<<Gg, 256, 0, stream>>>(psum, pmax, pcnt, Wp1, bp1, Wp2, bp2, out);
}

// Round 5
// 1288.276 us; speedup vs baseline: 2.1093x; 1.4342x over previous
//
#include <hip/hip_runtime.h>
#include <cfloat>

// Problem constants (match reference setup_inputs)
#define Nn 50000
#define Ee 800000
#define Etot (Ee + Nn)   // edges + self loops = 850000
#define Gg 64
#define HIDc 256
#define BN_EPS 1e-5f

// ---------------------------------------------------------------------------
// small helpers
// ---------------------------------------------------------------------------
__device__ inline void atomicMaxFloat(float* addr, float val) {
    int old = __float_as_int(*addr);
    while (__int_as_float(old) < val) {
        int assumed = old;
        old = atomicCAS((int*)addr, assumed, __float_as_int(val));
        if (old == assumed) break;
    }
}

// ---------------------------------------------------------------------------
// edge_attr mean (sum, divided later)
// ---------------------------------------------------------------------------
__global__ void ea_sum_kernel(const float* __restrict__ ea, float* __restrict__ out) {
    __shared__ float sh0[256], sh1[256];
    float s0 = 0.f, s1 = 0.f;
    for (int e = blockIdx.x * blockDim.x + threadIdx.x; e < Ee; e += gridDim.x * blockDim.x) {
        s0 += ea[2 * e];
        s1 += ea[2 * e + 1];
    }
    sh0[threadIdx.x] = s0; sh1[threadIdx.x] = s1;
    __syncthreads();
    for (int off = 128; off > 0; off >>= 1) {
        if ((int)threadIdx.x < off) {
            sh0[threadIdx.x] += sh0[threadIdx.x + off];
            sh1[threadIdx.x] += sh1[threadIdx.x + off];
        }
        __syncthreads();
    }
    if (threadIdx.x == 0) { atomicAdd(&out[0], sh0[0]); atomicAdd(&out[1], sh1[0]); }
}

// ---------------------------------------------------------------------------
// M[l][d][h] = sum_c We_l[d, h*C+c] * ae_l[h, c]   (layout M[l*8 + d*H + h])
// ---------------------------------------------------------------------------
__global__ void m_kernel(const float* __restrict__ We0, const float* __restrict__ ae0,
                         const float* __restrict__ We1, const float* __restrict__ ae1,
                         const float* __restrict__ We2, const float* __restrict__ ae2,
                         float* __restrict__ M) {
    int t = threadIdx.x;
    if (t >= 18) return;
    int l = t < 8 ? 0 : (t < 16 ? 1 : 2);
    int r = t - l * 8;
    const float* We = (l == 0) ? We0 : (l == 1 ? We1 : We2);
    const float* ae = (l == 0) ? ae0 : (l == 1 ? ae1 : ae2);
    int Hl = (l < 2) ? 4 : 1;
    int Cl = 256 / Hl;
    int d = r / Hl, hh = r % Hl;
    float s = 0.f;
    for (int c = 0; c < Cl; ++c)
        s += We[d * 256 + hh * Cl + c] * ae[hh * Cl + c];
    M[l * 8 + r] = s;
}

// ---------------------------------------------------------------------------
// CSR build: histogram -> scan -> scatter (with src + permutation payload)
// ---------------------------------------------------------------------------
__global__ void hist_kernel(const int* __restrict__ ei, int* __restrict__ counts) {
    int e = blockIdx.x * blockDim.x + threadIdx.x;
    if (e >= Etot) return;
    int d = (e < Ee) ? ei[Ee + e] : (e - Ee);
    atomicAdd(&counts[d], 1);
}

__global__ void scan1_kernel(const int* __restrict__ in, int* __restrict__ inc,
                             int* __restrict__ bsums) {
    __shared__ int sh[256];
    int i = blockIdx.x * 256 + threadIdx.x;
    int v = (i < Nn) ? in[i] : 0;
    sh[threadIdx.x] = v;
    __syncthreads();
    for (int off = 1; off < 256; off <<= 1) {
        int t = ((int)threadIdx.x >= off) ? sh[threadIdx.x - off] : 0;
        __syncthreads();
        sh[threadIdx.x] += t;
        __syncthreads();
    }
    if (i < Nn) inc[i] = sh[threadIdx.x];
    if (threadIdx.x == 255) bsums[blockIdx.x] = sh[255];
}

__global__ void scan2_kernel(int* __restrict__ bsums, int nb) {
    if (blockIdx.x == 0 && threadIdx.x == 0) {
        int acc = 0;
        for (int i = 0; i < nb; ++i) { int v = bsums[i]; bsums[i] = acc; acc += v; }
    }
}

__global__ void scan3_kernel(const int* __restrict__ inc, const int* __restrict__ bsums,
                             int* __restrict__ row_start, int* __restrict__ cursor) {
    int i = blockIdx.x * 256 + threadIdx.x;
    if (i < Nn) {
        int v = inc[i] + bsums[blockIdx.x];
        row_start[i + 1] = v;
        cursor[i + 1] = v;
    }
    if (i == 0) { row_start[0] = 0; cursor[0] = 0; }
}

// writes CSR-ordered src list and the edge->pos permutation
__global__ void scatter_kernel(const int* __restrict__ ei, int* __restrict__ cursor,
                               int* __restrict__ src_sorted, int* __restrict__ eperm) {
    int e = blockIdx.x * blockDim.x + threadIdx.x;
    if (e >= Etot) return;
    int s, d;
    if (e < Ee) { s = ei[e]; d = ei[Ee + e]; }
    else        { s = d = e - Ee; }
    int pos = atomicAdd(&cursor[d], 1);
    src_sorted[pos] = s;
    eperm[e] = pos;
}

// ---------------------------------------------------------------------------
// Register-tiled GEMM: out[n,256] = in[n,K] @ W[K,256] (+bias)
// 128x128 block tile, 256 threads, 8x8 per thread (2x2 sub-tiles of 4x4,
// 64-apart strides so LDS reads are broadcast/2-way conflict-free).
// ---------------------------------------------------------------------------
#define BM 128
#define BN 128
#define BK 16
__global__ __launch_bounds__(256) void gemm_kernel(
        const float* __restrict__ in, const float* __restrict__ W,
        const float* __restrict__ bias, float* __restrict__ out, int n, int K) {
    __shared__ float As[BK][BM];
    __shared__ float Bs[BK][BN];
    const int t  = threadIdx.x;
    const int n0 = blockIdx.x * BM;
    const int c0 = blockIdx.y * BN;
    const int tr = t >> 4;          // 0..15
    const int tc = t & 15;          // 0..15

    // A staging indices: row = t&127 (lane==row -> conflict-free LDS writes)
    const int arow = t & 127;
    const int akq  = t >> 7;        // 0..1, float4-quad along k

    // B staging indices
    const int bkk = t >> 5;         // 0..7
    const int bcq = t & 31;         // 0..31 float4 along cols

    float acc[8][8];
#pragma unroll
    for (int i = 0; i < 8; ++i)
#pragma unroll
        for (int j = 0; j < 8; ++j) acc[i][j] = 0.f;

    for (int k0 = 0; k0 < K; k0 += BK) {
#pragma unroll
        for (int h = 0; h < 2; ++h) {
            int kq = akq + 2 * h;
            int grow = n0 + arow;
            float4 v = make_float4(0.f, 0.f, 0.f, 0.f);
            if (grow < n) v = *(const float4*)&in[(long)grow * K + k0 + 4 * kq];
            As[4 * kq + 0][arow] = v.x;
            As[4 * kq + 1][arow] = v.y;
            As[4 * kq + 2][arow] = v.z;
            As[4 * kq + 3][arow] = v.w;
        }
#pragma unroll
        for (int h = 0; h < 2; ++h) {
            int kk = bkk + 8 * h;
            *(float4*)&Bs[kk][4 * bcq] = *(const float4*)&W[(long)(k0 + kk) * 256 + c0 + 4 * bcq];
        }
        __syncthreads();
#pragma unroll
        for (int kk = 0; kk < BK; ++kk) {
            float a[8], b[8];
            *(float4*)&a[0] = *(const float4*)&As[kk][4 * tr];
            *(float4*)&a[4] = *(const float4*)&As[kk][64 + 4 * tr];
            *(float4*)&b[0] = *(const float4*)&Bs[kk][4 * tc];
            *(float4*)&b[4] = *(const float4*)&Bs[kk][64 + 4 * tc];
#pragma unroll
            for (int i = 0; i < 8; ++i)
#pragma unroll
                for (int j = 0; j < 8; ++j)
                    acc[i][j] += a[i] * b[j];
        }
        __syncthreads();
    }

    // epilogue
    float bb[8];
#pragma unroll
    for (int j = 0; j < 8; ++j) {
        int col = c0 + ((j < 4) ? (4 * tc + j) : (64 + 4 * tc + j - 4));
        bb[j] = bias ? bias[col] : 0.f;
    }
#pragma unroll
    for (int i = 0; i < 8; ++i) {
        int row = n0 + ((i < 4) ? (4 * tr + i) : (64 + 4 * tr + i - 4));
        if (row < n) {
            float4 lo, hi;
            lo.x = acc[i][0] + bb[0]; lo.y = acc[i][1] + bb[1];
            lo.z = acc[i][2] + bb[2]; lo.w = acc[i][3] + bb[3];
            hi.x = acc[i][4] + bb[4]; hi.y = acc[i][5] + bb[5];
            hi.z = acc[i][6] + bb[6]; hi.w = acc[i][7] + bb[7];
            *(float4*)&out[(long)row * 256 + c0 + 4 * tc]      = lo;
            *(float4*)&out[(long)row * 256 + c0 + 64 + 4 * tc] = hi;
        }
    }
}

// ---------------------------------------------------------------------------
// per-node attention terms: ssrc[n,h], sdst[n,h]  (one wave per node)
// ---------------------------------------------------------------------------
__global__ void attn_node_kernel(const float* __restrict__ h, const float* __restrict__ a_s,
                                 const float* __restrict__ a_d, float* __restrict__ ssrc,
                                 float* __restrict__ sdst, int H) {
    int wave = (blockIdx.x * blockDim.x + threadIdx.x) >> 6;
    int lane = threadIdx.x & 63;
    if (wave >= Nn) return;
    int C = 256 / H;
    for (int hh = 0; hh < H; ++hh) {
        float ps = 0.f, pd = 0.f;
        for (int c = lane; c < C; c += 64) {
            float v = h[(long)wave * 256 + hh * C + c];
            ps += v * a_s[hh * C + c];
            pd += v * a_d[hh * C + c];
        }
        for (int off = 32; off > 0; off >>= 1) {
            ps += __shfl_down(ps, off);
            pd += __shfl_down(pd, off);
        }
        if (lane == 0) { ssrc[wave * H + hh] = ps; sdst[wave * H + hh] = pd; }
    }
}

// ---------------------------------------------------------------------------
// per-edge attention logits (post-leaky-relu), written in CSR order via eperm
// ---------------------------------------------------------------------------
__global__ void logits_kernel(const int* __restrict__ ei, const float* __restrict__ ea,
                              const float* __restrict__ ea_sum, const int* __restrict__ eperm,
                              const float* __restrict__ ssrc, const float* __restrict__ sdst,
                              const float* __restrict__ M, float* __restrict__ al, int H) {
    int e = blockIdx.x * blockDim.x + threadIdx.x;
    if (e >= Etot) return;
    int s, d; float e0, e1;
    if (e < Ee) {
        s = ei[e]; d = ei[Ee + e];
        e0 = ea[2 * e]; e1 = ea[2 * e + 1];
    } else {
        s = d = e - Ee;
        const float invE = 1.f / (float)Ee;
        e0 = ea_sum[0] * invE; e1 = ea_sum[1] * invE;
    }
    long pos = eperm[e];
    for (int hh = 0; hh < H; ++hh) {
        float v = ssrc[s * H + hh] + sdst[d * H + hh] + e0 * M[hh] + e1 * M[H + hh];
        al[pos * H + hh] = (v > 0.f) ? v : 0.2f * v;
    }
}

// ---------------------------------------------------------------------------
// segment softmax: one thread per (node, head); al is CSR-contiguous
// writes normalized weights w[pos*H+h]
// ---------------------------------------------------------------------------
__global__ void softmax_w_kernel(const float* __restrict__ al, const int* __restrict__ row_start,
                                 float* __restrict__ w, int H) {
    int t = blockIdx.x * blockDim.x + threadIdx.x;
    if (t >= Nn * H) return;
    int n = t / H, hh = t % H;
    int beg = row_start[n], end = row_start[n + 1];
    float m = -FLT_MAX;
    for (int i = beg; i < end; ++i) m = fmaxf(m, al[(long)i * H + hh]);
    float den = 0.f;
    for (int i = beg; i < end; ++i) den += expf(al[(long)i * H + hh] - m);
    float inv = 1.f / (den + 1e-16f);
    for (int i = beg; i < end; ++i) w[(long)i * H + hh] = expf(al[(long)i * H + hh] - m) * inv;
}

// ---------------------------------------------------------------------------
// weighted gather + bconv + BN(eval) + ELU + residual, one block per dst node
// 4-way unrolled with masked tail -> 4 independent gathers in flight
// ---------------------------------------------------------------------------
__global__ __launch_bounds__(256) void agg_kernel(
        const int* __restrict__ src_sorted, const int* __restrict__ row_start,
        const float* __restrict__ hbuf, const float* __restrict__ w,
        const float* __restrict__ bconv,
        const float* __restrict__ bn_g, const float* __restrict__ bn_b,
        const float* __restrict__ bn_m, const float* __restrict__ bn_v,
        const float* __restrict__ identity, float* __restrict__ out, int H) {
    int node = blockIdx.x;
    int c = threadIdx.x;
    int C = 256 / H;
    int hh = c / C;
    int beg = row_start[node], end = row_start[node + 1];
    float acc = 0.f;
    for (int idx = beg; idx < end; idx += 4) {
        int   s[4];
        float ww[4];
#pragma unroll
        for (int k = 0; k < 4; ++k) {
            int j = idx + k;
            bool ok = j < end;
            int jj = ok ? j : beg;
            s[k]  = src_sorted[jj];
            ww[k] = ok ? w[(long)jj * H + hh] : 0.f;
        }
        float v0 = hbuf[(long)s[0] * 256 + c];
        float v1 = hbuf[(long)s[1] * 256 + c];
        float v2 = hbuf[(long)s[2] * 256 + c];
        float v3 = hbuf[(long)s[3] * 256 + c];
        acc += ww[0] * v0;
        acc += ww[1] * v1;
        acc += ww[2] * v2;
        acc += ww[3] * v3;
    }
    float v = acc + bconv[c];
    v = (v - bn_m[c]) * rsqrtf(bn_v[c] + BN_EPS) * bn_g[c] + bn_b[c];
    v = (v > 0.f) ? v : (expf(v) - 1.f);
    out[(long)node * 256 + c] = v + identity[(long)node * 256 + c];
}

// ---------------------------------------------------------------------------
// pooling
// ---------------------------------------------------------------------------
__global__ void pool_init_kernel(float* __restrict__ pmax) {
    int i = blockIdx.x * blockDim.x + threadIdx.x;
    if (i < Gg * 256) pmax[i] = -FLT_MAX;
}

__global__ __launch_bounds__(256) void pool_kernel(
        const float* __restrict__ x, const int* __restrict__ batch,
        float* __restrict__ psum, float* __restrict__ pmax, float* __restrict__ pcnt) {
    int c = threadIdx.x;
    int n0 = blockIdx.x * 256;
    if (n0 >= Nn) return;
    int n1 = min(n0 + 256, Nn);
    int cur = batch[n0];
    float s = 0.f, mx = -FLT_MAX;
    int cnt = 0;
    for (int i = n0; i < n1; ++i) {
        int g = batch[i];
        if (g != cur) {
            atomicAdd(&psum[cur * 256 + c], s);
            atomicMaxFloat(&pmax[cur * 256 + c], mx);
            if (c == 0) atomicAdd(&pcnt[cur], (float)cnt);
            cur = g; s = 0.f; mx = -FLT_MAX; cnt = 0;
        }
        float v = x[(long)i * 256 + c];
        s += v; mx = fmaxf(mx, v); ++cnt;
    }
    atomicAdd(&psum[cur * 256 + c], s);
    atomicMaxFloat(&pmax[cur * 256 + c], mx);
    if (c == 0) atomicAdd(&pcnt[cur], (float)cnt);
}

// ---------------------------------------------------------------------------
// head MLP: relu(emb @ Wp1 + bp1) @ Wp2 + bp2  -> out[g]
// ---------------------------------------------------------------------------
__global__ __launch_bounds__(256) void mlp_kernel(
        const float* __restrict__ psum, const float* __restrict__ pmax,
        const float* __restrict__ pcnt, const float* __restrict__ Wp1,
        const float* __restrict__ bp1, const float* __restrict__ Wp2,
        const float* __restrict__ bp2, float* __restrict__ out) {
    int g = blockIdx.x;
    int j = threadIdx.x;
    float inv = 1.f / fmaxf(pcnt[g], 1.f);
    float acc = bp1[j];
    for (int k = 0; k < 256; ++k)
        acc += (psum[g * 256 + k] * inv) * Wp1[k * 256 + j];
    for (int k = 0; k < 256; ++k)
        acc += pmax[g * 256 + k] * Wp1[(256 + k) * 256 + j];
    float v = fmaxf(acc, 0.f) * Wp2[j];
    __shared__ float red[256];
    red[j] = v;
    __syncthreads();
    for (int off = 128; off > 0; off >>= 1) {
        if (j < off) red[j] += red[j + off];
        __syncthreads();
    }
    if (j == 0) out[g] = red[0] + bp2[0];
}

// ---------------------------------------------------------------------------
// launch
// ---------------------------------------------------------------------------
extern "C" void kernel_launch(void* const* d_in, const int* in_sizes, int n_in,
                              void* d_out, int out_size, void* d_ws, size_t ws_size,
                              hipStream_t stream) {
    const float* x   = (const float*)d_in[0];
    const int*   ei  = (const int*)d_in[1];
    const float* ea  = (const float*)d_in[2];
    const int*   bat = (const int*)d_in[3];
    auto LP = [&](int l, int j) { return (const float*)d_in[4 + l * 10 + j]; };
    const float* Wskip = (const float*)d_in[34];
    const float* bskip = (const float*)d_in[35];
    const float* Wp1   = (const float*)d_in[36];
    const float* bp1   = (const float*)d_in[37];
    const float* Wp2   = (const float*)d_in[38];
    const float* bp2   = (const float*)d_in[39];
    float* out = (float*)d_out;

    // workspace carve-up (256B aligned)
    char* p = (char*)d_ws;
    auto alloc = [&](size_t bytes) { void* r = (void*)p; p += (bytes + 255) & ~(size_t)255; return r; };
    float* big0   = (float*)alloc((size_t)Nn * 256 * 4);   // xskip, later layer1-out
    float* big1   = (float*)alloc((size_t)Nn * 256 * 4);   // layer0-out / layer2-out (final x)
    float* hbuf   = (float*)alloc((size_t)Nn * 256 * 4);
    float* albuf  = (float*)alloc((size_t)Etot * 4 * 4);   // CSR-ordered logits
    float* wbuf   = (float*)alloc((size_t)Etot * 4 * 4);   // CSR-ordered softmax weights
    float* ssrc   = (float*)alloc((size_t)Nn * 4 * 4);
    float* sdst   = (float*)alloc((size_t)Nn * 4 * 4);
    int*   counts = (int*)alloc((size_t)Nn * 4);
    int*   incb   = (int*)alloc((size_t)Nn * 4);
    int*   row_start = (int*)alloc((size_t)(Nn + 1) * 4);
    int*   cursor    = (int*)alloc((size_t)(Nn + 1) * 4);
    int*   src_sorted = (int*)alloc((size_t)Etot * 4);
    int*   eperm      = (int*)alloc((size_t)Etot * 4);
    int*   bsums  = (int*)alloc(256 * 4);
    float* ea_s   = (float*)alloc(2 * 4);
    float* Mbuf   = (float*)alloc(32 * 4);
    float* psum   = (float*)alloc((size_t)Gg * 256 * 4);
    float* pmax   = (float*)alloc((size_t)Gg * 256 * 4);
    float* pcnt   = (float*)alloc((size_t)Gg * 4);

    const int nb = (Nn + 255) / 256;           // scan blocks
    const int ebks = (Etot + 255) / 256;       // edge-parallel blocks
    dim3 ggrid((Nn + BM - 1) / BM, 256 / BN);

    // zero init
    hipMemsetAsync(counts, 0, (size_t)Nn * 4, stream);
    hipMemsetAsync(ea_s, 0, 8, stream);
    hipMemsetAsync(psum, 0, (size_t)Gg * 256 * 4, stream);
    hipMemsetAsync(pcnt, 0, (size_t)Gg * 4, stream);

    // edge-attr mean + M
    ea_sum_kernel<<<256, 256, 0, stream>>>(ea, ea_s);
    m_kernel<<<1, 64, 0, stream>>>(LP(0,3), LP(0,4), LP(1,3), LP(1,4), LP(2,3), LP(2,4), Mbuf);

    // CSR
    hist_kernel<<<ebks, 256, 0, stream>>>(ei, counts);
    scan1_kernel<<<nb, 256, 0, stream>>>(counts, incb, bsums);
    scan2_kernel<<<1, 64, 0, stream>>>(bsums, nb);
    scan3_kernel<<<nb, 256, 0, stream>>>(incb, bsums, row_start, cursor);
    scatter_kernel<<<ebks, 256, 0, stream>>>(ei, cursor, src_sorted, eperm);

    // skip projection: big0 = x @ Wskip + bskip
    gemm_kernel<<<ggrid, 256, 0, stream>>>(x, Wskip, bskip, big0, Nn, 128);

    // layers
    const float* lin[3] = { x,    big1, big0 };
    const float* lid[3] = { big0, big1, big0 };
    float*       lou[3] = { big1, big0, big1 };
    const int    Kd[3]  = { 128, 256, 256 };
    const int    Hh[3]  = { 4, 4, 1 };
    for (int l = 0; l < 3; ++l) {
        const int H = Hh[l];
        gemm_kernel<<<ggrid, 256, 0, stream>>>(lin[l], LP(l,0), nullptr, hbuf, Nn, Kd[l]);
        attn_node_kernel<<<(Nn * 64 + 255) / 256, 256, 0, stream>>>(
            hbuf, LP(l,1), LP(l,2), ssrc, sdst, H);
        logits_kernel<<<ebks, 256, 0, stream>>>(ei, ea, ea_s, eperm, ssrc, sdst,
                                                Mbuf + l * 8, albuf, H);
        softmax_w_kernel<<<(Nn * H + 255) / 256, 256, 0, stream>>>(albuf, row_start, wbuf, H);
        agg_kernel<<<Nn, 256, 0, stream>>>(src_sorted, row_start, hbuf, wbuf,
            LP(l,5), LP(l,6), LP(l,7), LP(l,8), LP(l,9), lid[l], lou[l], H);
    }

    // pooling + head
    pool_init_kernel<<<(Gg * 256 + 255) / 256, 256, 0, stream>>>(pmax);
    pool_kernel<<<nb, 256, 0, stream>>>(big1, bat, psum, pmax, pcnt);
    mlp_kernel<<<Gg, 256, 0, stream>>>(psum, pmax, pcnt, Wp1, bp1, Wp2, bp2, out);
}

// Round 6
// 1079.352 us; speedup vs baseline: 2.5176x; 1.1936x over previous
//
#include <hip/hip_runtime.h>
#include <cfloat>

// Problem constants (match reference setup_inputs)
#define Nn 50000
#define Ee 800000
#define Etot (Ee + Nn)   // edges + self loops = 850000
#define Gg 64
#define HIDc 256
#define BN_EPS 1e-5f

typedef unsigned int  uint32;
typedef unsigned short ushort16;

// ---------------------------------------------------------------------------
// small helpers
// ---------------------------------------------------------------------------
__device__ inline void atomicMaxFloat(float* addr, float val) {
    int old = __float_as_int(*addr);
    while (__int_as_float(old) < val) {
        int assumed = old;
        old = atomicCAS((int*)addr, assumed, __float_as_int(val));
        if (old == assumed) break;
    }
}

__device__ inline ushort16 f2bf(float f) {            // RNE fp32 -> bf16
    uint32 u = __float_as_uint(f);
    u = (u + 0x7fffu + ((u >> 16) & 1u)) >> 16;
    return (ushort16)u;
}
__device__ inline float bf2f(ushort16 u) {
    return __uint_as_float(((uint32)u) << 16);
}

// ---------------------------------------------------------------------------
// edge_attr mean (sum, divided later)
// ---------------------------------------------------------------------------
__global__ void ea_sum_kernel(const float* __restrict__ ea, float* __restrict__ out) {
    __shared__ float sh0[256], sh1[256];
    float s0 = 0.f, s1 = 0.f;
    for (int e = blockIdx.x * blockDim.x + threadIdx.x; e < Ee; e += gridDim.x * blockDim.x) {
        s0 += ea[2 * e];
        s1 += ea[2 * e + 1];
    }
    sh0[threadIdx.x] = s0; sh1[threadIdx.x] = s1;
    __syncthreads();
    for (int off = 128; off > 0; off >>= 1) {
        if ((int)threadIdx.x < off) {
            sh0[threadIdx.x] += sh0[threadIdx.x + off];
            sh1[threadIdx.x] += sh1[threadIdx.x + off];
        }
        __syncthreads();
    }
    if (threadIdx.x == 0) { atomicAdd(&out[0], sh0[0]); atomicAdd(&out[1], sh1[0]); }
}

// ---------------------------------------------------------------------------
// M[l][d][h] = sum_c We_l[d, h*C+c] * ae_l[h, c]   (layout M[l*8 + d*H + h])
// ---------------------------------------------------------------------------
__global__ void m_kernel(const float* __restrict__ We0, const float* __restrict__ ae0,
                         const float* __restrict__ We1, const float* __restrict__ ae1,
                         const float* __restrict__ We2, const float* __restrict__ ae2,
                         float* __restrict__ M) {
    int t = threadIdx.x;
    if (t >= 18) return;
    int l = t < 8 ? 0 : (t < 16 ? 1 : 2);
    int r = t - l * 8;
    const float* We = (l == 0) ? We0 : (l == 1 ? We1 : We2);
    const float* ae = (l == 0) ? ae0 : (l == 1 ? ae1 : ae2);
    int Hl = (l < 2) ? 4 : 1;
    int Cl = 256 / Hl;
    int d = r / Hl, hh = r % Hl;
    float s = 0.f;
    for (int c = 0; c < Cl; ++c)
        s += We[d * 256 + hh * Cl + c] * ae[hh * Cl + c];
    M[l * 8 + r] = s;
}

// ---------------------------------------------------------------------------
// CSR build: histogram -> scan -> scatter (src + CSR-ordered edge attrs)
// ---------------------------------------------------------------------------
__global__ void hist_kernel(const int* __restrict__ ei, int* __restrict__ counts) {
    int e = blockIdx.x * blockDim.x + threadIdx.x;
    if (e >= Etot) return;
    int d = (e < Ee) ? ei[Ee + e] : (e - Ee);
    atomicAdd(&counts[d], 1);
}

__global__ void scan1_kernel(const int* __restrict__ in, int* __restrict__ inc,
                             int* __restrict__ bsums) {
    __shared__ int sh[256];
    int i = blockIdx.x * 256 + threadIdx.x;
    int v = (i < Nn) ? in[i] : 0;
    sh[threadIdx.x] = v;
    __syncthreads();
    for (int off = 1; off < 256; off <<= 1) {
        int t = ((int)threadIdx.x >= off) ? sh[threadIdx.x - off] : 0;
        __syncthreads();
        sh[threadIdx.x] += t;
        __syncthreads();
    }
    if (i < Nn) inc[i] = sh[threadIdx.x];
    if (threadIdx.x == 255) bsums[blockIdx.x] = sh[255];
}

__global__ void scan2_kernel(int* __restrict__ bsums, int nb) {
    if (blockIdx.x == 0 && threadIdx.x == 0) {
        int acc = 0;
        for (int i = 0; i < nb; ++i) { int v = bsums[i]; bsums[i] = acc; acc += v; }
    }
}

__global__ void scan3_kernel(const int* __restrict__ inc, const int* __restrict__ bsums,
                             int* __restrict__ row_start, int* __restrict__ cursor) {
    int i = blockIdx.x * 256 + threadIdx.x;
    if (i < Nn) {
        int v = inc[i] + bsums[blockIdx.x];
        row_start[i + 1] = v;
        cursor[i + 1] = v;
    }
    if (i == 0) { row_start[0] = 0; cursor[0] = 0; }
}

// writes CSR-ordered src list and CSR-ordered edge attributes
__global__ void scatter_kernel(const int* __restrict__ ei, const float* __restrict__ ea,
                               const float* __restrict__ ea_sum, int* __restrict__ cursor,
                               int* __restrict__ src_sorted, float* __restrict__ ea_sorted) {
    int e = blockIdx.x * blockDim.x + threadIdx.x;
    if (e >= Etot) return;
    int s, d; float e0, e1;
    if (e < Ee) {
        s = ei[e]; d = ei[Ee + e];
        e0 = ea[2 * e]; e1 = ea[2 * e + 1];
    } else {
        s = d = e - Ee;
        const float invE = 1.f / (float)Ee;
        e0 = ea_sum[0] * invE; e1 = ea_sum[1] * invE;
    }
    int pos = atomicAdd(&cursor[d], 1);
    src_sorted[pos] = s;
    ea_sorted[2 * pos]     = e0;
    ea_sorted[2 * pos + 1] = e1;
}

// ---------------------------------------------------------------------------
// Register-tiled GEMM: out[n,256] = in[n,K] @ W[K,256] (+bias)
// 128x128 tile, 256 threads, 8x8 per thread. BF16OUT -> bf16 feature buffer.
// ---------------------------------------------------------------------------
#define BM 128
#define BN 128
#define BK 16
template <bool BF16OUT>
__global__ __launch_bounds__(256) void gemm_kernel(
        const float* __restrict__ in, const float* __restrict__ W,
        const float* __restrict__ bias, void* __restrict__ outp, int n, int K) {
    __shared__ float As[BK][BM];
    __shared__ float Bs[BK][BN];
    const int t  = threadIdx.x;
    const int n0 = blockIdx.x * BM;
    const int c0 = blockIdx.y * BN;
    const int tr = t >> 4;          // 0..15
    const int tc = t & 15;          // 0..15

    const int arow = t & 127;
    const int akq  = t >> 7;        // 0..1

    const int bkk = t >> 5;         // 0..7
    const int bcq = t & 31;         // 0..31

    float acc[8][8];
#pragma unroll
    for (int i = 0; i < 8; ++i)
#pragma unroll
        for (int j = 0; j < 8; ++j) acc[i][j] = 0.f;

    for (int k0 = 0; k0 < K; k0 += BK) {
#pragma unroll
        for (int h = 0; h < 2; ++h) {
            int kq = akq + 2 * h;
            int grow = n0 + arow;
            float4 v = make_float4(0.f, 0.f, 0.f, 0.f);
            if (grow < n) v = *(const float4*)&in[(long)grow * K + k0 + 4 * kq];
            As[4 * kq + 0][arow] = v.x;
            As[4 * kq + 1][arow] = v.y;
            As[4 * kq + 2][arow] = v.z;
            As[4 * kq + 3][arow] = v.w;
        }
#pragma unroll
        for (int h = 0; h < 2; ++h) {
            int kk = bkk + 8 * h;
            *(float4*)&Bs[kk][4 * bcq] = *(const float4*)&W[(long)(k0 + kk) * 256 + c0 + 4 * bcq];
        }
        __syncthreads();
#pragma unroll
        for (int kk = 0; kk < BK; ++kk) {
            float a[8], b[8];
            *(float4*)&a[0] = *(const float4*)&As[kk][4 * tr];
            *(float4*)&a[4] = *(const float4*)&As[kk][64 + 4 * tr];
            *(float4*)&b[0] = *(const float4*)&Bs[kk][4 * tc];
            *(float4*)&b[4] = *(const float4*)&Bs[kk][64 + 4 * tc];
#pragma unroll
            for (int i = 0; i < 8; ++i)
#pragma unroll
                for (int j = 0; j < 8; ++j)
                    acc[i][j] += a[i] * b[j];
        }
        __syncthreads();
    }

    float bb[8];
#pragma unroll
    for (int j = 0; j < 8; ++j) {
        int col = c0 + ((j < 4) ? (4 * tc + j) : (64 + 4 * tc + j - 4));
        bb[j] = bias ? bias[col] : 0.f;
    }
#pragma unroll
    for (int i = 0; i < 8; ++i) {
        int row = n0 + ((i < 4) ? (4 * tr + i) : (64 + 4 * tr + i - 4));
        if (row < n) {
            if constexpr (BF16OUT) {
                ushort16* out = (ushort16*)outp;
                ushort4 lo, hi;
                lo.x = f2bf(acc[i][0] + bb[0]); lo.y = f2bf(acc[i][1] + bb[1]);
                lo.z = f2bf(acc[i][2] + bb[2]); lo.w = f2bf(acc[i][3] + bb[3]);
                hi.x = f2bf(acc[i][4] + bb[4]); hi.y = f2bf(acc[i][5] + bb[5]);
                hi.z = f2bf(acc[i][6] + bb[6]); hi.w = f2bf(acc[i][7] + bb[7]);
                *(ushort4*)&out[(long)row * 256 + c0 + 4 * tc]      = lo;
                *(ushort4*)&out[(long)row * 256 + c0 + 64 + 4 * tc] = hi;
            } else {
                float* out = (float*)outp;
                float4 lo, hi;
                lo.x = acc[i][0] + bb[0]; lo.y = acc[i][1] + bb[1];
                lo.z = acc[i][2] + bb[2]; lo.w = acc[i][3] + bb[3];
                hi.x = acc[i][4] + bb[4]; hi.y = acc[i][5] + bb[5];
                hi.z = acc[i][6] + bb[6]; hi.w = acc[i][7] + bb[7];
                *(float4*)&out[(long)row * 256 + c0 + 4 * tc]      = lo;
                *(float4*)&out[(long)row * 256 + c0 + 64 + 4 * tc] = hi;
            }
        }
    }
}

// ---------------------------------------------------------------------------
// per-node attention terms: ssrc[n,h], sdst[n,h]  (one wave per node, bf16 h)
// ---------------------------------------------------------------------------
__global__ void attn_node_kernel(const ushort16* __restrict__ h, const float* __restrict__ a_s,
                                 const float* __restrict__ a_d, float* __restrict__ ssrc,
                                 float* __restrict__ sdst, int H) {
    int wave = (blockIdx.x * blockDim.x + threadIdx.x) >> 6;
    int lane = threadIdx.x & 63;
    if (wave >= Nn) return;
    int C = 256 / H;
    for (int hh = 0; hh < H; ++hh) {
        float ps = 0.f, pd = 0.f;
        for (int c = lane; c < C; c += 64) {
            float v = bf2f(h[(long)wave * 256 + hh * C + c]);
            ps += v * a_s[hh * C + c];
            pd += v * a_d[hh * C + c];
        }
        for (int off = 32; off > 0; off >>= 1) {
            ps += __shfl_down(ps, off);
            pd += __shfl_down(pd, off);
        }
        if (lane == 0) { ssrc[wave * H + hh] = ps; sdst[wave * H + hh] = pd; }
    }
}

// ---------------------------------------------------------------------------
// fused edge logits + segment softmax, one wave per dst node, CSR order.
// phase1: compute leaky-relu logits, write to w, online (m,den) per lane;
// cross-lane combine; phase2: rewrite w as normalized weights.
// ---------------------------------------------------------------------------
template <int H>
__global__ __launch_bounds__(256) void edge_softmax_kernel(
        const int* __restrict__ src_sorted, const int* __restrict__ row_start,
        const float* __restrict__ ea_sorted, const float* __restrict__ ssrc,
        const float* __restrict__ sdst, const float* __restrict__ M,
        float* __restrict__ w) {
    int node = (blockIdx.x * blockDim.x + threadIdx.x) >> 6;
    int lane = threadIdx.x & 63;
    if (node >= Nn) return;
    int beg = row_start[node], end = row_start[node + 1];
    float sd[H], M0[H], M1[H], m[H], den[H];
#pragma unroll
    for (int h = 0; h < H; ++h) {
        sd[h] = sdst[node * H + h];
        M0[h] = M[h]; M1[h] = M[H + h];
        m[h] = -FLT_MAX; den[h] = 0.f;
    }
    for (int idx = beg + lane; idx < end; idx += 64) {
        int s = src_sorted[idx];
        float e0 = ea_sorted[2 * idx], e1 = ea_sorted[2 * idx + 1];
#pragma unroll
        for (int h = 0; h < H; ++h) {
            float l = ssrc[s * H + h] + sd[h] + e0 * M0[h] + e1 * M1[h];
            l = (l > 0.f) ? l : 0.2f * l;
            w[(long)idx * H + h] = l;
            if (l > m[h]) { den[h] = den[h] * __expf(m[h] - l) + 1.f; m[h] = l; }
            else den[h] += __expf(l - m[h]);
        }
    }
#pragma unroll
    for (int h = 0; h < H; ++h) {
        for (int off = 32; off > 0; off >>= 1) {
            float om = __shfl_down(m[h], off);
            float od = __shfl_down(den[h], off);
            float nm = fmaxf(m[h], om);
            den[h] = den[h] * __expf(m[h] - nm) + od * __expf(om - nm);
            m[h] = nm;
        }
        m[h]   = __shfl(m[h], 0);
        den[h] = __shfl(den[h], 0);
        den[h] = 1.f / (den[h] + 1e-16f);
    }
    for (int idx = beg + lane; idx < end; idx += 64) {
#pragma unroll
        for (int h = 0; h < H; ++h) {
            float l = w[(long)idx * H + h];
            w[(long)idx * H + h] = __expf(l - m[h]) * den[h];
        }
    }
}

// ---------------------------------------------------------------------------
// weighted gather (bf16 features) + bconv + BN + ELU + residual.
// one block of 128 threads per dst node; thread c2 handles channels 2c2,2c2+1
// via one packed bf16x2 (uint) load per edge. 4-way unrolled.
// ---------------------------------------------------------------------------
__global__ __launch_bounds__(128) void agg_kernel(
        const int* __restrict__ src_sorted, const int* __restrict__ row_start,
        const uint32* __restrict__ hbuf2, const float* __restrict__ w,
        const float* __restrict__ bconv,
        const float* __restrict__ bn_g, const float* __restrict__ bn_b,
        const float* __restrict__ bn_m, const float* __restrict__ bn_v,
        const float* __restrict__ identity, float* __restrict__ out, int H) {
    int node = blockIdx.x;
    int c2 = threadIdx.x;            // 0..127
    int C2 = 128 / H;
    int hh = c2 / C2;
    int beg = row_start[node], end = row_start[node + 1];
    float a0 = 0.f, a1 = 0.f;
    for (int idx = beg; idx < end; idx += 4) {
        int   s[4];
        float ww[4];
#pragma unroll
        for (int k = 0; k < 4; ++k) {
            int j = idx + k;
            bool ok = j < end;
            int jj = ok ? j : beg;
            s[k]  = src_sorted[jj];
            ww[k] = ok ? w[(long)jj * H + hh] : 0.f;
        }
#pragma unroll
        for (int k = 0; k < 4; ++k) {
            uint32 u = hbuf2[(long)s[k] * 128 + c2];
            float lo = __uint_as_float(u << 16);
            float hi = __uint_as_float(u & 0xffff0000u);
            a0 += ww[k] * lo;
            a1 += ww[k] * hi;
        }
    }
    int c = 2 * c2;
    float v0 = a0 + bconv[c];
    float v1 = a1 + bconv[c + 1];
    v0 = (v0 - bn_m[c])     * rsqrtf(bn_v[c]     + BN_EPS) * bn_g[c]     + bn_b[c];
    v1 = (v1 - bn_m[c + 1]) * rsqrtf(bn_v[c + 1] + BN_EPS) * bn_g[c + 1] + bn_b[c + 1];
    v0 = (v0 > 0.f) ? v0 : (expf(v0) - 1.f);
    v1 = (v1 > 0.f) ? v1 : (expf(v1) - 1.f);
    float2 id = *(const float2*)&identity[(long)node * 256 + c];
    float2 o;
    o.x = v0 + id.x;
    o.y = v1 + id.y;
    *(float2*)&out[(long)node * 256 + c] = o;
}

// ---------------------------------------------------------------------------
// pooling
// ---------------------------------------------------------------------------
__global__ void pool_init_kernel(float* __restrict__ pmax) {
    int i = blockIdx.x * blockDim.x + threadIdx.x;
    if (i < Gg * 256) pmax[i] = -FLT_MAX;
}

__global__ __launch_bounds__(256) void pool_kernel(
        const float* __restrict__ x, const int* __restrict__ batch,
        float* __restrict__ psum, float* __restrict__ pmax, float* __restrict__ pcnt) {
    int c = threadIdx.x;
    int n0 = blockIdx.x * 256;
    if (n0 >= Nn) return;
    int n1 = min(n0 + 256, Nn);
    int cur = batch[n0];
    float s = 0.f, mx = -FLT_MAX;
    int cnt = 0;
    for (int i = n0; i < n1; ++i) {
        int g = batch[i];
        if (g != cur) {
            atomicAdd(&psum[cur * 256 + c], s);
            atomicMaxFloat(&pmax[cur * 256 + c], mx);
            if (c == 0) atomicAdd(&pcnt[cur], (float)cnt);
            cur = g; s = 0.f; mx = -FLT_MAX; cnt = 0;
        }
        float v = x[(long)i * 256 + c];
        s += v; mx = fmaxf(mx, v); ++cnt;
    }
    atomicAdd(&psum[cur * 256 + c], s);
    atomicMaxFloat(&pmax[cur * 256 + c], mx);
    if (c == 0) atomicAdd(&pcnt[cur], (float)cnt);
}

// ---------------------------------------------------------------------------
// head MLP: relu(emb @ Wp1 + bp1) @ Wp2 + bp2  -> out[g]
// ---------------------------------------------------------------------------
__global__ __launch_bounds__(256) void mlp_kernel(
        const float* __restrict__ psum, const float* __restrict__ pmax,
        const float* __restrict__ pcnt, const float* __restrict__ Wp1,
        const float* __restrict__ bp1, const float* __restrict__ Wp2,
        const float* __restrict__ bp2, float* __restrict__ out) {
    int g = blockIdx.x;
    int j = threadIdx.x;
    float inv = 1.f / fmaxf(pcnt[g], 1.f);
    float acc = bp1[j];
    for (int k = 0; k < 256; ++k)
        acc += (psum[g * 256 + k] * inv) * Wp1[k * 256 + j];
    for (int k = 0; k < 256; ++k)
        acc += pmax[g * 256 + k] * Wp1[(256 + k) * 256 + j];
    float v = fmaxf(acc, 0.f) * Wp2[j];
    __shared__ float red[256];
    red[j] = v;
    __syncthreads();
    for (int off = 128; off > 0; off >>= 1) {
        if (j < off) red[j] += red[j + off];
        __syncthreads();
    }
    if (j == 0) out[g] = red[0] + bp2[0];
}

// ---------------------------------------------------------------------------
// launch
// ---------------------------------------------------------------------------
extern "C" void kernel_launch(void* const* d_in, const int* in_sizes, int n_in,
                              void* d_out, int out_size, void* d_ws, size_t ws_size,
                              hipStream_t stream) {
    const float* x   = (const float*)d_in[0];
    const int*   ei  = (const int*)d_in[1];
    const float* ea  = (const float*)d_in[2];
    const int*   bat = (const int*)d_in[3];
    auto LP = [&](int l, int j) { return (const float*)d_in[4 + l * 10 + j]; };
    const float* Wskip = (const float*)d_in[34];
    const float* bskip = (const float*)d_in[35];
    const float* Wp1   = (const float*)d_in[36];
    const float* bp1   = (const float*)d_in[37];
    const float* Wp2   = (const float*)d_in[38];
    const float* bp2   = (const float*)d_in[39];
    float* out = (float*)d_out;

    // workspace carve-up (256B aligned)
    char* p = (char*)d_ws;
    auto alloc = [&](size_t bytes) { void* r = (void*)p; p += (bytes + 255) & ~(size_t)255; return r; };
    float*  big0   = (float*)alloc((size_t)Nn * 256 * 4);   // xskip / layer1-out
    float*  big1   = (float*)alloc((size_t)Nn * 256 * 4);   // layer0-out / layer2-out
    uint32* hbuf2  = (uint32*)alloc((size_t)Nn * 256 * 2);  // bf16 features [n][256]
    float*  wbuf   = (float*)alloc((size_t)Etot * 4 * 4);   // CSR logits->weights
    float*  ea_sorted = (float*)alloc((size_t)Etot * 2 * 4);
    float*  ssrc   = (float*)alloc((size_t)Nn * 4 * 4);
    float*  sdst   = (float*)alloc((size_t)Nn * 4 * 4);
    int*    counts = (int*)alloc((size_t)Nn * 4);
    int*    incb   = (int*)alloc((size_t)Nn * 4);
    int*    row_start = (int*)alloc((size_t)(Nn + 1) * 4);
    int*    cursor    = (int*)alloc((size_t)(Nn + 1) * 4);
    int*    src_sorted = (int*)alloc((size_t)Etot * 4);
    int*    bsums  = (int*)alloc(256 * 4);
    float*  ea_s   = (float*)alloc(2 * 4);
    float*  Mbuf   = (float*)alloc(32 * 4);
    float*  psum   = (float*)alloc((size_t)Gg * 256 * 4);
    float*  pmax   = (float*)alloc((size_t)Gg * 256 * 4);
    float*  pcnt   = (float*)alloc((size_t)Gg * 4);

    const int nb = (Nn + 255) / 256;
    const int ebks = (Etot + 255) / 256;
    dim3 ggrid((Nn + BM - 1) / BM, 256 / BN);
    const int wgrid = (Nn * 64 + 255) / 256;   // wave-per-node kernels

    // zero init
    hipMemsetAsync(counts, 0, (size_t)Nn * 4, stream);
    hipMemsetAsync(ea_s, 0, 8, stream);
    hipMemsetAsync(psum, 0, (size_t)Gg * 256 * 4, stream);
    hipMemsetAsync(pcnt, 0, (size_t)Gg * 4, stream);

    // edge-attr mean + M
    ea_sum_kernel<<<256, 256, 0, stream>>>(ea, ea_s);
    m_kernel<<<1, 64, 0, stream>>>(LP(0,3), LP(0,4), LP(1,3), LP(1,4), LP(2,3), LP(2,4), Mbuf);

    // CSR (with CSR-ordered edge attrs)
    hist_kernel<<<ebks, 256, 0, stream>>>(ei, counts);
    scan1_kernel<<<nb, 256, 0, stream>>>(counts, incb, bsums);
    scan2_kernel<<<1, 64, 0, stream>>>(bsums, nb);
    scan3_kernel<<<nb, 256, 0, stream>>>(incb, bsums, row_start, cursor);
    scatter_kernel<<<ebks, 256, 0, stream>>>(ei, ea, ea_s, cursor, src_sorted, ea_sorted);

    // skip projection: big0 = x @ Wskip + bskip   (fp32 residual stream)
    gemm_kernel<false><<<ggrid, 256, 0, stream>>>(x, Wskip, bskip, big0, Nn, 128);

    // layers
    const float* lin[3] = { x,    big1, big0 };
    const float* lid[3] = { big0, big1, big0 };
    float*       lou[3] = { big1, big0, big1 };
    const int    Kd[3]  = { 128, 256, 256 };
    const int    Hh[3]  = { 4, 4, 1 };
    for (int l = 0; l < 3; ++l) {
        const int H = Hh[l];
        gemm_kernel<true><<<ggrid, 256, 0, stream>>>(lin[l], LP(l,0), nullptr, hbuf2, Nn, Kd[l]);
        attn_node_kernel<<<wgrid, 256, 0, stream>>>(
            (const ushort16*)hbuf2, LP(l,1), LP(l,2), ssrc, sdst, H);
        if (H == 4)
            edge_softmax_kernel<4><<<wgrid, 256, 0, stream>>>(
                src_sorted, row_start, ea_sorted, ssrc, sdst, Mbuf + l * 8, wbuf);
        else
            edge_softmax_kernel<1><<<wgrid, 256, 0, stream>>>(
                src_sorted, row_start, ea_sorted, ssrc, sdst, Mbuf + l * 8, wbuf);
        agg_kernel<<<Nn, 128, 0, stream>>>(src_sorted, row_start, hbuf2, wbuf,
            LP(l,5), LP(l,6), LP(l,7), LP(l,8), LP(l,9), lid[l], lou[l], H);
    }

    // pooling + head
    pool_init_kernel<<<(Gg * 256 + 255) / 256, 256, 0, stream>>>(pmax);
    pool_kernel<<<nb, 256, 0, stream>>>(big1, bat, psum, pmax, pcnt);
    mlp_kernel<<<Gg, 256, 0, stream>>>(psum, pmax, pcnt, Wp1, bp1, Wp2, bp2, out);
}

// Round 7
// 977.628 us; speedup vs baseline: 2.7795x; 1.1041x over previous
//
#include <hip/hip_runtime.h>
#include <cfloat>

// Problem constants (match reference setup_inputs)
#define Nn 50000
#define Ee 800000
#define Etot (Ee + Nn)   // edges + self loops = 850000
#define Gg 64
#define HIDc 256
#define BN_EPS 1e-5f

typedef unsigned int   uint32;
typedef unsigned short ushort16;
typedef short  bf16x8 __attribute__((ext_vector_type(8)));
typedef float  f32x4  __attribute__((ext_vector_type(4)));

// ---------------------------------------------------------------------------
// small helpers
// ---------------------------------------------------------------------------
__device__ inline void atomicMaxFloat(float* addr, float val) {
    int old = __float_as_int(*addr);
    while (__int_as_float(old) < val) {
        int assumed = old;
        old = atomicCAS((int*)addr, assumed, __float_as_int(val));
        if (old == assumed) break;
    }
}

__device__ inline ushort16 f2bf(float f) {            // RNE fp32 -> bf16
    uint32 u = __float_as_uint(f);
    u = (u + 0x7fffu + ((u >> 16) & 1u)) >> 16;
    return (ushort16)u;
}
__device__ inline float bf2f(ushort16 u) {
    return __uint_as_float(((uint32)u) << 16);
}

// ---------------------------------------------------------------------------
// edge_attr mean (sum, divided later)
// ---------------------------------------------------------------------------
__global__ void ea_sum_kernel(const float* __restrict__ ea, float* __restrict__ out) {
    __shared__ float sh0[256], sh1[256];
    float s0 = 0.f, s1 = 0.f;
    for (int e = blockIdx.x * blockDim.x + threadIdx.x; e < Ee; e += gridDim.x * blockDim.x) {
        s0 += ea[2 * e];
        s1 += ea[2 * e + 1];
    }
    sh0[threadIdx.x] = s0; sh1[threadIdx.x] = s1;
    __syncthreads();
    for (int off = 128; off > 0; off >>= 1) {
        if ((int)threadIdx.x < off) {
            sh0[threadIdx.x] += sh0[threadIdx.x + off];
            sh1[threadIdx.x] += sh1[threadIdx.x + off];
        }
        __syncthreads();
    }
    if (threadIdx.x == 0) { atomicAdd(&out[0], sh0[0]); atomicAdd(&out[1], sh1[0]); }
}

// ---------------------------------------------------------------------------
// M[l][d][h] = sum_c We_l[d, h*C+c] * ae_l[h, c]   (layout M[l*8 + d*H + h])
// ---------------------------------------------------------------------------
__global__ void m_kernel(const float* __restrict__ We0, const float* __restrict__ ae0,
                         const float* __restrict__ We1, const float* __restrict__ ae1,
                         const float* __restrict__ We2, const float* __restrict__ ae2,
                         float* __restrict__ M) {
    int t = threadIdx.x;
    if (t >= 18) return;
    int l = t < 8 ? 0 : (t < 16 ? 1 : 2);
    int r = t - l * 8;
    const float* We = (l == 0) ? We0 : (l == 1 ? We1 : We2);
    const float* ae = (l == 0) ? ae0 : (l == 1 ? ae1 : ae2);
    int Hl = (l < 2) ? 4 : 1;
    int Cl = 256 / Hl;
    int d = r / Hl, hh = r % Hl;
    float s = 0.f;
    for (int c = 0; c < Cl; ++c)
        s += We[d * 256 + hh * Cl + c] * ae[hh * Cl + c];
    M[l * 8 + r] = s;
}

// ---------------------------------------------------------------------------
// weight transpose + bf16 convert: Wt[n][k] = bf16(W[k][n]),  n in [0,256)
// ---------------------------------------------------------------------------
__global__ void wt_kernel(const float* __restrict__ W, ushort16* __restrict__ Wt, int K) {
    int k = blockIdx.x;
    int n = threadIdx.x;
    Wt[(long)n * K + k] = f2bf(W[(long)k * 256 + n]);
}

// x fp32 -> bf16 (flat)
__global__ void cvtx_kernel(const float* __restrict__ x, ushort16* __restrict__ xbf, int total4) {
    int i = blockIdx.x * blockDim.x + threadIdx.x;
    if (i >= total4) return;
    float4 v = *(const float4*)&x[i * 4];
    ushort4 o;
    o.x = f2bf(v.x); o.y = f2bf(v.y); o.z = f2bf(v.z); o.w = f2bf(v.w);
    *(ushort4*)&xbf[i * 4] = o;
}

// ---------------------------------------------------------------------------
// CSR build: histogram -> scan -> scatter (src + CSR-ordered edge attrs)
// ---------------------------------------------------------------------------
__global__ void hist_kernel(const int* __restrict__ ei, int* __restrict__ counts) {
    int e = blockIdx.x * blockDim.x + threadIdx.x;
    if (e >= Etot) return;
    int d = (e < Ee) ? ei[Ee + e] : (e - Ee);
    atomicAdd(&counts[d], 1);
}

__global__ void scan1_kernel(const int* __restrict__ in, int* __restrict__ inc,
                             int* __restrict__ bsums) {
    __shared__ int sh[256];
    int i = blockIdx.x * 256 + threadIdx.x;
    int v = (i < Nn) ? in[i] : 0;
    sh[threadIdx.x] = v;
    __syncthreads();
    for (int off = 1; off < 256; off <<= 1) {
        int t = ((int)threadIdx.x >= off) ? sh[threadIdx.x - off] : 0;
        __syncthreads();
        sh[threadIdx.x] += t;
        __syncthreads();
    }
    if (i < Nn) inc[i] = sh[threadIdx.x];
    if (threadIdx.x == 255) bsums[blockIdx.x] = sh[255];
}

__global__ void scan2_kernel(int* __restrict__ bsums, int nb) {
    if (blockIdx.x == 0 && threadIdx.x == 0) {
        int acc = 0;
        for (int i = 0; i < nb; ++i) { int v = bsums[i]; bsums[i] = acc; acc += v; }
    }
}

__global__ void scan3_kernel(const int* __restrict__ inc, const int* __restrict__ bsums,
                             int* __restrict__ row_start, int* __restrict__ cursor) {
    int i = blockIdx.x * 256 + threadIdx.x;
    if (i < Nn) {
        int v = inc[i] + bsums[blockIdx.x];
        row_start[i + 1] = v;
        cursor[i + 1] = v;
    }
    if (i == 0) { row_start[0] = 0; cursor[0] = 0; }
}

// writes CSR-ordered src list and CSR-ordered edge attributes
__global__ void scatter_kernel(const int* __restrict__ ei, const float* __restrict__ ea,
                               const float* __restrict__ ea_sum, int* __restrict__ cursor,
                               int* __restrict__ src_sorted, float* __restrict__ ea_sorted) {
    int e = blockIdx.x * blockDim.x + threadIdx.x;
    if (e >= Etot) return;
    int s, d; float e0, e1;
    if (e < Ee) {
        s = ei[e]; d = ei[Ee + e];
        e0 = ea[2 * e]; e1 = ea[2 * e + 1];
    } else {
        s = d = e - Ee;
        const float invE = 1.f / (float)Ee;
        e0 = ea_sum[0] * invE; e1 = ea_sum[1] * invE;
    }
    int pos = atomicAdd(&cursor[d], 1);
    src_sorted[pos] = s;
    ea_sorted[2 * pos]     = e0;
    ea_sorted[2 * pos + 1] = e1;
}

// ---------------------------------------------------------------------------
// MFMA bf16 GEMM: out[n,256] = A[n,K](bf16) @ W[K,256] (+bias)
// 128x128 tile / block, 4 waves, each wave a 64x64 sub-tile via 4x4 MFMA
// 16x16x32 frags. A layout [m][k]; B staged n-major [n][k] (from Wt).
// LDS rows padded to 40 bf16 (80 B, 16B-aligned, 2-way bank alias = free).
// ---------------------------------------------------------------------------
#define LDK 40
template <bool BF16OUT>
__global__ __launch_bounds__(256) void mfma_gemm_kernel(
        const ushort16* __restrict__ A,   // [n][K] bf16
        const ushort16* __restrict__ Wt,  // [256][K] bf16 (n-major)
        const float* __restrict__ bias,
        void* __restrict__ outp, int n, int K) {
    __shared__ ushort16 As[128 * LDK];
    __shared__ ushort16 Bs[128 * LDK];
    const int t    = threadIdx.x;
    const int row0 = blockIdx.x * 128;
    const int c0   = blockIdx.y * 128;
    const int wave = t >> 6, lane = t & 63;
    const int wr = wave >> 1, wc = wave & 1;      // wave tile position (2x2)
    const int l15 = lane & 15, quad = lane >> 4;

    f32x4 acc[4][4];
#pragma unroll
    for (int i = 0; i < 4; ++i)
#pragma unroll
        for (int j = 0; j < 4; ++j) {
            acc[i][j][0] = 0.f; acc[i][j][1] = 0.f;
            acc[i][j][2] = 0.f; acc[i][j][3] = 0.f;
        }

    const int sm = t & 127;   // staging row (A) / n (B)
    const int so = t >> 7;    // 0..1

    for (int k0 = 0; k0 < K; k0 += 32) {
#pragma unroll
        for (int h = 0; h < 2; ++h) {
            int oct = so + 2 * h;                 // 0..3 (8 bf16 each)
            int grow = row0 + sm;
            uint4 va = make_uint4(0, 0, 0, 0);
            if (grow < n) va = *(const uint4*)&A[(long)grow * K + k0 + 8 * oct];
            *(uint4*)&As[sm * LDK + 8 * oct] = va;
            *(uint4*)&Bs[sm * LDK + 8 * oct] =
                *(const uint4*)&Wt[(long)(c0 + sm) * K + k0 + 8 * oct];
        }
        __syncthreads();
        bf16x8 af[4], bfv[4];
#pragma unroll
        for (int i = 0; i < 4; ++i) {
            af[i]  = *(const bf16x8*)&As[(wr * 64 + i * 16 + l15) * LDK + quad * 8];
            bfv[i] = *(const bf16x8*)&Bs[(wc * 64 + i * 16 + l15) * LDK + quad * 8];
        }
#pragma unroll
        for (int i = 0; i < 4; ++i)
#pragma unroll
            for (int j = 0; j < 4; ++j)
                acc[i][j] = __builtin_amdgcn_mfma_f32_16x16x32_bf16(
                    af[i], bfv[j], acc[i][j], 0, 0, 0);
        __syncthreads();
    }

    // epilogue: D col = lane&15, row = quad*4 + reg
#pragma unroll
    for (int i = 0; i < 4; ++i) {
#pragma unroll
        for (int j = 0; j < 4; ++j) {
            int col = c0 + wc * 64 + j * 16 + l15;
            float b = bias ? bias[col] : 0.f;
#pragma unroll
            for (int r = 0; r < 4; ++r) {
                int row = row0 + wr * 64 + i * 16 + quad * 4 + r;
                if (row < n) {
                    float v = acc[i][j][r] + b;
                    if constexpr (BF16OUT)
                        ((ushort16*)outp)[(long)row * 256 + col] = f2bf(v);
                    else
                        ((float*)outp)[(long)row * 256 + col] = v;
                }
            }
        }
    }
}

// ---------------------------------------------------------------------------
// per-node attention terms: ssrc[n,h], sdst[n,h]  (one wave per node, bf16 h)
// ---------------------------------------------------------------------------
__global__ void attn_node_kernel(const ushort16* __restrict__ h, const float* __restrict__ a_s,
                                 const float* __restrict__ a_d, float* __restrict__ ssrc,
                                 float* __restrict__ sdst, int H) {
    int wave = (blockIdx.x * blockDim.x + threadIdx.x) >> 6;
    int lane = threadIdx.x & 63;
    if (wave >= Nn) return;
    int C = 256 / H;
    for (int hh = 0; hh < H; ++hh) {
        float ps = 0.f, pd = 0.f;
        for (int c = lane; c < C; c += 64) {
            float v = bf2f(h[(long)wave * 256 + hh * C + c]);
            ps += v * a_s[hh * C + c];
            pd += v * a_d[hh * C + c];
        }
        for (int off = 32; off > 0; off >>= 1) {
            ps += __shfl_down(ps, off);
            pd += __shfl_down(pd, off);
        }
        if (lane == 0) { ssrc[wave * H + hh] = ps; sdst[wave * H + hh] = pd; }
    }
}

// ---------------------------------------------------------------------------
// fused edge logits + segment softmax, one wave per dst node, CSR order.
// ---------------------------------------------------------------------------
template <int H>
__global__ __launch_bounds__(256) void edge_softmax_kernel(
        const int* __restrict__ src_sorted, const int* __restrict__ row_start,
        const float* __restrict__ ea_sorted, const float* __restrict__ ssrc,
        const float* __restrict__ sdst, const float* __restrict__ M,
        float* __restrict__ w) {
    int node = (blockIdx.x * blockDim.x + threadIdx.x) >> 6;
    int lane = threadIdx.x & 63;
    if (node >= Nn) return;
    int beg = row_start[node], end = row_start[node + 1];
    float sd[H], M0[H], M1[H], m[H], den[H];
#pragma unroll
    for (int h = 0; h < H; ++h) {
        sd[h] = sdst[node * H + h];
        M0[h] = M[h]; M1[h] = M[H + h];
        m[h] = -FLT_MAX; den[h] = 0.f;
    }
    for (int idx = beg + lane; idx < end; idx += 64) {
        int s = src_sorted[idx];
        float e0 = ea_sorted[2 * idx], e1 = ea_sorted[2 * idx + 1];
#pragma unroll
        for (int h = 0; h < H; ++h) {
            float l = ssrc[s * H + h] + sd[h] + e0 * M0[h] + e1 * M1[h];
            l = (l > 0.f) ? l : 0.2f * l;
            w[(long)idx * H + h] = l;
            if (l > m[h]) { den[h] = den[h] * __expf(m[h] - l) + 1.f; m[h] = l; }
            else den[h] += __expf(l - m[h]);
        }
    }
#pragma unroll
    for (int h = 0; h < H; ++h) {
        for (int off = 32; off > 0; off >>= 1) {
            float om = __shfl_down(m[h], off);
            float od = __shfl_down(den[h], off);
            float nm = fmaxf(m[h], om);
            den[h] = den[h] * __expf(m[h] - nm) + od * __expf(om - nm);
            m[h] = nm;
        }
        m[h]   = __shfl(m[h], 0);
        den[h] = __shfl(den[h], 0);
        den[h] = 1.f / (den[h] + 1e-16f);
    }
    for (int idx = beg + lane; idx < end; idx += 64) {
#pragma unroll
        for (int h = 0; h < H; ++h) {
            float l = w[(long)idx * H + h];
            w[(long)idx * H + h] = __expf(l - m[h]) * den[h];
        }
    }
}

// ---------------------------------------------------------------------------
// weighted gather (bf16 features) + bconv + BN + ELU + residual.
// 128 threads/node; thread c2 handles channels 2c2,2c2+1 (packed bf16x2).
// also emits a packed-bf16 copy of the residual output (next layer's GEMM A).
// ---------------------------------------------------------------------------
__global__ __launch_bounds__(128) void agg_kernel(
        const int* __restrict__ src_sorted, const int* __restrict__ row_start,
        const uint32* __restrict__ hbuf2, const float* __restrict__ w,
        const float* __restrict__ bconv,
        const float* __restrict__ bn_g, const float* __restrict__ bn_b,
        const float* __restrict__ bn_m, const float* __restrict__ bn_v,
        const float* __restrict__ identity, float* __restrict__ out,
        uint32* __restrict__ out_bf2, int H) {
    int node = blockIdx.x;
    int c2 = threadIdx.x;            // 0..127
    int C2 = 128 / H;
    int hh = c2 / C2;
    int beg = row_start[node], end = row_start[node + 1];
    float a0 = 0.f, a1 = 0.f;
    for (int idx = beg; idx < end; idx += 4) {
        int   s[4];
        float ww[4];
#pragma unroll
        for (int k = 0; k < 4; ++k) {
            int j = idx + k;
            bool ok = j < end;
            int jj = ok ? j : beg;
            s[k]  = src_sorted[jj];
            ww[k] = ok ? w[(long)jj * H + hh] : 0.f;
        }
#pragma unroll
        for (int k = 0; k < 4; ++k) {
            uint32 u = hbuf2[(long)s[k] * 128 + c2];
            float lo = __uint_as_float(u << 16);
            float hi = __uint_as_float(u & 0xffff0000u);
            a0 += ww[k] * lo;
            a1 += ww[k] * hi;
        }
    }
    int c = 2 * c2;
    float v0 = a0 + bconv[c];
    float v1 = a1 + bconv[c + 1];
    v0 = (v0 - bn_m[c])     * rsqrtf(bn_v[c]     + BN_EPS) * bn_g[c]     + bn_b[c];
    v1 = (v1 - bn_m[c + 1]) * rsqrtf(bn_v[c + 1] + BN_EPS) * bn_g[c + 1] + bn_b[c + 1];
    v0 = (v0 > 0.f) ? v0 : (expf(v0) - 1.f);
    v1 = (v1 > 0.f) ? v1 : (expf(v1) - 1.f);
    float2 id = *(const float2*)&identity[(long)node * 256 + c];
    float2 o;
    o.x = v0 + id.x;
    o.y = v1 + id.y;
    *(float2*)&out[(long)node * 256 + c] = o;
    out_bf2[(long)node * 128 + c2] = (uint32)f2bf(o.x) | ((uint32)f2bf(o.y) << 16);
}

// ---------------------------------------------------------------------------
// pooling
// ---------------------------------------------------------------------------
__global__ void pool_init_kernel(float* __restrict__ pmax) {
    int i = blockIdx.x * blockDim.x + threadIdx.x;
    if (i < Gg * 256) pmax[i] = -FLT_MAX;
}

__global__ __launch_bounds__(256) void pool_kernel(
        const float* __restrict__ x, const int* __restrict__ batch,
        float* __restrict__ psum, float* __restrict__ pmax, float* __restrict__ pcnt) {
    int c = threadIdx.x;
    int n0 = blockIdx.x * 256;
    if (n0 >= Nn) return;
    int n1 = min(n0 + 256, Nn);
    int cur = batch[n0];
    float s = 0.f, mx = -FLT_MAX;
    int cnt = 0;
    for (int i = n0; i < n1; ++i) {
        int g = batch[i];
        if (g != cur) {
            atomicAdd(&psum[cur * 256 + c], s);
            atomicMaxFloat(&pmax[cur * 256 + c], mx);
            if (c == 0) atomicAdd(&pcnt[cur], (float)cnt);
            cur = g; s = 0.f; mx = -FLT_MAX; cnt = 0;
        }
        float v = x[(long)i * 256 + c];
        s += v; mx = fmaxf(mx, v); ++cnt;
    }
    atomicAdd(&psum[cur * 256 + c], s);
    atomicMaxFloat(&pmax[cur * 256 + c], mx);
    if (c == 0) atomicAdd(&pcnt[cur], (float)cnt);
}

// ---------------------------------------------------------------------------
// head MLP: relu(emb @ Wp1 + bp1) @ Wp2 + bp2  -> out[g]
// ---------------------------------------------------------------------------
__global__ __launch_bounds__(256) void mlp_kernel(
        const float* __restrict__ psum, const float* __restrict__ pmax,
        const float* __restrict__ pcnt, const float* __restrict__ Wp1,
        const float* __restrict__ bp1, const float* __restrict__ Wp2,
        const float* __restrict__ bp2, float* __restrict__ out) {
    int g = blockIdx.x;
    int j = threadIdx.x;
    float inv = 1.f / fmaxf(pcnt[g], 1.f);
    float acc = bp1[j];
    for (int k = 0; k < 256; ++k)
        acc += (psum[g * 256 + k] * inv) * Wp1[k * 256 + j];
    for (int k = 0; k < 256; ++k)
        acc += pmax[g * 256 + k] * Wp1[(256 + k) * 256 + j];
    float v = fmaxf(acc, 0.f) * Wp2[j];
    __shared__ float red[256];
    red[j] = v;
    __syncthreads();
    for (int off = 128; off > 0; off >>= 1) {
        if (j < off) red[j] += red[j + off];
        __syncthreads();
    }
    if (j == 0) out[g] = red[0] + bp2[0];
}

// ---------------------------------------------------------------------------
// launch
// ---------------------------------------------------------------------------
extern "C" void kernel_launch(void* const* d_in, const int* in_sizes, int n_in,
                              void* d_out, int out_size, void* d_ws, size_t ws_size,
                              hipStream_t stream) {
    const float* x   = (const float*)d_in[0];
    const int*   ei  = (const int*)d_in[1];
    const float* ea  = (const float*)d_in[2];
    const int*   bat = (const int*)d_in[3];
    auto LP = [&](int l, int j) { return (const float*)d_in[4 + l * 10 + j]; };
    const float* Wskip = (const float*)d_in[34];
    const float* bskip = (const float*)d_in[35];
    const float* Wp1   = (const float*)d_in[36];
    const float* bp1   = (const float*)d_in[37];
    const float* Wp2   = (const float*)d_in[38];
    const float* bp2   = (const float*)d_in[39];
    float* out = (float*)d_out;

    // workspace carve-up (256B aligned)
    char* p = (char*)d_ws;
    auto alloc = [&](size_t bytes) { void* r = (void*)p; p += (bytes + 255) & ~(size_t)255; return r; };
    float*    big0   = (float*)alloc((size_t)Nn * 256 * 4);   // xskip / layer1-out
    float*    big1   = (float*)alloc((size_t)Nn * 256 * 4);   // layer0-out / layer2-out
    uint32*   hbuf2  = (uint32*)alloc((size_t)Nn * 256 * 2);  // bf16 features [n][256]
    ushort16* xbf    = (ushort16*)alloc((size_t)Nn * 128 * 2);  // bf16 x [n][128]
    uint32*   xresbf = (uint32*)alloc((size_t)Nn * 128 * 4);    // bf16 residual [n][256] packed
    float*    wbuf   = (float*)alloc((size_t)Etot * 4 * 4);   // CSR logits->weights
    float*    ea_sorted = (float*)alloc((size_t)Etot * 2 * 4);
    float*    ssrc   = (float*)alloc((size_t)Nn * 4 * 4);
    float*    sdst   = (float*)alloc((size_t)Nn * 4 * 4);
    int*      counts = (int*)alloc((size_t)Nn * 4);
    int*      incb   = (int*)alloc((size_t)Nn * 4);
    int*      row_start = (int*)alloc((size_t)(Nn + 1) * 4);
    int*      cursor    = (int*)alloc((size_t)(Nn + 1) * 4);
    int*      src_sorted = (int*)alloc((size_t)Etot * 4);
    int*      bsums  = (int*)alloc(256 * 4);
    float*    ea_s   = (float*)alloc(2 * 4);
    float*    Mbuf   = (float*)alloc(32 * 4);
    ushort16* Wt0    = (ushort16*)alloc((size_t)256 * 128 * 2);
    ushort16* Wt1    = (ushort16*)alloc((size_t)256 * 256 * 2);
    ushort16* Wt2    = (ushort16*)alloc((size_t)256 * 256 * 2);
    ushort16* Wts    = (ushort16*)alloc((size_t)256 * 128 * 2);
    float*    psum   = (float*)alloc((size_t)Gg * 256 * 4);
    float*    pmax   = (float*)alloc((size_t)Gg * 256 * 4);
    float*    pcnt   = (float*)alloc((size_t)Gg * 4);

    const int nb = (Nn + 255) / 256;
    const int ebks = (Etot + 255) / 256;
    dim3 ggrid((Nn + 127) / 128, 2);
    const int wgrid = (Nn * 64 + 255) / 256;   // wave-per-node kernels

    // zero init
    hipMemsetAsync(counts, 0, (size_t)Nn * 4, stream);
    hipMemsetAsync(ea_s, 0, 8, stream);
    hipMemsetAsync(psum, 0, (size_t)Gg * 256 * 4, stream);
    hipMemsetAsync(pcnt, 0, (size_t)Gg * 4, stream);

    // edge-attr mean + M + weight prep + x conversion
    ea_sum_kernel<<<256, 256, 0, stream>>>(ea, ea_s);
    m_kernel<<<1, 64, 0, stream>>>(LP(0,3), LP(0,4), LP(1,3), LP(1,4), LP(2,3), LP(2,4), Mbuf);
    wt_kernel<<<128, 256, 0, stream>>>(LP(0,0), Wt0, 128);
    wt_kernel<<<256, 256, 0, stream>>>(LP(1,0), Wt1, 256);
    wt_kernel<<<256, 256, 0, stream>>>(LP(2,0), Wt2, 256);
    wt_kernel<<<128, 256, 0, stream>>>(Wskip, Wts, 128);
    cvtx_kernel<<<(Nn * 128 / 4 + 255) / 256, 256, 0, stream>>>(x, xbf, Nn * 128 / 4);

    // CSR (with CSR-ordered edge attrs)
    hist_kernel<<<ebks, 256, 0, stream>>>(ei, counts);
    scan1_kernel<<<nb, 256, 0, stream>>>(counts, incb, bsums);
    scan2_kernel<<<1, 64, 0, stream>>>(bsums, nb);
    scan3_kernel<<<nb, 256, 0, stream>>>(incb, bsums, row_start, cursor);
    scatter_kernel<<<ebks, 256, 0, stream>>>(ei, ea, ea_s, cursor, src_sorted, ea_sorted);

    // skip projection: big0 = x @ Wskip + bskip   (fp32 residual stream)
    mfma_gemm_kernel<false><<<ggrid, 256, 0, stream>>>(xbf, Wts, bskip, big0, Nn, 128);

    // layers
    const float* lid[3] = { big0, big1, big0 };
    float*       lou[3] = { big1, big0, big1 };
    const int    Kd[3]  = { 128, 256, 256 };
    const int    Hh[3]  = { 4, 4, 1 };
    const ushort16* lain[3] = { xbf, (ushort16*)xresbf, (ushort16*)xresbf };
    const ushort16* lwt[3]  = { Wt0, Wt1, Wt2 };
    for (int l = 0; l < 3; ++l) {
        const int H = Hh[l];
        mfma_gemm_kernel<true><<<ggrid, 256, 0, stream>>>(
            lain[l], lwt[l], nullptr, hbuf2, Nn, Kd[l]);
        attn_node_kernel<<<wgrid, 256, 0, stream>>>(
            (const ushort16*)hbuf2, LP(l,1), LP(l,2), ssrc, sdst, H);
        if (H == 4)
            edge_softmax_kernel<4><<<wgrid, 256, 0, stream>>>(
                src_sorted, row_start, ea_sorted, ssrc, sdst, Mbuf + l * 8, wbuf);
        else
            edge_softmax_kernel<1><<<wgrid, 256, 0, stream>>>(
                src_sorted, row_start, ea_sorted, ssrc, sdst, Mbuf + l * 8, wbuf);
        agg_kernel<<<Nn, 128, 0, stream>>>(src_sorted, row_start, hbuf2, wbuf,
            LP(l,5), LP(l,6), LP(l,7), LP(l,8), LP(l,9), lid[l], lou[l], xresbf, H);
    }

    // pooling + head
    pool_init_kernel<<<(Gg * 256 + 255) / 256, 256, 0, stream>>>(pmax);
    pool_kernel<<<nb, 256, 0, stream>>>(big1, bat, psum, pmax, pcnt);
    mlp_kernel<<<Gg, 256, 0, stream>>>(psum, pmax, pcnt, Wp1, bp1, Wp2, bp2, out);
}

// Round 8
// 890.777 us; speedup vs baseline: 3.0505x; 1.0975x over previous
//
#include <hip/hip_runtime.h>
#include <cfloat>

// Problem constants (match reference setup_inputs)
#define Nn 50000
#define Ee 800000
#define Etot (Ee + Nn)   // edges + self loops = 850000
#define Gg 64
#define HIDc 256
#define BN_EPS 1e-5f

typedef unsigned int   uint32;
typedef unsigned short ushort16;
typedef short  bf16x8 __attribute__((ext_vector_type(8)));
typedef float  f32x4  __attribute__((ext_vector_type(4)));

// ---------------------------------------------------------------------------
// small helpers
// ---------------------------------------------------------------------------
__device__ inline void atomicMaxFloat(float* addr, float val) {
    int old = __float_as_int(*addr);
    while (__int_as_float(old) < val) {
        int assumed = old;
        old = atomicCAS((int*)addr, assumed, __float_as_int(val));
        if (old == assumed) break;
    }
}

__device__ inline ushort16 f2bf(float f) {            // RNE fp32 -> bf16
    uint32 u = __float_as_uint(f);
    u = (u + 0x7fffu + ((u >> 16) & 1u)) >> 16;
    return (ushort16)u;
}
__device__ inline float bf2f(ushort16 u) {
    return __uint_as_float(((uint32)u) << 16);
}

// ---------------------------------------------------------------------------
// edge_attr mean (sum, divided later)
// ---------------------------------------------------------------------------
__global__ void ea_sum_kernel(const float* __restrict__ ea, float* __restrict__ out) {
    __shared__ float sh0[256], sh1[256];
    float s0 = 0.f, s1 = 0.f;
    for (int e = blockIdx.x * blockDim.x + threadIdx.x; e < Ee; e += gridDim.x * blockDim.x) {
        s0 += ea[2 * e];
        s1 += ea[2 * e + 1];
    }
    sh0[threadIdx.x] = s0; sh1[threadIdx.x] = s1;
    __syncthreads();
    for (int off = 128; off > 0; off >>= 1) {
        if ((int)threadIdx.x < off) {
            sh0[threadIdx.x] += sh0[threadIdx.x + off];
            sh1[threadIdx.x] += sh1[threadIdx.x + off];
        }
        __syncthreads();
    }
    if (threadIdx.x == 0) { atomicAdd(&out[0], sh0[0]); atomicAdd(&out[1], sh1[0]); }
}

// ---------------------------------------------------------------------------
// M[l][d][h] = sum_c We_l[d, h*C+c] * ae_l[h, c]   (layout M[l*8 + d*H + h])
// ---------------------------------------------------------------------------
__global__ void m_kernel(const float* __restrict__ We0, const float* __restrict__ ae0,
                         const float* __restrict__ We1, const float* __restrict__ ae1,
                         const float* __restrict__ We2, const float* __restrict__ ae2,
                         float* __restrict__ M) {
    int t = threadIdx.x;
    if (t >= 18) return;
    int l = t < 8 ? 0 : (t < 16 ? 1 : 2);
    int r = t - l * 8;
    const float* We = (l == 0) ? We0 : (l == 1 ? We1 : We2);
    const float* ae = (l == 0) ? ae0 : (l == 1 ? ae1 : ae2);
    int Hl = (l < 2) ? 4 : 1;
    int Cl = 256 / Hl;
    int d = r / Hl, hh = r % Hl;
    float s = 0.f;
    for (int c = 0; c < Cl; ++c)
        s += We[d * 256 + hh * Cl + c] * ae[hh * Cl + c];
    M[l * 8 + r] = s;
}

// ---------------------------------------------------------------------------
// weight transpose + bf16 convert: Wt[n][k] = bf16(W[k][n]),  n in [0,256)
// ---------------------------------------------------------------------------
__global__ void wt_kernel(const float* __restrict__ W, ushort16* __restrict__ Wt, int K) {
    int k = blockIdx.x;
    int n = threadIdx.x;
    Wt[(long)n * K + k] = f2bf(W[(long)k * 256 + n]);
}

// x fp32 -> bf16 (flat)
__global__ void cvtx_kernel(const float* __restrict__ x, ushort16* __restrict__ xbf, int total4) {
    int i = blockIdx.x * blockDim.x + threadIdx.x;
    if (i >= total4) return;
    float4 v = *(const float4*)&x[i * 4];
    ushort4 o;
    o.x = f2bf(v.x); o.y = f2bf(v.y); o.z = f2bf(v.z); o.w = f2bf(v.w);
    *(ushort4*)&xbf[i * 4] = o;
}

// ---------------------------------------------------------------------------
// CSR build: histogram -> scan -> scatter (src + CSR-ordered edge attrs)
// ---------------------------------------------------------------------------
__global__ void hist_kernel(const int* __restrict__ ei, int* __restrict__ counts) {
    int e = blockIdx.x * blockDim.x + threadIdx.x;
    if (e >= Etot) return;
    int d = (e < Ee) ? ei[Ee + e] : (e - Ee);
    atomicAdd(&counts[d], 1);
}

__global__ void scan1_kernel(const int* __restrict__ in, int* __restrict__ inc,
                             int* __restrict__ bsums) {
    __shared__ int sh[256];
    int i = blockIdx.x * 256 + threadIdx.x;
    int v = (i < Nn) ? in[i] : 0;
    sh[threadIdx.x] = v;
    __syncthreads();
    for (int off = 1; off < 256; off <<= 1) {
        int t = ((int)threadIdx.x >= off) ? sh[threadIdx.x - off] : 0;
        __syncthreads();
        sh[threadIdx.x] += t;
        __syncthreads();
    }
    if (i < Nn) inc[i] = sh[threadIdx.x];
    if (threadIdx.x == 255) bsums[blockIdx.x] = sh[255];
}

__global__ void scan2_kernel(int* __restrict__ bsums, int nb) {
    if (blockIdx.x == 0 && threadIdx.x == 0) {
        int acc = 0;
        for (int i = 0; i < nb; ++i) { int v = bsums[i]; bsums[i] = acc; acc += v; }
    }
}

__global__ void scan3_kernel(const int* __restrict__ inc, const int* __restrict__ bsums,
                             int* __restrict__ row_start, int* __restrict__ cursor) {
    int i = blockIdx.x * 256 + threadIdx.x;
    if (i < Nn) {
        int v = inc[i] + bsums[blockIdx.x];
        row_start[i + 1] = v;
        cursor[i + 1] = v;
    }
    if (i == 0) { row_start[0] = 0; cursor[0] = 0; }
}

// writes CSR-ordered src list and CSR-ordered edge attributes
__global__ void scatter_kernel(const int* __restrict__ ei, const float* __restrict__ ea,
                               const float* __restrict__ ea_sum, int* __restrict__ cursor,
                               int* __restrict__ src_sorted, float* __restrict__ ea_sorted) {
    int e = blockIdx.x * blockDim.x + threadIdx.x;
    if (e >= Etot) return;
    int s, d; float e0, e1;
    if (e < Ee) {
        s = ei[e]; d = ei[Ee + e];
        e0 = ea[2 * e]; e1 = ea[2 * e + 1];
    } else {
        s = d = e - Ee;
        const float invE = 1.f / (float)Ee;
        e0 = ea_sum[0] * invE; e1 = ea_sum[1] * invE;
    }
    int pos = atomicAdd(&cursor[d], 1);
    src_sorted[pos] = s;
    ea_sorted[2 * pos]     = e0;
    ea_sorted[2 * pos + 1] = e1;
}

// ---------------------------------------------------------------------------
// MFMA bf16 GEMM: out[n,256] = A[n,K](bf16) @ W[K,256] (+bias), bf16 out
// 128x128 tile / block, 4 waves, each wave a 64x64 sub-tile via 4x4 MFMA
// 16x16x32 frags. LDS rows padded to 40 bf16.
// ---------------------------------------------------------------------------
#define LDK 40
__global__ __launch_bounds__(256) void mfma_gemm_kernel(
        const ushort16* __restrict__ A,   // [n][K] bf16
        const ushort16* __restrict__ Wt,  // [256][K] bf16 (n-major)
        const float* __restrict__ bias,
        ushort16* __restrict__ outp, int n, int K) {
    __shared__ ushort16 As[128 * LDK];
    __shared__ ushort16 Bs[128 * LDK];
    const int t    = threadIdx.x;
    const int row0 = blockIdx.x * 128;
    const int c0   = blockIdx.y * 128;
    const int wave = t >> 6, lane = t & 63;
    const int wr = wave >> 1, wc = wave & 1;      // wave tile position (2x2)
    const int l15 = lane & 15, quad = lane >> 4;

    f32x4 acc[4][4];
#pragma unroll
    for (int i = 0; i < 4; ++i)
#pragma unroll
        for (int j = 0; j < 4; ++j) {
            acc[i][j][0] = 0.f; acc[i][j][1] = 0.f;
            acc[i][j][2] = 0.f; acc[i][j][3] = 0.f;
        }

    const int sm = t & 127;   // staging row (A) / n (B)
    const int so = t >> 7;    // 0..1

    for (int k0 = 0; k0 < K; k0 += 32) {
#pragma unroll
        for (int h = 0; h < 2; ++h) {
            int oct = so + 2 * h;                 // 0..3 (8 bf16 each)
            int grow = row0 + sm;
            uint4 va = make_uint4(0, 0, 0, 0);
            if (grow < n) va = *(const uint4*)&A[(long)grow * K + k0 + 8 * oct];
            *(uint4*)&As[sm * LDK + 8 * oct] = va;
            *(uint4*)&Bs[sm * LDK + 8 * oct] =
                *(const uint4*)&Wt[(long)(c0 + sm) * K + k0 + 8 * oct];
        }
        __syncthreads();
        bf16x8 af[4], bfv[4];
#pragma unroll
        for (int i = 0; i < 4; ++i) {
            af[i]  = *(const bf16x8*)&As[(wr * 64 + i * 16 + l15) * LDK + quad * 8];
            bfv[i] = *(const bf16x8*)&Bs[(wc * 64 + i * 16 + l15) * LDK + quad * 8];
        }
#pragma unroll
        for (int i = 0; i < 4; ++i)
#pragma unroll
            for (int j = 0; j < 4; ++j)
                acc[i][j] = __builtin_amdgcn_mfma_f32_16x16x32_bf16(
                    af[i], bfv[j], acc[i][j], 0, 0, 0);
        __syncthreads();
    }

    // epilogue: D col = lane&15, row = quad*4 + reg
#pragma unroll
    for (int i = 0; i < 4; ++i) {
#pragma unroll
        for (int j = 0; j < 4; ++j) {
            int col = c0 + wc * 64 + j * 16 + l15;
            float b = bias ? bias[col] : 0.f;
#pragma unroll
            for (int r = 0; r < 4; ++r) {
                int row = row0 + wr * 64 + i * 16 + quad * 4 + r;
                if (row < n)
                    outp[(long)row * 256 + col] = f2bf(acc[i][j][r] + b);
            }
        }
    }
}

// ---------------------------------------------------------------------------
// per-node attention terms: ssrc[n,h], sdst[n,h]  (one wave per node, bf16 h)
// ---------------------------------------------------------------------------
__global__ void attn_node_kernel(const ushort16* __restrict__ h, const float* __restrict__ a_s,
                                 const float* __restrict__ a_d, float* __restrict__ ssrc,
                                 float* __restrict__ sdst, int H) {
    int wave = (blockIdx.x * blockDim.x + threadIdx.x) >> 6;
    int lane = threadIdx.x & 63;
    if (wave >= Nn) return;
    int C = 256 / H;
    for (int hh = 0; hh < H; ++hh) {
        float ps = 0.f, pd = 0.f;
        for (int c = lane; c < C; c += 64) {
            float v = bf2f(h[(long)wave * 256 + hh * C + c]);
            ps += v * a_s[hh * C + c];
            pd += v * a_d[hh * C + c];
        }
        for (int off = 32; off > 0; off >>= 1) {
            ps += __shfl_down(ps, off);
            pd += __shfl_down(pd, off);
        }
        if (lane == 0) { ssrc[wave * H + hh] = ps; sdst[wave * H + hh] = pd; }
    }
}

// ---------------------------------------------------------------------------
// fused edge logits + segment softmax, one wave per dst node, CSR order.
// ---------------------------------------------------------------------------
template <int H>
__global__ __launch_bounds__(256) void edge_softmax_kernel(
        const int* __restrict__ src_sorted, const int* __restrict__ row_start,
        const float* __restrict__ ea_sorted, const float* __restrict__ ssrc,
        const float* __restrict__ sdst, const float* __restrict__ M,
        float* __restrict__ w) {
    int node = (blockIdx.x * blockDim.x + threadIdx.x) >> 6;
    int lane = threadIdx.x & 63;
    if (node >= Nn) return;
    int beg = row_start[node], end = row_start[node + 1];
    float sd[H], M0[H], M1[H], m[H], den[H];
#pragma unroll
    for (int h = 0; h < H; ++h) {
        sd[h] = sdst[node * H + h];
        M0[h] = M[h]; M1[h] = M[H + h];
        m[h] = -FLT_MAX; den[h] = 0.f;
    }
    for (int idx = beg + lane; idx < end; idx += 64) {
        int s = src_sorted[idx];
        float e0 = ea_sorted[2 * idx], e1 = ea_sorted[2 * idx + 1];
#pragma unroll
        for (int h = 0; h < H; ++h) {
            float l = ssrc[s * H + h] + sd[h] + e0 * M0[h] + e1 * M1[h];
            l = (l > 0.f) ? l : 0.2f * l;
            w[(long)idx * H + h] = l;
            if (l > m[h]) { den[h] = den[h] * __expf(m[h] - l) + 1.f; m[h] = l; }
            else den[h] += __expf(l - m[h]);
        }
    }
#pragma unroll
    for (int h = 0; h < H; ++h) {
        for (int off = 32; off > 0; off >>= 1) {
            float om = __shfl_down(m[h], off);
            float od = __shfl_down(den[h], off);
            float nm = fmaxf(m[h], om);
            den[h] = den[h] * __expf(m[h] - nm) + od * __expf(om - nm);
            m[h] = nm;
        }
        m[h]   = __shfl(m[h], 0);
        den[h] = __shfl(den[h], 0);
        den[h] = 1.f / (den[h] + 1e-16f);
    }
    for (int idx = beg + lane; idx < end; idx += 64) {
#pragma unroll
        for (int h = 0; h < H; ++h) {
            float l = w[(long)idx * H + h];
            w[(long)idx * H + h] = __expf(l - m[h]) * den[h];
        }
    }
}

// ---------------------------------------------------------------------------
// weighted gather (bf16 features) + bconv + BN + ELU + residual(bf16).
// 128 threads/node; thread c2 handles channels 2c2,2c2+1 (packed bf16x2).
// identity and output are both packed-bf16 residual streams.
// ---------------------------------------------------------------------------
__global__ __launch_bounds__(128) void agg_kernel(
        const int* __restrict__ src_sorted, const int* __restrict__ row_start,
        const uint32* __restrict__ hbuf2, const float* __restrict__ w,
        const float* __restrict__ bconv,
        const float* __restrict__ bn_g, const float* __restrict__ bn_b,
        const float* __restrict__ bn_m, const float* __restrict__ bn_v,
        const uint32* __restrict__ identity2, uint32* __restrict__ out2, int H) {
    int node = blockIdx.x;
    int c2 = threadIdx.x;            // 0..127
    int C2 = 128 / H;
    int hh = c2 / C2;
    int beg = row_start[node], end = row_start[node + 1];
    float a0 = 0.f, a1 = 0.f;
    for (int idx = beg; idx < end; idx += 4) {
        int   s[4];
        float ww[4];
#pragma unroll
        for (int k = 0; k < 4; ++k) {
            int j = idx + k;
            bool ok = j < end;
            int jj = ok ? j : beg;
            s[k]  = src_sorted[jj];
            ww[k] = ok ? w[(long)jj * H + hh] : 0.f;
        }
#pragma unroll
        for (int k = 0; k < 4; ++k) {
            uint32 u = hbuf2[(long)s[k] * 128 + c2];
            float lo = __uint_as_float(u << 16);
            float hi = __uint_as_float(u & 0xffff0000u);
            a0 += ww[k] * lo;
            a1 += ww[k] * hi;
        }
    }
    int c = 2 * c2;
    float v0 = a0 + bconv[c];
    float v1 = a1 + bconv[c + 1];
    v0 = (v0 - bn_m[c])     * rsqrtf(bn_v[c]     + BN_EPS) * bn_g[c]     + bn_b[c];
    v1 = (v1 - bn_m[c + 1]) * rsqrtf(bn_v[c + 1] + BN_EPS) * bn_g[c + 1] + bn_b[c + 1];
    v0 = (v0 > 0.f) ? v0 : (expf(v0) - 1.f);
    v1 = (v1 > 0.f) ? v1 : (expf(v1) - 1.f);
    uint32 idu = identity2[(long)node * 128 + c2];
    v0 += __uint_as_float(idu << 16);
    v1 += __uint_as_float(idu & 0xffff0000u);
    out2[(long)node * 128 + c2] = (uint32)f2bf(v0) | ((uint32)f2bf(v1) << 16);
}

// ---------------------------------------------------------------------------
// pooling (bf16 input, 32 rows/block, 128 threads = 2 channels each)
// ---------------------------------------------------------------------------
#define POOL_ROWS 32
__global__ void pool_init_kernel(float* __restrict__ pmax) {
    int i = blockIdx.x * blockDim.x + threadIdx.x;
    if (i < Gg * 256) pmax[i] = -FLT_MAX;
}

__global__ __launch_bounds__(128) void pool_kernel(
        const uint32* __restrict__ x2, const int* __restrict__ batch,
        float* __restrict__ psum, float* __restrict__ pmax, float* __restrict__ pcnt) {
    int c2 = threadIdx.x;
    int n0 = blockIdx.x * POOL_ROWS;
    if (n0 >= Nn) return;
    int n1 = min(n0 + POOL_ROWS, Nn);
    int cur = batch[n0];
    float s0 = 0.f, s1 = 0.f, m0 = -FLT_MAX, m1 = -FLT_MAX;
    int cnt = 0;
    int c = 2 * c2;
    for (int i = n0; i < n1; ++i) {
        int g = batch[i];
        if (g != cur) {
            atomicAdd(&psum[cur * 256 + c], s0);
            atomicAdd(&psum[cur * 256 + c + 1], s1);
            atomicMaxFloat(&pmax[cur * 256 + c], m0);
            atomicMaxFloat(&pmax[cur * 256 + c + 1], m1);
            if (c2 == 0) atomicAdd(&pcnt[cur], (float)cnt);
            cur = g; s0 = s1 = 0.f; m0 = m1 = -FLT_MAX; cnt = 0;
        }
        uint32 u = x2[(long)i * 128 + c2];
        float lo = __uint_as_float(u << 16);
        float hi = __uint_as_float(u & 0xffff0000u);
        s0 += lo; s1 += hi;
        m0 = fmaxf(m0, lo); m1 = fmaxf(m1, hi);
        ++cnt;
    }
    atomicAdd(&psum[cur * 256 + c], s0);
    atomicAdd(&psum[cur * 256 + c + 1], s1);
    atomicMaxFloat(&pmax[cur * 256 + c], m0);
    atomicMaxFloat(&pmax[cur * 256 + c + 1], m1);
    if (c2 == 0) atomicAdd(&pcnt[cur], (float)cnt);
}

// ---------------------------------------------------------------------------
// head MLP: relu(emb @ Wp1 + bp1) @ Wp2 + bp2  -> out[g]
// ---------------------------------------------------------------------------
__global__ __launch_bounds__(256) void mlp_kernel(
        const float* __restrict__ psum, const float* __restrict__ pmax,
        const float* __restrict__ pcnt, const float* __restrict__ Wp1,
        const float* __restrict__ bp1, const float* __restrict__ Wp2,
        const float* __restrict__ bp2, float* __restrict__ out) {
    int g = blockIdx.x;
    int j = threadIdx.x;
    float inv = 1.f / fmaxf(pcnt[g], 1.f);
    float acc = bp1[j];
    for (int k = 0; k < 256; ++k)
        acc += (psum[g * 256 + k] * inv) * Wp1[k * 256 + j];
    for (int k = 0; k < 256; ++k)
        acc += pmax[g * 256 + k] * Wp1[(256 + k) * 256 + j];
    float v = fmaxf(acc, 0.f) * Wp2[j];
    __shared__ float red[256];
    red[j] = v;
    __syncthreads();
    for (int off = 128; off > 0; off >>= 1) {
        if (j < off) red[j] += red[j + off];
        __syncthreads();
    }
    if (j == 0) out[g] = red[0] + bp2[0];
}

// ---------------------------------------------------------------------------
// launch
// ---------------------------------------------------------------------------
extern "C" void kernel_launch(void* const* d_in, const int* in_sizes, int n_in,
                              void* d_out, int out_size, void* d_ws, size_t ws_size,
                              hipStream_t stream) {
    const float* x   = (const float*)d_in[0];
    const int*   ei  = (const int*)d_in[1];
    const float* ea  = (const float*)d_in[2];
    const int*   bat = (const int*)d_in[3];
    auto LP = [&](int l, int j) { return (const float*)d_in[4 + l * 10 + j]; };
    const float* Wskip = (const float*)d_in[34];
    const float* bskip = (const float*)d_in[35];
    const float* Wp1   = (const float*)d_in[36];
    const float* bp1   = (const float*)d_in[37];
    const float* Wp2   = (const float*)d_in[38];
    const float* bp2   = (const float*)d_in[39];
    float* out = (float*)d_out;

    // workspace carve-up (256B aligned)
    char* p = (char*)d_ws;
    auto alloc = [&](size_t bytes) { void* r = (void*)p; p += (bytes + 255) & ~(size_t)255; return r; };
    uint32*   hbuf2  = (uint32*)alloc((size_t)Nn * 256 * 2);   // bf16 features [n][256]
    uint32*   skipbf = (uint32*)alloc((size_t)Nn * 128 * 4);   // bf16 skip residual
    uint32*   resA   = (uint32*)alloc((size_t)Nn * 128 * 4);   // bf16 residual streams
    uint32*   resB   = (uint32*)alloc((size_t)Nn * 128 * 4);
    ushort16* xbf    = (ushort16*)alloc((size_t)Nn * 128 * 2); // bf16 x [n][128]
    float*    wbuf   = (float*)alloc((size_t)Etot * 4 * 4);    // CSR logits->weights
    float*    ea_sorted = (float*)alloc((size_t)Etot * 2 * 4);
    float*    ssrc   = (float*)alloc((size_t)Nn * 4 * 4);
    float*    sdst   = (float*)alloc((size_t)Nn * 4 * 4);
    int*      counts = (int*)alloc((size_t)Nn * 4);
    int*      incb   = (int*)alloc((size_t)Nn * 4);
    int*      row_start = (int*)alloc((size_t)(Nn + 1) * 4);
    int*      cursor    = (int*)alloc((size_t)(Nn + 1) * 4);
    int*      src_sorted = (int*)alloc((size_t)Etot * 4);
    int*      bsums  = (int*)alloc(256 * 4);
    float*    ea_s   = (float*)alloc(2 * 4);
    float*    Mbuf   = (float*)alloc(32 * 4);
    ushort16* Wt0    = (ushort16*)alloc((size_t)256 * 128 * 2);
    ushort16* Wt1    = (ushort16*)alloc((size_t)256 * 256 * 2);
    ushort16* Wt2    = (ushort16*)alloc((size_t)256 * 256 * 2);
    ushort16* Wts    = (ushort16*)alloc((size_t)256 * 128 * 2);
    float*    psum   = (float*)alloc((size_t)Gg * 256 * 4);
    float*    pmax   = (float*)alloc((size_t)Gg * 256 * 4);
    float*    pcnt   = (float*)alloc((size_t)Gg * 4);

    const int nb = (Nn + 255) / 256;
    const int ebks = (Etot + 255) / 256;
    dim3 ggrid((Nn + 127) / 128, 2);
    const int wgrid = (Nn * 64 + 255) / 256;   // wave-per-node kernels

    // zero init
    hipMemsetAsync(counts, 0, (size_t)Nn * 4, stream);
    hipMemsetAsync(ea_s, 0, 8, stream);
    hipMemsetAsync(psum, 0, (size_t)Gg * 256 * 4, stream);
    hipMemsetAsync(pcnt, 0, (size_t)Gg * 4, stream);

    // edge-attr mean + M + weight prep + x conversion
    ea_sum_kernel<<<256, 256, 0, stream>>>(ea, ea_s);
    m_kernel<<<1, 64, 0, stream>>>(LP(0,3), LP(0,4), LP(1,3), LP(1,4), LP(2,3), LP(2,4), Mbuf);
    wt_kernel<<<128, 256, 0, stream>>>(LP(0,0), Wt0, 128);
    wt_kernel<<<256, 256, 0, stream>>>(LP(1,0), Wt1, 256);
    wt_kernel<<<256, 256, 0, stream>>>(LP(2,0), Wt2, 256);
    wt_kernel<<<128, 256, 0, stream>>>(Wskip, Wts, 128);
    cvtx_kernel<<<(Nn * 128 / 4 + 255) / 256, 256, 0, stream>>>(x, xbf, Nn * 128 / 4);

    // CSR (with CSR-ordered edge attrs)
    hist_kernel<<<ebks, 256, 0, stream>>>(ei, counts);
    scan1_kernel<<<nb, 256, 0, stream>>>(counts, incb, bsums);
    scan2_kernel<<<1, 64, 0, stream>>>(bsums, nb);
    scan3_kernel<<<nb, 256, 0, stream>>>(incb, bsums, row_start, cursor);
    scatter_kernel<<<ebks, 256, 0, stream>>>(ei, ea, ea_s, cursor, src_sorted, ea_sorted);

    // skip projection: skipbf = bf16(x @ Wskip + bskip)
    mfma_gemm_kernel<<<ggrid, 256, 0, stream>>>(xbf, Wts, bskip, (ushort16*)skipbf, Nn, 128);

    // layers
    const uint32* lid[3] = { skipbf, resA, resB };
    uint32*       lou[3] = { resA, resB, resA };
    const int     Kd[3]  = { 128, 256, 256 };
    const int     Hh[3]  = { 4, 4, 1 };
    const ushort16* lain[3] = { xbf, (ushort16*)resA, (ushort16*)resB };
    const ushort16* lwt[3]  = { Wt0, Wt1, Wt2 };
    for (int l = 0; l < 3; ++l) {
        const int H = Hh[l];
        mfma_gemm_kernel<<<ggrid, 256, 0, stream>>>(
            lain[l], lwt[l], nullptr, (ushort16*)hbuf2, Nn, Kd[l]);
        attn_node_kernel<<<wgrid, 256, 0, stream>>>(
            (const ushort16*)hbuf2, LP(l,1), LP(l,2), ssrc, sdst, H);
        if (H == 4)
            edge_softmax_kernel<4><<<wgrid, 256, 0, stream>>>(
                src_sorted, row_start, ea_sorted, ssrc, sdst, Mbuf + l * 8, wbuf);
        else
            edge_softmax_kernel<1><<<wgrid, 256, 0, stream>>>(
                src_sorted, row_start, ea_sorted, ssrc, sdst, Mbuf + l * 8, wbuf);
        agg_kernel<<<Nn, 128, 0, stream>>>(src_sorted, row_start, hbuf2, wbuf,
            LP(l,5), LP(l,6), LP(l,7), LP(l,8), LP(l,9), lid[l], lou[l], H);
    }

    // pooling + head (final x = resA, bf16-packed)
    pool_init_kernel<<<(Gg * 256 + 255) / 256, 256, 0, stream>>>(pmax);
    pool_kernel<<<(Nn + POOL_ROWS - 1) / POOL_ROWS, 128, 0, stream>>>(resA, bat, psum, pmax, pcnt);
    mlp_kernel<<<Gg, 256, 0, stream>>>(psum, pmax, pcnt, Wp1, bp1, Wp2, bp2, out);
}

// Round 9
// 837.838 us; speedup vs baseline: 3.2433x; 1.0632x over previous
//
#include <hip/hip_runtime.h>
#include <cfloat>

// Problem constants (match reference setup_inputs)
#define Nn 50000
#define Ee 800000
#define Etot (Ee + Nn)   // edges + self loops = 850000
#define Gg 64
#define HIDc 256
#define BN_EPS 1e-5f

typedef unsigned int   uint32;
typedef unsigned short ushort16;
typedef short  bf16x8 __attribute__((ext_vector_type(8)));
typedef float  f32x4  __attribute__((ext_vector_type(4)));

// ---------------------------------------------------------------------------
// small helpers
// ---------------------------------------------------------------------------
__device__ inline void atomicMaxFloat(float* addr, float val) {
    int old = __float_as_int(*addr);
    while (__int_as_float(old) < val) {
        int assumed = old;
        old = atomicCAS((int*)addr, assumed, __float_as_int(val));
        if (old == assumed) break;
    }
}

__device__ inline ushort16 f2bf(float f) {            // RNE fp32 -> bf16
    uint32 u = __float_as_uint(f);
    u = (u + 0x7fffu + ((u >> 16) & 1u)) >> 16;
    return (ushort16)u;
}
__device__ inline float bf2f(ushort16 u) {
    return __uint_as_float(((uint32)u) << 16);
}

// ---------------------------------------------------------------------------
// edge_attr mean (sum, divided later)
// ---------------------------------------------------------------------------
__global__ void ea_sum_kernel(const float* __restrict__ ea, float* __restrict__ out) {
    __shared__ float sh0[256], sh1[256];
    float s0 = 0.f, s1 = 0.f;
    for (int e = blockIdx.x * blockDim.x + threadIdx.x; e < Ee; e += gridDim.x * blockDim.x) {
        s0 += ea[2 * e];
        s1 += ea[2 * e + 1];
    }
    sh0[threadIdx.x] = s0; sh1[threadIdx.x] = s1;
    __syncthreads();
    for (int off = 128; off > 0; off >>= 1) {
        if ((int)threadIdx.x < off) {
            sh0[threadIdx.x] += sh0[threadIdx.x + off];
            sh1[threadIdx.x] += sh1[threadIdx.x + off];
        }
        __syncthreads();
    }
    if (threadIdx.x == 0) { atomicAdd(&out[0], sh0[0]); atomicAdd(&out[1], sh1[0]); }
}

// ---------------------------------------------------------------------------
// M[l][d][h] = sum_c We_l[d, h*C+c] * ae_l[h, c]   (layout M[l*8 + d*H + h])
// ---------------------------------------------------------------------------
__global__ void m_kernel(const float* __restrict__ We0, const float* __restrict__ ae0,
                         const float* __restrict__ We1, const float* __restrict__ ae1,
                         const float* __restrict__ We2, const float* __restrict__ ae2,
                         float* __restrict__ M) {
    int t = threadIdx.x;
    if (t >= 18) return;
    int l = t < 8 ? 0 : (t < 16 ? 1 : 2);
    int r = t - l * 8;
    const float* We = (l == 0) ? We0 : (l == 1 ? We1 : We2);
    const float* ae = (l == 0) ? ae0 : (l == 1 ? ae1 : ae2);
    int Hl = (l < 2) ? 4 : 1;
    int Cl = 256 / Hl;
    int d = r / Hl, hh = r % Hl;
    float s = 0.f;
    for (int c = 0; c < Cl; ++c)
        s += We[d * 256 + hh * Cl + c] * ae[hh * Cl + c];
    M[l * 8 + r] = s;
}

// ---------------------------------------------------------------------------
// weight transpose + bf16 convert: Wt[n][k] = bf16(W[k][n]),  n in [0,256)
// ---------------------------------------------------------------------------
__global__ void wt_kernel(const float* __restrict__ W, ushort16* __restrict__ Wt, int K) {
    int k = blockIdx.x;
    int n = threadIdx.x;
    Wt[(long)n * K + k] = f2bf(W[(long)k * 256 + n]);
}

// zero a float buffer
__global__ void zero_kernel(float* __restrict__ b, int n) {
    int i = blockIdx.x * blockDim.x + threadIdx.x;
    if (i < n) b[i] = 0.f;
}

// ---------------------------------------------------------------------------
// CSR build: histogram -> scan -> scatter (src + CSR-ordered edge attrs)
// ---------------------------------------------------------------------------
__global__ void hist_kernel(const int* __restrict__ ei, int* __restrict__ counts) {
    int e = blockIdx.x * blockDim.x + threadIdx.x;
    if (e >= Etot) return;
    int d = (e < Ee) ? ei[Ee + e] : (e - Ee);
    atomicAdd(&counts[d], 1);
}

__global__ void scan1_kernel(const int* __restrict__ in, int* __restrict__ inc,
                             int* __restrict__ bsums) {
    __shared__ int sh[256];
    int i = blockIdx.x * 256 + threadIdx.x;
    int v = (i < Nn) ? in[i] : 0;
    sh[threadIdx.x] = v;
    __syncthreads();
    for (int off = 1; off < 256; off <<= 1) {
        int t = ((int)threadIdx.x >= off) ? sh[threadIdx.x - off] : 0;
        __syncthreads();
        sh[threadIdx.x] += t;
        __syncthreads();
    }
    if (i < Nn) inc[i] = sh[threadIdx.x];
    if (threadIdx.x == 255) bsums[blockIdx.x] = sh[255];
}

__global__ void scan2_kernel(int* __restrict__ bsums, int nb) {
    if (blockIdx.x == 0 && threadIdx.x == 0) {
        int acc = 0;
        for (int i = 0; i < nb; ++i) { int v = bsums[i]; bsums[i] = acc; acc += v; }
    }
}

__global__ void scan3_kernel(const int* __restrict__ inc, const int* __restrict__ bsums,
                             int* __restrict__ row_start, int* __restrict__ cursor) {
    int i = blockIdx.x * 256 + threadIdx.x;
    if (i < Nn) {
        int v = inc[i] + bsums[blockIdx.x];
        row_start[i + 1] = v;
        cursor[i + 1] = v;
    }
    if (i == 0) { row_start[0] = 0; cursor[0] = 0; }
}

// writes CSR-ordered src list and CSR-ordered edge attributes
__global__ void scatter_kernel(const int* __restrict__ ei, const float* __restrict__ ea,
                               const float* __restrict__ ea_sum, int* __restrict__ cursor,
                               int* __restrict__ src_sorted, float* __restrict__ ea_sorted) {
    int e = blockIdx.x * blockDim.x + threadIdx.x;
    if (e >= Etot) return;
    int s, d; float e0, e1;
    if (e < Ee) {
        s = ei[e]; d = ei[Ee + e];
        e0 = ea[2 * e]; e1 = ea[2 * e + 1];
    } else {
        s = d = e - Ee;
        const float invE = 1.f / (float)Ee;
        e0 = ea_sum[0] * invE; e1 = ea_sum[1] * invE;
    }
    int pos = atomicAdd(&cursor[d], 1);
    src_sorted[pos] = s;
    ea_sorted[2 * pos]     = e0;
    ea_sorted[2 * pos + 1] = e1;
}

// ---------------------------------------------------------------------------
// MFMA bf16 GEMM + fused attention-epilogue.
// out[n,256] = A[n,K] @ W[K,256]; 128x128 tile, 4 waves (2x2 of 64x64).
// If outS != null: grid.y=4, cols 256..511 route to outS (skip proj, +bskip).
// If a_s != null: feature cols also produce ssrc/sdst (per-row per-head dots)
//   via in-register partials + 16-lane xor-shuffle reduction.
//   H==4 -> direct store (one writer per (row,head)); H==1 -> atomicAdd
//   (ssrc/sdst pre-zeroed).
// ---------------------------------------------------------------------------
#define LDK 40
template <bool F32A>
__global__ __launch_bounds__(256) void mfma_gemm_kernel(
        const void* __restrict__ Aptr,    // [n][K] bf16 (or fp32 if F32A)
        const ushort16* __restrict__ Wt,  // [NCOLS][K] bf16 (n-major)
        ushort16* __restrict__ outF,      // feature out [n][256] bf16
        ushort16* __restrict__ outS,      // skip out [n][256] bf16 (or null)
        const float* __restrict__ bskip,
        const float* __restrict__ a_s, const float* __restrict__ a_d,
        float* __restrict__ ssrc, float* __restrict__ sdst,
        int H, int n, int K) {
    __shared__ ushort16 As[128 * LDK];
    __shared__ ushort16 Bs[128 * LDK];
    const int t    = threadIdx.x;
    const int row0 = blockIdx.x * 128;
    const int c0   = blockIdx.y * 128;
    const bool isSkip = (outS != nullptr) && (c0 >= 256);
    const int cc0  = isSkip ? c0 - 256 : c0;
    const int wave = t >> 6, lane = t & 63;
    const int wr = wave >> 1, wc = wave & 1;
    const int l15 = lane & 15, quad = lane >> 4;

    f32x4 acc[4][4];
#pragma unroll
    for (int i = 0; i < 4; ++i)
#pragma unroll
        for (int j = 0; j < 4; ++j) {
            acc[i][j][0] = 0.f; acc[i][j][1] = 0.f;
            acc[i][j][2] = 0.f; acc[i][j][3] = 0.f;
        }

    const int sm = t & 127;   // staging row (A) / col (B)
    const int so = t >> 7;    // 0..1

    for (int k0 = 0; k0 < K; k0 += 32) {
#pragma unroll
        for (int h = 0; h < 2; ++h) {
            int oct = so + 2 * h;                 // 0..3 (8 bf16 each)
            int grow = row0 + sm;
            uint4 va = make_uint4(0, 0, 0, 0);
            if (grow < n) {
                if constexpr (F32A) {
                    const float* Af = (const float*)Aptr;
                    float4 v0 = *(const float4*)&Af[(long)grow * K + k0 + 8 * oct];
                    float4 v1 = *(const float4*)&Af[(long)grow * K + k0 + 8 * oct + 4];
                    va.x = (uint32)f2bf(v0.x) | ((uint32)f2bf(v0.y) << 16);
                    va.y = (uint32)f2bf(v0.z) | ((uint32)f2bf(v0.w) << 16);
                    va.z = (uint32)f2bf(v1.x) | ((uint32)f2bf(v1.y) << 16);
                    va.w = (uint32)f2bf(v1.z) | ((uint32)f2bf(v1.w) << 16);
                } else {
                    const ushort16* Ab = (const ushort16*)Aptr;
                    va = *(const uint4*)&Ab[(long)grow * K + k0 + 8 * oct];
                }
            }
            *(uint4*)&As[sm * LDK + 8 * oct] = va;
            *(uint4*)&Bs[sm * LDK + 8 * oct] =
                *(const uint4*)&Wt[(long)(c0 + sm) * K + k0 + 8 * oct];
        }
        __syncthreads();
        bf16x8 af[4], bfv[4];
#pragma unroll
        for (int i = 0; i < 4; ++i) {
            af[i]  = *(const bf16x8*)&As[(wr * 64 + i * 16 + l15) * LDK + quad * 8];
            bfv[i] = *(const bf16x8*)&Bs[(wc * 64 + i * 16 + l15) * LDK + quad * 8];
        }
#pragma unroll
        for (int i = 0; i < 4; ++i)
#pragma unroll
            for (int j = 0; j < 4; ++j)
                acc[i][j] = __builtin_amdgcn_mfma_f32_16x16x32_bf16(
                    af[i], bfv[j], acc[i][j], 0, 0, 0);
        __syncthreads();
    }

    // ---- store: D col = l15 (+j*16), row = quad*4 + reg (+i*16) ----
    ushort16* target = isSkip ? outS : outF;
#pragma unroll
    for (int i = 0; i < 4; ++i) {
#pragma unroll
        for (int j = 0; j < 4; ++j) {
            int col = cc0 + wc * 64 + j * 16 + l15;
            float b = isSkip ? bskip[col] : 0.f;
#pragma unroll
            for (int r = 0; r < 4; ++r) {
                int row = row0 + wr * 64 + i * 16 + quad * 4 + r;
                if (row < n)
                    target[(long)row * 256 + col] = f2bf(acc[i][j][r] + b);
            }
        }
    }

    // ---- fused attention dots (feature cols only) ----
    if (!isSkip && a_s != nullptr) {
        float as_c[4], ad_c[4];
#pragma unroll
        for (int j = 0; j < 4; ++j) {
            int col = cc0 + wc * 64 + j * 16 + l15;
            as_c[j] = a_s[col];
            ad_c[j] = a_d[col];
        }
        float ps[4][4], pd[4][4];
#pragma unroll
        for (int i = 0; i < 4; ++i)
#pragma unroll
            for (int r = 0; r < 4; ++r) {
                float s = 0.f, d = 0.f;
#pragma unroll
                for (int j = 0; j < 4; ++j) {
                    s += acc[i][j][r] * as_c[j];
                    d += acc[i][j][r] * ad_c[j];
                }
                ps[i][r] = s; pd[i][r] = d;
            }
#pragma unroll
        for (int off = 1; off < 16; off <<= 1) {
#pragma unroll
            for (int i = 0; i < 4; ++i)
#pragma unroll
                for (int r = 0; r < 4; ++r) {
                    ps[i][r] += __shfl_xor(ps[i][r], off);
                    pd[i][r] += __shfl_xor(pd[i][r], off);
                }
        }
        if (l15 == 0) {
            int hd = (H == 4) ? ((cc0 + wc * 64) >> 6) : 0;
#pragma unroll
            for (int i = 0; i < 4; ++i)
#pragma unroll
                for (int r = 0; r < 4; ++r) {
                    int row = row0 + wr * 64 + i * 16 + quad * 4 + r;
                    if (row < n) {
                        if (H == 4) {
                            ssrc[row * 4 + hd] = ps[i][r];
                            sdst[row * 4 + hd] = pd[i][r];
                        } else {
                            atomicAdd(&ssrc[row], ps[i][r]);
                            atomicAdd(&sdst[row], pd[i][r]);
                        }
                    }
                }
        }
    }
}

// ---------------------------------------------------------------------------
// fused edge logits + segment softmax, one wave per dst node, CSR order.
// Single-pass: logits cached in registers (deg<=256), one write of w.
// Fallback to 2-pass via w buffer for deg>256 (never hit on this graph).
// ---------------------------------------------------------------------------
template <int H>
__global__ __launch_bounds__(256) void edge_softmax_kernel(
        const int* __restrict__ src_sorted, const int* __restrict__ row_start,
        const float* __restrict__ ea_sorted, const float* __restrict__ ssrc,
        const float* __restrict__ sdst, const float* __restrict__ M,
        float* __restrict__ w) {
    int node = (blockIdx.x * blockDim.x + threadIdx.x) >> 6;
    int lane = threadIdx.x & 63;
    if (node >= Nn) return;
    int beg = row_start[node], end = row_start[node + 1];
    int deg = end - beg;
    float sd[H], M0[H], M1[H], m[H], den[H];
#pragma unroll
    for (int h = 0; h < H; ++h) {
        sd[h] = sdst[node * H + h];
        M0[h] = M[h]; M1[h] = M[H + h];
        m[h] = -FLT_MAX; den[h] = 0.f;
    }
    if (deg <= 256) {
        float lreg[4][H];
#pragma unroll
        for (int k = 0; k < 4; ++k) {
            int idx = beg + lane + (k << 6);
            if (idx < end) {
                int s = src_sorted[idx];
                float e0 = ea_sorted[2 * idx], e1 = ea_sorted[2 * idx + 1];
#pragma unroll
                for (int h = 0; h < H; ++h) {
                    float l = ssrc[s * H + h] + sd[h] + e0 * M0[h] + e1 * M1[h];
                    l = (l > 0.f) ? l : 0.2f * l;
                    lreg[k][h] = l;
                    if (l > m[h]) { den[h] = den[h] * __expf(m[h] - l) + 1.f; m[h] = l; }
                    else den[h] += __expf(l - m[h]);
                }
            }
        }
#pragma unroll
        for (int h = 0; h < H; ++h) {
            for (int off = 32; off > 0; off >>= 1) {
                float om = __shfl_down(m[h], off);
                float od = __shfl_down(den[h], off);
                float nm = fmaxf(m[h], om);
                den[h] = den[h] * __expf(m[h] - nm) + od * __expf(om - nm);
                m[h] = nm;
            }
            m[h]   = __shfl(m[h], 0);
            den[h] = __shfl(den[h], 0);
            den[h] = 1.f / (den[h] + 1e-16f);
        }
#pragma unroll
        for (int k = 0; k < 4; ++k) {
            int idx = beg + lane + (k << 6);
            if (idx < end) {
#pragma unroll
                for (int h = 0; h < H; ++h)
                    w[(long)idx * H + h] = __expf(lreg[k][h] - m[h]) * den[h];
            }
        }
    } else {
        // 2-pass fallback
        for (int idx = beg + lane; idx < end; idx += 64) {
            int s = src_sorted[idx];
            float e0 = ea_sorted[2 * idx], e1 = ea_sorted[2 * idx + 1];
#pragma unroll
            for (int h = 0; h < H; ++h) {
                float l = ssrc[s * H + h] + sd[h] + e0 * M0[h] + e1 * M1[h];
                l = (l > 0.f) ? l : 0.2f * l;
                w[(long)idx * H + h] = l;
                if (l > m[h]) { den[h] = den[h] * __expf(m[h] - l) + 1.f; m[h] = l; }
                else den[h] += __expf(l - m[h]);
            }
        }
#pragma unroll
        for (int h = 0; h < H; ++h) {
            for (int off = 32; off > 0; off >>= 1) {
                float om = __shfl_down(m[h], off);
                float od = __shfl_down(den[h], off);
                float nm = fmaxf(m[h], om);
                den[h] = den[h] * __expf(m[h] - nm) + od * __expf(om - nm);
                m[h] = nm;
            }
            m[h]   = __shfl(m[h], 0);
            den[h] = __shfl(den[h], 0);
            den[h] = 1.f / (den[h] + 1e-16f);
        }
        for (int idx = beg + lane; idx < end; idx += 64) {
#pragma unroll
            for (int h = 0; h < H; ++h) {
                float l = w[(long)idx * H + h];
                w[(long)idx * H + h] = __expf(l - m[h]) * den[h];
            }
        }
    }
}

// ---------------------------------------------------------------------------
// weighted gather (bf16 features) + bconv + BN + ELU + residual(bf16).
// 128 threads/node; thread c2 handles channels 2c2,2c2+1 (packed bf16x2).
// ---------------------------------------------------------------------------
__global__ __launch_bounds__(128) void agg_kernel(
        const int* __restrict__ src_sorted, const int* __restrict__ row_start,
        const uint32* __restrict__ hbuf2, const float* __restrict__ w,
        const float* __restrict__ bconv,
        const float* __restrict__ bn_g, const float* __restrict__ bn_b,
        const float* __restrict__ bn_m, const float* __restrict__ bn_v,
        const uint32* __restrict__ identity2, uint32* __restrict__ out2, int H) {
    int node = blockIdx.x;
    int c2 = threadIdx.x;            // 0..127
    int C2 = 128 / H;
    int hh = c2 / C2;
    int beg = row_start[node], end = row_start[node + 1];
    float a0 = 0.f, a1 = 0.f;
    for (int idx = beg; idx < end; idx += 4) {
        int   s[4];
        float ww[4];
#pragma unroll
        for (int k = 0; k < 4; ++k) {
            int j = idx + k;
            bool ok = j < end;
            int jj = ok ? j : beg;
            s[k]  = src_sorted[jj];
            ww[k] = ok ? w[(long)jj * H + hh] : 0.f;
        }
#pragma unroll
        for (int k = 0; k < 4; ++k) {
            uint32 u = hbuf2[(long)s[k] * 128 + c2];
            float lo = __uint_as_float(u << 16);
            float hi = __uint_as_float(u & 0xffff0000u);
            a0 += ww[k] * lo;
            a1 += ww[k] * hi;
        }
    }
    int c = 2 * c2;
    float v0 = a0 + bconv[c];
    float v1 = a1 + bconv[c + 1];
    v0 = (v0 - bn_m[c])     * rsqrtf(bn_v[c]     + BN_EPS) * bn_g[c]     + bn_b[c];
    v1 = (v1 - bn_m[c + 1]) * rsqrtf(bn_v[c + 1] + BN_EPS) * bn_g[c + 1] + bn_b[c + 1];
    v0 = (v0 > 0.f) ? v0 : (expf(v0) - 1.f);
    v1 = (v1 > 0.f) ? v1 : (expf(v1) - 1.f);
    uint32 idu = identity2[(long)node * 128 + c2];
    v0 += __uint_as_float(idu << 16);
    v1 += __uint_as_float(idu & 0xffff0000u);
    out2[(long)node * 128 + c2] = (uint32)f2bf(v0) | ((uint32)f2bf(v1) << 16);
}

// ---------------------------------------------------------------------------
// pooling (bf16 input, 32 rows/block, 128 threads = 2 channels each)
// ---------------------------------------------------------------------------
#define POOL_ROWS 32
__global__ void pool_init_kernel(float* __restrict__ pmax) {
    int i = blockIdx.x * blockDim.x + threadIdx.x;
    if (i < Gg * 256) pmax[i] = -FLT_MAX;
}

__global__ __launch_bounds__(128) void pool_kernel(
        const uint32* __restrict__ x2, const int* __restrict__ batch,
        float* __restrict__ psum, float* __restrict__ pmax, float* __restrict__ pcnt) {
    int c2 = threadIdx.x;
    int n0 = blockIdx.x * POOL_ROWS;
    if (n0 >= Nn) return;
    int n1 = min(n0 + POOL_ROWS, Nn);
    int cur = batch[n0];
    float s0 = 0.f, s1 = 0.f, m0 = -FLT_MAX, m1 = -FLT_MAX;
    int cnt = 0;
    int c = 2 * c2;
    for (int i = n0; i < n1; ++i) {
        int g = batch[i];
        if (g != cur) {
            atomicAdd(&psum[cur * 256 + c], s0);
            atomicAdd(&psum[cur * 256 + c + 1], s1);
            atomicMaxFloat(&pmax[cur * 256 + c], m0);
            atomicMaxFloat(&pmax[cur * 256 + c + 1], m1);
            if (c2 == 0) atomicAdd(&pcnt[cur], (float)cnt);
            cur = g; s0 = s1 = 0.f; m0 = m1 = -FLT_MAX; cnt = 0;
        }
        uint32 u = x2[(long)i * 128 + c2];
        float lo = __uint_as_float(u << 16);
        float hi = __uint_as_float(u & 0xffff0000u);
        s0 += lo; s1 += hi;
        m0 = fmaxf(m0, lo); m1 = fmaxf(m1, hi);
        ++cnt;
    }
    atomicAdd(&psum[cur * 256 + c], s0);
    atomicAdd(&psum[cur * 256 + c + 1], s1);
    atomicMaxFloat(&pmax[cur * 256 + c], m0);
    atomicMaxFloat(&pmax[cur * 256 + c + 1], m1);
    if (c2 == 0) atomicAdd(&pcnt[cur], (float)cnt);
}

// ---------------------------------------------------------------------------
// head MLP: relu(emb @ Wp1 + bp1) @ Wp2 + bp2  -> out[g]
// ---------------------------------------------------------------------------
__global__ __launch_bounds__(256) void mlp_kernel(
        const float* __restrict__ psum, const float* __restrict__ pmax,
        const float* __restrict__ pcnt, const float* __restrict__ Wp1,
        const float* __restrict__ bp1, const float* __restrict__ Wp2,
        const float* __restrict__ bp2, float* __restrict__ out) {
    int g = blockIdx.x;
    int j = threadIdx.x;
    float inv = 1.f / fmaxf(pcnt[g], 1.f);
    float acc = bp1[j];
    for (int k = 0; k < 256; ++k)
        acc += (psum[g * 256 + k] * inv) * Wp1[k * 256 + j];
    for (int k = 0; k < 256; ++k)
        acc += pmax[g * 256 + k] * Wp1[(256 + k) * 256 + j];
    float v = fmaxf(acc, 0.f) * Wp2[j];
    __shared__ float red[256];
    red[j] = v;
    __syncthreads();
    for (int off = 128; off > 0; off >>= 1) {
        if (j < off) red[j] += red[j + off];
        __syncthreads();
    }
    if (j == 0) out[g] = red[0] + bp2[0];
}

// ---------------------------------------------------------------------------
// launch
// ---------------------------------------------------------------------------
extern "C" void kernel_launch(void* const* d_in, const int* in_sizes, int n_in,
                              void* d_out, int out_size, void* d_ws, size_t ws_size,
                              hipStream_t stream) {
    const float* x   = (const float*)d_in[0];
    const int*   ei  = (const int*)d_in[1];
    const float* ea  = (const float*)d_in[2];
    const int*   bat = (const int*)d_in[3];
    auto LP = [&](int l, int j) { return (const float*)d_in[4 + l * 10 + j]; };
    const float* Wskip = (const float*)d_in[34];
    const float* bskip = (const float*)d_in[35];
    const float* Wp1   = (const float*)d_in[36];
    const float* bp1   = (const float*)d_in[37];
    const float* Wp2   = (const float*)d_in[38];
    const float* bp2   = (const float*)d_in[39];
    float* out = (float*)d_out;

    // workspace carve-up (256B aligned)
    char* p = (char*)d_ws;
    auto alloc = [&](size_t bytes) { void* r = (void*)p; p += (bytes + 255) & ~(size_t)255; return r; };
    uint32*   hbuf2  = (uint32*)alloc((size_t)Nn * 256 * 2);   // bf16 features [n][256]
    uint32*   skipbf = (uint32*)alloc((size_t)Nn * 128 * 4);   // bf16 skip residual
    uint32*   resA   = (uint32*)alloc((size_t)Nn * 128 * 4);   // bf16 residual streams
    uint32*   resB   = (uint32*)alloc((size_t)Nn * 128 * 4);
    float*    wbuf   = (float*)alloc((size_t)Etot * 4 * 4);    // CSR softmax weights
    float*    ea_sorted = (float*)alloc((size_t)Etot * 2 * 4);
    float*    ssrc   = (float*)alloc((size_t)Nn * 4 * 4);
    float*    sdst   = (float*)alloc((size_t)Nn * 4 * 4);
    int*      counts = (int*)alloc((size_t)Nn * 4);
    int*      incb   = (int*)alloc((size_t)Nn * 4);
    int*      row_start = (int*)alloc((size_t)(Nn + 1) * 4);
    int*      cursor    = (int*)alloc((size_t)(Nn + 1) * 4);
    int*      src_sorted = (int*)alloc((size_t)Etot * 4);
    int*      bsums  = (int*)alloc(256 * 4);
    float*    ea_s   = (float*)alloc(2 * 4);
    float*    Mbuf   = (float*)alloc(32 * 4);
    ushort16* WtC    = (ushort16*)alloc((size_t)512 * 128 * 2); // W0 | Wskip combined
    ushort16* Wt1    = (ushort16*)alloc((size_t)256 * 256 * 2);
    ushort16* Wt2    = (ushort16*)alloc((size_t)256 * 256 * 2);
    float*    psum   = (float*)alloc((size_t)Gg * 256 * 4);
    float*    pmax   = (float*)alloc((size_t)Gg * 256 * 4);
    float*    pcnt   = (float*)alloc((size_t)Gg * 4);

    const int nb = (Nn + 255) / 256;
    const int ebks = (Etot + 255) / 256;
    const int wgrid = (Nn * 64 + 255) / 256;   // wave-per-node kernels

    // zero init
    hipMemsetAsync(counts, 0, (size_t)Nn * 4, stream);
    hipMemsetAsync(ea_s, 0, 8, stream);
    hipMemsetAsync(psum, 0, (size_t)Gg * 256 * 4, stream);
    hipMemsetAsync(pcnt, 0, (size_t)Gg * 4, stream);

    // edge-attr mean + M + weight prep
    ea_sum_kernel<<<256, 256, 0, stream>>>(ea, ea_s);
    m_kernel<<<1, 64, 0, stream>>>(LP(0,3), LP(0,4), LP(1,3), LP(1,4), LP(2,3), LP(2,4), Mbuf);
    wt_kernel<<<128, 256, 0, stream>>>(LP(0,0), WtC, 128);
    wt_kernel<<<128, 256, 0, stream>>>(Wskip, WtC + 256 * 128, 128);
    wt_kernel<<<256, 256, 0, stream>>>(LP(1,0), Wt1, 256);
    wt_kernel<<<256, 256, 0, stream>>>(LP(2,0), Wt2, 256);

    // CSR (with CSR-ordered edge attrs)
    hist_kernel<<<ebks, 256, 0, stream>>>(ei, counts);
    scan1_kernel<<<nb, 256, 0, stream>>>(counts, incb, bsums);
    scan2_kernel<<<1, 64, 0, stream>>>(bsums, nb);
    scan3_kernel<<<nb, 256, 0, stream>>>(incb, bsums, row_start, cursor);
    scatter_kernel<<<ebks, 256, 0, stream>>>(ei, ea, ea_s, cursor, src_sorted, ea_sorted);

    // fused layer-0 GEMM + skip projection + attn dots (fp32 A = x)
    {
        dim3 g0((Nn + 127) / 128, 4);
        mfma_gemm_kernel<true><<<g0, 256, 0, stream>>>(
            x, WtC, (ushort16*)hbuf2, (ushort16*)skipbf, bskip,
            LP(0,1), LP(0,2), ssrc, sdst, 4, Nn, 128);
    }

    // layers
    const uint32* lid[3] = { skipbf, resA, resB };
    uint32*       lou[3] = { resA, resB, resA };
    const int     Hh[3]  = { 4, 4, 1 };
    const ushort16* lain[3] = { nullptr, (ushort16*)resA, (ushort16*)resB };
    const ushort16* lwt[3]  = { nullptr, Wt1, Wt2 };
    for (int l = 0; l < 3; ++l) {
        const int H = Hh[l];
        if (l > 0) {
            if (H == 1) {   // atomic-accumulated attn dots need zeroed buffers
                zero_kernel<<<(Nn + 255) / 256, 256, 0, stream>>>(ssrc, Nn);
                zero_kernel<<<(Nn + 255) / 256, 256, 0, stream>>>(sdst, Nn);
            }
            dim3 gl((Nn + 127) / 128, 2);
            mfma_gemm_kernel<false><<<gl, 256, 0, stream>>>(
                lain[l], lwt[l], (ushort16*)hbuf2, nullptr, nullptr,
                LP(l,1), LP(l,2), ssrc, sdst, H, Nn, 256);
        }
        if (H == 4)
            edge_softmax_kernel<4><<<wgrid, 256, 0, stream>>>(
                src_sorted, row_start, ea_sorted, ssrc, sdst, Mbuf + l * 8, wbuf);
        else
            edge_softmax_kernel<1><<<wgrid, 256, 0, stream>>>(
                src_sorted, row_start, ea_sorted, ssrc, sdst, Mbuf + l * 8, wbuf);
        agg_kernel<<<Nn, 128, 0, stream>>>(src_sorted, row_start, hbuf2, wbuf,
            LP(l,5), LP(l,6), LP(l,7), LP(l,8), LP(l,9), lid[l], lou[l], H);
    }

    // pooling + head (final x = resA, bf16-packed)
    pool_init_kernel<<<(Gg * 256 + 255) / 256, 256, 0, stream>>>(pmax);
    pool_kernel<<<(Nn + POOL_ROWS - 1) / POOL_ROWS, 128, 0, stream>>>(resA, bat, psum, pmax, pcnt);
    mlp_kernel<<<Gg, 256, 0, stream>>>(psum, pmax, pcnt, Wp1, bp1, Wp2, bp2, out);
}

// Round 10
// 726.320 us; speedup vs baseline: 3.7413x; 1.1535x over previous
//
#include <hip/hip_runtime.h>
#include <cfloat>

// Problem constants (match reference setup_inputs)
#define Nn 50000
#define Ee 800000
#define Etot (Ee + Nn)   // edges + self loops = 850000
#define Gg 64
#define HIDc 256
#define BN_EPS 1e-5f

typedef unsigned int   uint32;
typedef unsigned short ushort16;
typedef short  bf16x8 __attribute__((ext_vector_type(8)));
typedef float  f32x4  __attribute__((ext_vector_type(4)));

// ---------------------------------------------------------------------------
// helpers
// ---------------------------------------------------------------------------
__device__ inline ushort16 f2bf(float f) {            // RNE fp32 -> bf16
    uint32 u = __float_as_uint(f);
    u = (u + 0x7fffu + ((u >> 16) & 1u)) >> 16;
    return (ushort16)u;
}
__device__ inline float bf2f(ushort16 u) {
    return __uint_as_float(((uint32)u) << 16);
}
__device__ inline uint32 pack2(float a, float b) {
    return (uint32)f2bf(a) | ((uint32)f2bf(b) << 16);
}
// monotone float<->uint encoding for atomicMax-based float max
__device__ inline uint32 fenc(float f) {
    uint32 b = __float_as_uint(f);
    return (b & 0x80000000u) ? ~b : (b | 0x80000000u);
}
__device__ inline float fdec(uint32 u) {
    uint32 b = (u & 0x80000000u) ? (u & 0x7fffffffu) : ~u;
    return __uint_as_float(b);
}

// ---------------------------------------------------------------------------
// prep kernel: ea_sum | M | Wt conversions | x->bf16    (one dispatch)
// block map: [0,256) ea_sum, 256 m, [257,385) W0, [385,513) Wskip,
//            [513,769) W1, [769,1025) W2, [1025,7275) cvtx
// ---------------------------------------------------------------------------
#define CVT4 (Nn * 128 / 4)
__global__ __launch_bounds__(256) void prep_kernel(
        const float* __restrict__ ea, float* __restrict__ ea_s,
        const float* __restrict__ We0, const float* __restrict__ ae0,
        const float* __restrict__ We1, const float* __restrict__ ae1,
        const float* __restrict__ We2, const float* __restrict__ ae2,
        float* __restrict__ M,
        const float* __restrict__ W0, const float* __restrict__ Wskip,
        const float* __restrict__ W1, const float* __restrict__ W2,
        ushort16* __restrict__ WtC, ushort16* __restrict__ Wt1,
        ushort16* __restrict__ Wt2,
        const float* __restrict__ x, ushort16* __restrict__ xbf) {
    int bid = blockIdx.x, t = threadIdx.x;
    if (bid < 256) {
        __shared__ float sh0[256], sh1[256];
        float s0 = 0.f, s1 = 0.f;
        for (int e = bid * 256 + t; e < Ee; e += 256 * 256) {
            s0 += ea[2 * e];
            s1 += ea[2 * e + 1];
        }
        sh0[t] = s0; sh1[t] = s1;
        __syncthreads();
        for (int off = 128; off > 0; off >>= 1) {
            if (t < off) { sh0[t] += sh0[t + off]; sh1[t] += sh1[t + off]; }
            __syncthreads();
        }
        if (t == 0) { atomicAdd(&ea_s[0], sh0[0]); atomicAdd(&ea_s[1], sh1[0]); }
    } else if (bid == 256) {
        if (t >= 18) return;
        int l = t < 8 ? 0 : (t < 16 ? 1 : 2);
        int r = t - l * 8;
        const float* We = (l == 0) ? We0 : (l == 1 ? We1 : We2);
        const float* ae = (l == 0) ? ae0 : (l == 1 ? ae1 : ae2);
        int Hl = (l < 2) ? 4 : 1;
        int Cl = 256 / Hl;
        int d = r / Hl, hh = r % Hl;
        float s = 0.f;
        for (int c = 0; c < Cl; ++c)
            s += We[d * 256 + hh * Cl + c] * ae[hh * Cl + c];
        M[l * 8 + r] = s;
    } else if (bid < 385) {
        int k = bid - 257;
        WtC[(long)t * 128 + k] = f2bf(W0[(long)k * 256 + t]);
    } else if (bid < 513) {
        int k = bid - 385;
        WtC[(long)(256 + t) * 128 + k] = f2bf(Wskip[(long)k * 256 + t]);
    } else if (bid < 769) {
        int k = bid - 513;
        Wt1[(long)t * 256 + k] = f2bf(W1[(long)k * 256 + t]);
    } else if (bid < 1025) {
        int k = bid - 769;
        Wt2[(long)t * 256 + k] = f2bf(W2[(long)k * 256 + t]);
    } else {
        int i = (bid - 1025) * 256 + t;
        if (i < CVT4) {
            float4 v = *(const float4*)&x[i * 4];
            ushort4 o;
            o.x = f2bf(v.x); o.y = f2bf(v.y); o.z = f2bf(v.z); o.w = f2bf(v.w);
            *(ushort4*)&xbf[i * 4] = o;
        }
    }
}

// ---------------------------------------------------------------------------
// CSR build: histogram -> scan1 -> scan23 -> scatter
// ---------------------------------------------------------------------------
__global__ void hist_kernel(const int* __restrict__ ei, int* __restrict__ counts) {
    int e = blockIdx.x * blockDim.x + threadIdx.x;
    if (e >= Etot) return;
    int d = (e < Ee) ? ei[Ee + e] : (e - Ee);
    atomicAdd(&counts[d], 1);
}

__global__ void scan1_kernel(const int* __restrict__ in, int* __restrict__ inc,
                             int* __restrict__ bsums) {
    __shared__ int sh[256];
    int i = blockIdx.x * 256 + threadIdx.x;
    int v = (i < Nn) ? in[i] : 0;
    sh[threadIdx.x] = v;
    __syncthreads();
    for (int off = 1; off < 256; off <<= 1) {
        int t = ((int)threadIdx.x >= off) ? sh[threadIdx.x - off] : 0;
        __syncthreads();
        sh[threadIdx.x] += t;
        __syncthreads();
    }
    if (i < Nn) inc[i] = sh[threadIdx.x];
    if (threadIdx.x == 255) bsums[blockIdx.x] = sh[255];
}

// scan2+scan3 merged: each block reduces bsums[0..blockIdx) itself (nb<=256)
__global__ void scan23_kernel(const int* __restrict__ inc, const int* __restrict__ bsums,
                              int* __restrict__ row_start, int* __restrict__ cursor, int nb) {
    __shared__ int sh[256];
    int b = blockIdx.x, t = threadIdx.x;
    sh[t] = (t < b && t < nb) ? bsums[t] : 0;
    __syncthreads();
    for (int off = 128; off > 0; off >>= 1) {
        if (t < off) sh[t] += sh[t + off];
        __syncthreads();
    }
    int base = sh[0];
    int i = b * 256 + t;
    if (i < Nn) {
        int v = inc[i] + base;
        row_start[i + 1] = v;
        cursor[i + 1] = v;
    }
    if (i == 0) { row_start[0] = 0; cursor[0] = 0; }
}

// writes CSR-ordered src list and CSR-ordered edge attributes
__global__ void scatter_kernel(const int* __restrict__ ei, const float* __restrict__ ea,
                               const float* __restrict__ ea_sum, int* __restrict__ cursor,
                               int* __restrict__ src_sorted, float* __restrict__ ea_sorted) {
    int e = blockIdx.x * blockDim.x + threadIdx.x;
    if (e >= Etot) return;
    int s, d; float e0, e1;
    if (e < Ee) {
        s = ei[e]; d = ei[Ee + e];
        e0 = ea[2 * e]; e1 = ea[2 * e + 1];
    } else {
        s = d = e - Ee;
        const float invE = 1.f / (float)Ee;
        e0 = ea_sum[0] * invE; e1 = ea_sum[1] * invE;
    }
    int pos = atomicAdd(&cursor[d], 1);
    src_sorted[pos] = s;
    ea_sorted[2 * pos]     = e0;
    ea_sorted[2 * pos + 1] = e1;
}

// ---------------------------------------------------------------------------
// MFMA bf16 GEMM, operand-swapped (computes D^T fragments).
// mfma(bfv, af, acc): frag elem -> node row = l15 (+i*16+wr*64),
//                     feature col = quad*4+reg (+j*16+wc*64).
// Epilogue: packed uint2 stores (4 cols / 8B per store).
// Fused attention dots: per-row partial over this block's 64-col wave tile,
// reduced across quads (shfl_xor 16,32), written to ssrc/sdst[row*4+part]
// where part = colblock/64. (H=4: part==head; H=1: softmax sums parts.)
// If outS != null: grid.y=4, col blocks 256..511 route to outS (+bskip).
// ---------------------------------------------------------------------------
#define LDK 40
__global__ __launch_bounds__(256) void mfma_gemm_kernel(
        const ushort16* __restrict__ A,   // [n][K] bf16
        const ushort16* __restrict__ Wt,  // [NCOLS][K] bf16 (n-major)
        uint32* __restrict__ outF,        // feature out [n][128] packed bf16x2
        uint32* __restrict__ outS,        // skip out (or null)
        const float* __restrict__ bskip,
        const float* __restrict__ a_s, const float* __restrict__ a_d,
        float* __restrict__ ssrc, float* __restrict__ sdst,
        int n, int K) {
    __shared__ ushort16 As[128 * LDK];
    __shared__ ushort16 Bs[128 * LDK];
    const int t    = threadIdx.x;
    const int row0 = blockIdx.x * 128;
    const int c0   = blockIdx.y * 128;
    const bool isSkip = (outS != nullptr) && (c0 >= 256);
    const int cc0  = isSkip ? c0 - 256 : c0;
    const int wave = t >> 6, lane = t & 63;
    const int wr = wave >> 1, wc = wave & 1;
    const int l15 = lane & 15, quad = lane >> 4;

    f32x4 acc[4][4];   // acc[j][i]: j = feature-col block, i = node-row block
#pragma unroll
    for (int j = 0; j < 4; ++j)
#pragma unroll
        for (int i = 0; i < 4; ++i) {
            acc[j][i][0] = 0.f; acc[j][i][1] = 0.f;
            acc[j][i][2] = 0.f; acc[j][i][3] = 0.f;
        }

    const int sm = t & 127;
    const int so = t >> 7;

    for (int k0 = 0; k0 < K; k0 += 32) {
#pragma unroll
        for (int h = 0; h < 2; ++h) {
            int oct = so + 2 * h;
            int grow = row0 + sm;
            uint4 va = make_uint4(0, 0, 0, 0);
            if (grow < n) va = *(const uint4*)&A[(long)grow * K + k0 + 8 * oct];
            *(uint4*)&As[sm * LDK + 8 * oct] = va;
            *(uint4*)&Bs[sm * LDK + 8 * oct] =
                *(const uint4*)&Wt[(long)(c0 + sm) * K + k0 + 8 * oct];
        }
        __syncthreads();
        bf16x8 af[4], bfv[4];
#pragma unroll
        for (int i = 0; i < 4; ++i) {
            af[i]  = *(const bf16x8*)&As[(wr * 64 + i * 16 + l15) * LDK + quad * 8];
            bfv[i] = *(const bf16x8*)&Bs[(wc * 64 + i * 16 + l15) * LDK + quad * 8];
        }
#pragma unroll
        for (int j = 0; j < 4; ++j)
#pragma unroll
            for (int i = 0; i < 4; ++i)
                acc[j][i] = __builtin_amdgcn_mfma_f32_16x16x32_bf16(
                    bfv[j], af[i], acc[j][i], 0, 0, 0);
        __syncthreads();
    }

    // bias per (j) col run of 4
    float4 bb[4];
#pragma unroll
    for (int j = 0; j < 4; ++j) {
        if (isSkip) bb[j] = *(const float4*)&bskip[cc0 + wc * 64 + j * 16 + quad * 4];
        else        bb[j] = make_float4(0.f, 0.f, 0.f, 0.f);
    }

    uint32* tgt = isSkip ? outS : outF;
#pragma unroll
    for (int i = 0; i < 4; ++i) {
        int row = row0 + wr * 64 + i * 16 + l15;
        if (row >= n) continue;
#pragma unroll
        for (int j = 0; j < 4; ++j) {
            int col = cc0 + wc * 64 + j * 16 + quad * 4;
            uint2 pk;
            pk.x = pack2(acc[j][i][0] + bb[j].x, acc[j][i][1] + bb[j].y);
            pk.y = pack2(acc[j][i][2] + bb[j].z, acc[j][i][3] + bb[j].w);
            *(uint2*)&tgt[(long)row * 128 + (col >> 1)] = pk;
        }
    }

    // fused attention dots (feature cols only)
    if (!isSkip && a_s != nullptr) {
        float4 asv[4], adv[4];
#pragma unroll
        for (int j = 0; j < 4; ++j) {
            int col = cc0 + wc * 64 + j * 16 + quad * 4;
            asv[j] = *(const float4*)&a_s[col];
            adv[j] = *(const float4*)&a_d[col];
        }
        const int part = (cc0 + wc * 64) >> 6;
#pragma unroll
        for (int i = 0; i < 4; ++i) {
            float ps = 0.f, pd = 0.f;
#pragma unroll
            for (int j = 0; j < 4; ++j) {
                ps += acc[j][i][0] * asv[j].x + acc[j][i][1] * asv[j].y
                    + acc[j][i][2] * asv[j].z + acc[j][i][3] * asv[j].w;
                pd += acc[j][i][0] * adv[j].x + acc[j][i][1] * adv[j].y
                    + acc[j][i][2] * adv[j].z + acc[j][i][3] * adv[j].w;
            }
            ps += __shfl_xor(ps, 16); ps += __shfl_xor(ps, 32);
            pd += __shfl_xor(pd, 16); pd += __shfl_xor(pd, 32);
            if (quad == 0) {
                int row = row0 + wr * 64 + i * 16 + l15;
                if (row < n) {
                    ssrc[row * 4 + part] = ps;
                    sdst[row * 4 + part] = pd;
                }
            }
        }
    }
}

// ---------------------------------------------------------------------------
// fused edge logits + segment softmax, one wave per dst node, CSR order.
// H==1 sums the 4 partial slots of ssrc/sdst.
// ---------------------------------------------------------------------------
template <int H>
__global__ __launch_bounds__(256) void edge_softmax_kernel(
        const int* __restrict__ src_sorted, const int* __restrict__ row_start,
        const float* __restrict__ ea_sorted, const float* __restrict__ ssrc,
        const float* __restrict__ sdst, const float* __restrict__ M,
        float* __restrict__ w) {
    int node = (blockIdx.x * blockDim.x + threadIdx.x) >> 6;
    int lane = threadIdx.x & 63;
    if (node >= Nn) return;
    int beg = row_start[node], end = row_start[node + 1];
    int deg = end - beg;
    float sd[H], M0[H], M1[H], m[H], den[H];
    if (H == 4) {
#pragma unroll
        for (int h = 0; h < H; ++h) sd[h] = sdst[node * 4 + h];
    } else {
        float4 v = *(const float4*)&sdst[node * 4];
        sd[0] = v.x + v.y + v.z + v.w;
    }
#pragma unroll
    for (int h = 0; h < H; ++h) {
        M0[h] = M[h]; M1[h] = M[H + h];
        m[h] = -FLT_MAX; den[h] = 0.f;
    }
    auto ssval = [&](int s, int h) -> float {
        if (H == 4) return ssrc[s * 4 + h];
        float4 v = *(const float4*)&ssrc[s * 4];
        return v.x + v.y + v.z + v.w;
    };
    if (deg <= 256) {
        float lreg[4][H];
#pragma unroll
        for (int k = 0; k < 4; ++k) {
            int idx = beg + lane + (k << 6);
            if (idx < end) {
                int s = src_sorted[idx];
                float e0 = ea_sorted[2 * idx], e1 = ea_sorted[2 * idx + 1];
#pragma unroll
                for (int h = 0; h < H; ++h) {
                    float l = ssval(s, h) + sd[h] + e0 * M0[h] + e1 * M1[h];
                    l = (l > 0.f) ? l : 0.2f * l;
                    lreg[k][h] = l;
                    if (l > m[h]) { den[h] = den[h] * __expf(m[h] - l) + 1.f; m[h] = l; }
                    else den[h] += __expf(l - m[h]);
                }
            }
        }
#pragma unroll
        for (int h = 0; h < H; ++h) {
            for (int off = 32; off > 0; off >>= 1) {
                float om = __shfl_down(m[h], off);
                float od = __shfl_down(den[h], off);
                float nm = fmaxf(m[h], om);
                den[h] = den[h] * __expf(m[h] - nm) + od * __expf(om - nm);
                m[h] = nm;
            }
            m[h]   = __shfl(m[h], 0);
            den[h] = __shfl(den[h], 0);
            den[h] = 1.f / (den[h] + 1e-16f);
        }
#pragma unroll
        for (int k = 0; k < 4; ++k) {
            int idx = beg + lane + (k << 6);
            if (idx < end) {
#pragma unroll
                for (int h = 0; h < H; ++h)
                    w[(long)idx * H + h] = __expf(lreg[k][h] - m[h]) * den[h];
            }
        }
    } else {
        for (int idx = beg + lane; idx < end; idx += 64) {
            int s = src_sorted[idx];
            float e0 = ea_sorted[2 * idx], e1 = ea_sorted[2 * idx + 1];
#pragma unroll
            for (int h = 0; h < H; ++h) {
                float l = ssval(s, h) + sd[h] + e0 * M0[h] + e1 * M1[h];
                l = (l > 0.f) ? l : 0.2f * l;
                w[(long)idx * H + h] = l;
                if (l > m[h]) { den[h] = den[h] * __expf(m[h] - l) + 1.f; m[h] = l; }
                else den[h] += __expf(l - m[h]);
            }
        }
#pragma unroll
        for (int h = 0; h < H; ++h) {
            for (int off = 32; off > 0; off >>= 1) {
                float om = __shfl_down(m[h], off);
                float od = __shfl_down(den[h], off);
                float nm = fmaxf(m[h], om);
                den[h] = den[h] * __expf(m[h] - nm) + od * __expf(om - nm);
                m[h] = nm;
            }
            m[h]   = __shfl(m[h], 0);
            den[h] = __shfl(den[h], 0);
            den[h] = 1.f / (den[h] + 1e-16f);
        }
        for (int idx = beg + lane; idx < end; idx += 64) {
#pragma unroll
            for (int h = 0; h < H; ++h) {
                float l = w[(long)idx * H + h];
                w[(long)idx * H + h] = __expf(l - m[h]) * den[h];
            }
        }
    }
}

// ---------------------------------------------------------------------------
// weighted gather (bf16 features) + bconv + BN + ELU + residual(bf16).
// ---------------------------------------------------------------------------
__global__ __launch_bounds__(128) void agg_kernel(
        const int* __restrict__ src_sorted, const int* __restrict__ row_start,
        const uint32* __restrict__ hbuf2, const float* __restrict__ w,
        const float* __restrict__ bconv,
        const float* __restrict__ bn_g, const float* __restrict__ bn_b,
        const float* __restrict__ bn_m, const float* __restrict__ bn_v,
        const uint32* __restrict__ identity2, uint32* __restrict__ out2, int H) {
    int node = blockIdx.x;
    int c2 = threadIdx.x;            // 0..127
    int C2 = 128 / H;
    int hh = c2 / C2;
    int beg = row_start[node], end = row_start[node + 1];
    float a0 = 0.f, a1 = 0.f;
    for (int idx = beg; idx < end; idx += 4) {
        int   s[4];
        float ww[4];
#pragma unroll
        for (int k = 0; k < 4; ++k) {
            int j = idx + k;
            bool ok = j < end;
            int jj = ok ? j : beg;
            s[k]  = src_sorted[jj];
            ww[k] = ok ? w[(long)jj * H + hh] : 0.f;
        }
#pragma unroll
        for (int k = 0; k < 4; ++k) {
            uint32 u = hbuf2[(long)s[k] * 128 + c2];
            float lo = __uint_as_float(u << 16);
            float hi = __uint_as_float(u & 0xffff0000u);
            a0 += ww[k] * lo;
            a1 += ww[k] * hi;
        }
    }
    int c = 2 * c2;
    float v0 = a0 + bconv[c];
    float v1 = a1 + bconv[c + 1];
    v0 = (v0 - bn_m[c])     * rsqrtf(bn_v[c]     + BN_EPS) * bn_g[c]     + bn_b[c];
    v1 = (v1 - bn_m[c + 1]) * rsqrtf(bn_v[c + 1] + BN_EPS) * bn_g[c + 1] + bn_b[c + 1];
    v0 = (v0 > 0.f) ? v0 : (expf(v0) - 1.f);
    v1 = (v1 > 0.f) ? v1 : (expf(v1) - 1.f);
    uint32 idu = identity2[(long)node * 128 + c2];
    v0 += __uint_as_float(idu << 16);
    v1 += __uint_as_float(idu & 0xffff0000u);
    out2[(long)node * 128 + c2] = (uint32)f2bf(v0) | ((uint32)f2bf(v1) << 16);
}

// ---------------------------------------------------------------------------
// pooling (bf16 input; pmax uses monotone-uint atomicMax, init by memset 0)
// ---------------------------------------------------------------------------
#define POOL_ROWS 32
__global__ __launch_bounds__(128) void pool_kernel(
        const uint32* __restrict__ x2, const int* __restrict__ batch,
        float* __restrict__ psum, uint32* __restrict__ pmax, float* __restrict__ pcnt) {
    int c2 = threadIdx.x;
    int n0 = blockIdx.x * POOL_ROWS;
    if (n0 >= Nn) return;
    int n1 = min(n0 + POOL_ROWS, Nn);
    int cur = batch[n0];
    float s0 = 0.f, s1 = 0.f, m0 = -FLT_MAX, m1 = -FLT_MAX;
    int cnt = 0;
    int c = 2 * c2;
    for (int i = n0; i < n1; ++i) {
        int g = batch[i];
        if (g != cur) {
            atomicAdd(&psum[cur * 256 + c], s0);
            atomicAdd(&psum[cur * 256 + c + 1], s1);
            atomicMax(&pmax[cur * 256 + c], fenc(m0));
            atomicMax(&pmax[cur * 256 + c + 1], fenc(m1));
            if (c2 == 0) atomicAdd(&pcnt[cur], (float)cnt);
            cur = g; s0 = s1 = 0.f; m0 = m1 = -FLT_MAX; cnt = 0;
        }
        uint32 u = x2[(long)i * 128 + c2];
        float lo = __uint_as_float(u << 16);
        float hi = __uint_as_float(u & 0xffff0000u);
        s0 += lo; s1 += hi;
        m0 = fmaxf(m0, lo); m1 = fmaxf(m1, hi);
        ++cnt;
    }
    atomicAdd(&psum[cur * 256 + c], s0);
    atomicAdd(&psum[cur * 256 + c + 1], s1);
    atomicMax(&pmax[cur * 256 + c], fenc(m0));
    atomicMax(&pmax[cur * 256 + c + 1], fenc(m1));
    if (c2 == 0) atomicAdd(&pcnt[cur], (float)cnt);
}

// ---------------------------------------------------------------------------
// head MLP: relu(emb @ Wp1 + bp1) @ Wp2 + bp2  -> out[g]
// ---------------------------------------------------------------------------
__global__ __launch_bounds__(256) void mlp_kernel(
        const float* __restrict__ psum, const uint32* __restrict__ pmax,
        const float* __restrict__ pcnt, const float* __restrict__ Wp1,
        const float* __restrict__ bp1, const float* __restrict__ Wp2,
        const float* __restrict__ bp2, float* __restrict__ out) {
    int g = blockIdx.x;
    int j = threadIdx.x;
    float inv = 1.f / fmaxf(pcnt[g], 1.f);
    float acc = bp1[j];
    for (int k = 0; k < 256; ++k)
        acc += (psum[g * 256 + k] * inv) * Wp1[k * 256 + j];
    for (int k = 0; k < 256; ++k)
        acc += fdec(pmax[g * 256 + k]) * Wp1[(256 + k) * 256 + j];
    float v = fmaxf(acc, 0.f) * Wp2[j];
    __shared__ float red[256];
    red[j] = v;
    __syncthreads();
    for (int off = 128; off > 0; off >>= 1) {
        if (j < off) red[j] += red[j + off];
        __syncthreads();
    }
    if (j == 0) out[g] = red[0] + bp2[0];
}

// ---------------------------------------------------------------------------
// launch
// ---------------------------------------------------------------------------
extern "C" void kernel_launch(void* const* d_in, const int* in_sizes, int n_in,
                              void* d_out, int out_size, void* d_ws, size_t ws_size,
                              hipStream_t stream) {
    const float* x   = (const float*)d_in[0];
    const int*   ei  = (const int*)d_in[1];
    const float* ea  = (const float*)d_in[2];
    const int*   bat = (const int*)d_in[3];
    auto LP = [&](int l, int j) { return (const float*)d_in[4 + l * 10 + j]; };
    const float* Wskip = (const float*)d_in[34];
    const float* bskip = (const float*)d_in[35];
    const float* Wp1   = (const float*)d_in[36];
    const float* bp1   = (const float*)d_in[37];
    const float* Wp2   = (const float*)d_in[38];
    const float* bp2   = (const float*)d_in[39];
    float* out = (float*)d_out;

    // workspace carve-up (256B aligned)
    char* p = (char*)d_ws;
    auto alloc = [&](size_t bytes) { void* r = (void*)p; p += (bytes + 255) & ~(size_t)255; return r; };
    uint32*   hbuf2  = (uint32*)alloc((size_t)Nn * 256 * 2);   // bf16 features [n][128] packed
    uint32*   skipbf = (uint32*)alloc((size_t)Nn * 128 * 4);   // bf16 skip residual
    uint32*   resA   = (uint32*)alloc((size_t)Nn * 128 * 4);   // bf16 residual streams
    uint32*   resB   = (uint32*)alloc((size_t)Nn * 128 * 4);
    ushort16* xbf    = (ushort16*)alloc((size_t)Nn * 128 * 2); // bf16 x [n][128]
    float*    wbuf   = (float*)alloc((size_t)Etot * 4 * 4);    // CSR softmax weights
    float*    ea_sorted = (float*)alloc((size_t)Etot * 2 * 4);
    float*    ssrc   = (float*)alloc((size_t)Nn * 4 * 4);      // 4 partial slots
    float*    sdst   = (float*)alloc((size_t)Nn * 4 * 4);
    int*      counts = (int*)alloc((size_t)Nn * 4);
    int*      incb   = (int*)alloc((size_t)Nn * 4);
    int*      row_start = (int*)alloc((size_t)(Nn + 1) * 4);
    int*      cursor    = (int*)alloc((size_t)(Nn + 1) * 4);
    int*      src_sorted = (int*)alloc((size_t)Etot * 4);
    int*      bsums  = (int*)alloc(256 * 4);
    float*    ea_s   = (float*)alloc(2 * 4);
    float*    Mbuf   = (float*)alloc(32 * 4);
    ushort16* WtC    = (ushort16*)alloc((size_t)512 * 128 * 2); // W0 | Wskip combined
    ushort16* Wt1    = (ushort16*)alloc((size_t)256 * 256 * 2);
    ushort16* Wt2    = (ushort16*)alloc((size_t)256 * 256 * 2);
    float*    psum   = (float*)alloc((size_t)Gg * 256 * 4);    // psum|pmax|pcnt contiguous
    uint32*   pmax   = (uint32*)alloc((size_t)Gg * 256 * 4);
    float*    pcnt   = (float*)alloc((size_t)Gg * 4);

    const int nb = (Nn + 255) / 256;
    const int ebks = (Etot + 255) / 256;
    const int wgrid = (Nn * 64 + 255) / 256;

    // zero init (pool group = psum+pmax+pcnt contiguous; pmax encode: 0 = -max)
    hipMemsetAsync(counts, 0, (size_t)Nn * 4, stream);
    hipMemsetAsync(ea_s, 0, 8, stream);
    hipMemsetAsync(psum, 0, (size_t)Gg * 256 * 4 * 2 + (size_t)Gg * 4, stream);

    // one prep dispatch: ea_sum + M + all weight transposes + x->bf16
    prep_kernel<<<1025 + (CVT4 + 255) / 256, 256, 0, stream>>>(
        ea, ea_s, LP(0,3), LP(0,4), LP(1,3), LP(1,4), LP(2,3), LP(2,4), Mbuf,
        LP(0,0), Wskip, LP(1,0), LP(2,0), WtC, Wt1, Wt2, x, xbf);

    // CSR
    hist_kernel<<<ebks, 256, 0, stream>>>(ei, counts);
    scan1_kernel<<<nb, 256, 0, stream>>>(counts, incb, bsums);
    scan23_kernel<<<nb, 256, 0, stream>>>(incb, bsums, row_start, cursor, nb);
    scatter_kernel<<<ebks, 256, 0, stream>>>(ei, ea, ea_s, cursor, src_sorted, ea_sorted);

    // fused layer-0 GEMM + skip projection + attn dots
    {
        dim3 g0((Nn + 127) / 128, 4);
        mfma_gemm_kernel<<<g0, 256, 0, stream>>>(
            xbf, WtC, hbuf2, skipbf, bskip,
            LP(0,1), LP(0,2), ssrc, sdst, Nn, 128);
    }

    // layers
    const uint32* lid[3] = { skipbf, resA, resB };
    uint32*       lou[3] = { resA, resB, resA };
    const int     Hh[3]  = { 4, 4, 1 };
    const ushort16* lain[3] = { nullptr, (ushort16*)resA, (ushort16*)resB };
    const ushort16* lwt[3]  = { nullptr, Wt1, Wt2 };
    for (int l = 0; l < 3; ++l) {
        const int H = Hh[l];
        if (l > 0) {
            dim3 gl((Nn + 127) / 128, 2);
            mfma_gemm_kernel<<<gl, 256, 0, stream>>>(
                lain[l], lwt[l], hbuf2, nullptr, nullptr,
                LP(l,1), LP(l,2), ssrc, sdst, Nn, 256);
        }
        if (H == 4)
            edge_softmax_kernel<4><<<wgrid, 256, 0, stream>>>(
                src_sorted, row_start, ea_sorted, ssrc, sdst, Mbuf + l * 8, wbuf);
        else
            edge_softmax_kernel<1><<<wgrid, 256, 0, stream>>>(
                src_sorted, row_start, ea_sorted, ssrc, sdst, Mbuf + l * 8, wbuf);
        agg_kernel<<<Nn, 128, 0, stream>>>(src_sorted, row_start, hbuf2, wbuf,
            LP(l,5), LP(l,6), LP(l,7), LP(l,8), LP(l,9), lid[l], lou[l], H);
    }

    // pooling + head (final x = resA, bf16-packed)
    pool_kernel<<<(Nn + POOL_ROWS - 1) / POOL_ROWS, 128, 0, stream>>>(resA, bat, psum, pmax, pcnt);
    mlp_kernel<<<Gg, 256, 0, stream>>>(psum, pmax, pcnt, Wp1, bp1, Wp2, bp2, out);
}

// Round 11
// 709.002 us; speedup vs baseline: 3.8326x; 1.0244x over previous
//
#include <hip/hip_runtime.h>
#include <cfloat>

// Problem constants (match reference setup_inputs)
#define Nn 50000
#define Ee 800000
#define Etot (Ee + Nn)   // edges + self loops = 850000
#define Gg 64
#define HIDc 256
#define BN_EPS 1e-5f

typedef unsigned int   uint32;
typedef unsigned short ushort16;
typedef short  bf16x8 __attribute__((ext_vector_type(8)));
typedef float  f32x4  __attribute__((ext_vector_type(4)));

// ---------------------------------------------------------------------------
// helpers
// ---------------------------------------------------------------------------
__device__ inline ushort16 f2bf(float f) {            // RNE fp32 -> bf16
    uint32 u = __float_as_uint(f);
    u = (u + 0x7fffu + ((u >> 16) & 1u)) >> 16;
    return (ushort16)u;
}
__device__ inline uint32 pack2(float a, float b) {
    return (uint32)f2bf(a) | ((uint32)f2bf(b) << 16);
}
// monotone float<->uint encoding for atomicMax-based float max
__device__ inline uint32 fenc(float f) {
    uint32 b = __float_as_uint(f);
    return (b & 0x80000000u) ? ~b : (b | 0x80000000u);
}
__device__ inline float fdec(uint32 u) {
    uint32 b = (u & 0x80000000u) ? (u & 0x7fffffffu) : ~u;
    return __uint_as_float(b);
}

// W swizzle to MFMA A-operand fragment order:
// WS[((cb*KB + kb)*64 + q*16 + m)*8 + e]  where cb=c>>4, m=c&15,
// kb=k>>5, q=(k>>3)&3, e=k&7.  A wave then reads 64 lanes x 16B contiguous.
__device__ inline long ws_index(int c, int k, int KB) {
    int cb = c >> 4, m = c & 15, kb = k >> 5, q = (k >> 3) & 3, e = k & 7;
    return (((long)(cb * KB + kb) * 64 + q * 16 + m) << 3) + e;
}

// ---------------------------------------------------------------------------
// prep kernel: ea_sum | M | W swizzles | x->bf16 | hist   (one dispatch)
// ---------------------------------------------------------------------------
#define CVT4 (Nn * 128 / 4)
#define CVT_BLKS ((CVT4 + 255) / 256)
#define EBKS ((Etot + 255) / 256)
__global__ __launch_bounds__(256) void prep_kernel(
        const float* __restrict__ ea, float* __restrict__ ea_s,
        const float* __restrict__ We0, const float* __restrict__ ae0,
        const float* __restrict__ We1, const float* __restrict__ ae1,
        const float* __restrict__ We2, const float* __restrict__ ae2,
        float* __restrict__ M,
        const float* __restrict__ W0, const float* __restrict__ Wskip,
        const float* __restrict__ W1, const float* __restrict__ W2,
        ushort16* __restrict__ WtC, ushort16* __restrict__ Wt1,
        ushort16* __restrict__ Wt2,
        const float* __restrict__ x, ushort16* __restrict__ xbf,
        const int* __restrict__ ei, int* __restrict__ counts) {
    int bid = blockIdx.x, t = threadIdx.x;
    if (bid < 256) {
        __shared__ float sh0[256], sh1[256];
        float s0 = 0.f, s1 = 0.f;
        for (int e = bid * 256 + t; e < Ee; e += 256 * 256) {
            s0 += ea[2 * e];
            s1 += ea[2 * e + 1];
        }
        sh0[t] = s0; sh1[t] = s1;
        __syncthreads();
        for (int off = 128; off > 0; off >>= 1) {
            if (t < off) { sh0[t] += sh0[t + off]; sh1[t] += sh1[t + off]; }
            __syncthreads();
        }
        if (t == 0) { atomicAdd(&ea_s[0], sh0[0]); atomicAdd(&ea_s[1], sh1[0]); }
    } else if (bid == 256) {
        if (t >= 18) return;
        int l = t < 8 ? 0 : (t < 16 ? 1 : 2);
        int r = t - l * 8;
        const float* We = (l == 0) ? We0 : (l == 1 ? We1 : We2);
        const float* ae = (l == 0) ? ae0 : (l == 1 ? ae1 : ae2);
        int Hl = (l < 2) ? 4 : 1;
        int Cl = 256 / Hl;
        int d = r / Hl, hh = r % Hl;
        float s = 0.f;
        for (int c = 0; c < Cl; ++c)
            s += We[d * 256 + hh * Cl + c] * ae[hh * Cl + c];
        M[l * 8 + r] = s;
    } else if (bid < 385) {          // W0: cols 0..255, K=128 (KB=4)
        int k = bid - 257;
        WtC[ws_index(t, k, 4)] = f2bf(W0[(long)k * 256 + t]);
    } else if (bid < 513) {          // Wskip: cols 256..511, K=128
        int k = bid - 385;
        WtC[ws_index(256 + t, k, 4)] = f2bf(Wskip[(long)k * 256 + t]);
    } else if (bid < 769) {          // W1: K=256 (KB=8)
        int k = bid - 513;
        Wt1[ws_index(t, k, 8)] = f2bf(W1[(long)k * 256 + t]);
    } else if (bid < 1025) {         // W2
        int k = bid - 769;
        Wt2[ws_index(t, k, 8)] = f2bf(W2[(long)k * 256 + t]);
    } else if (bid < 1025 + CVT_BLKS) {
        int i = (bid - 1025) * 256 + t;
        if (i < CVT4) {
            float4 v = *(const float4*)&x[i * 4];
            ushort4 o;
            o.x = f2bf(v.x); o.y = f2bf(v.y); o.z = f2bf(v.z); o.w = f2bf(v.w);
            *(ushort4*)&xbf[i * 4] = o;
        }
    } else {                         // histogram
        int e = (bid - 1025 - CVT_BLKS) * 256 + t;
        if (e < Etot) {
            int d = (e < Ee) ? ei[Ee + e] : (e - Ee);
            atomicAdd(&counts[d], 1);
        }
    }
}

// ---------------------------------------------------------------------------
// CSR build: scan1 -> scan23 -> scatter
// ---------------------------------------------------------------------------
__global__ void scan1_kernel(const int* __restrict__ in, int* __restrict__ inc,
                             int* __restrict__ bsums) {
    __shared__ int sh[256];
    int i = blockIdx.x * 256 + threadIdx.x;
    int v = (i < Nn) ? in[i] : 0;
    sh[threadIdx.x] = v;
    __syncthreads();
    for (int off = 1; off < 256; off <<= 1) {
        int t = ((int)threadIdx.x >= off) ? sh[threadIdx.x - off] : 0;
        __syncthreads();
        sh[threadIdx.x] += t;
        __syncthreads();
    }
    if (i < Nn) inc[i] = sh[threadIdx.x];
    if (threadIdx.x == 255) bsums[blockIdx.x] = sh[255];
}

__global__ void scan23_kernel(const int* __restrict__ inc, const int* __restrict__ bsums,
                              int* __restrict__ row_start, int* __restrict__ cursor, int nb) {
    __shared__ int sh[256];
    int b = blockIdx.x, t = threadIdx.x;
    sh[t] = (t < b && t < nb) ? bsums[t] : 0;
    __syncthreads();
    for (int off = 128; off > 0; off >>= 1) {
        if (t < off) sh[t] += sh[t + off];
        __syncthreads();
    }
    int base = sh[0];
    int i = b * 256 + t;
    if (i < Nn) {
        int v = inc[i] + base;
        row_start[i + 1] = v;
        cursor[i + 1] = v;
    }
    if (i == 0) { row_start[0] = 0; cursor[0] = 0; }
}

__global__ void scatter_kernel(const int* __restrict__ ei, const float* __restrict__ ea,
                               const float* __restrict__ ea_sum, int* __restrict__ cursor,
                               int* __restrict__ src_sorted, float* __restrict__ ea_sorted) {
    int e = blockIdx.x * blockDim.x + threadIdx.x;
    if (e >= Etot) return;
    int s, d; float e0, e1;
    if (e < Ee) {
        s = ei[e]; d = ei[Ee + e];
        e0 = ea[2 * e]; e1 = ea[2 * e + 1];
    } else {
        s = d = e - Ee;
        const float invE = 1.f / (float)Ee;
        e0 = ea_sum[0] * invE; e1 = ea_sum[1] * invE;
    }
    int pos = atomicAdd(&cursor[d], 1);
    src_sorted[pos] = s;
    ea_sorted[2 * pos]     = e0;
    ea_sorted[2 * pos + 1] = e1;
}

// ---------------------------------------------------------------------------
// MFMA bf16 GEMM, operand-swapped; B read directly from global in
// fragment-swizzled order (L2-resident weights) -> only A goes through LDS.
// Fused attention dots into ssrc/sdst[row*4+part].
// If outS != null: grid.y=4, col blocks 256..511 route to outS (+bskip).
// ---------------------------------------------------------------------------
#define LDK 40
__global__ __launch_bounds__(256) void mfma_gemm_kernel(
        const ushort16* __restrict__ A,   // [n][K] bf16
        const ushort16* __restrict__ WS,  // swizzled weights
        uint32* __restrict__ outF,        // feature out [n][128] packed bf16x2
        uint32* __restrict__ outS,        // skip out (or null)
        const float* __restrict__ bskip,
        const float* __restrict__ a_s, const float* __restrict__ a_d,
        float* __restrict__ ssrc, float* __restrict__ sdst,
        int n, int K) {
    __shared__ ushort16 As[128 * LDK];
    const int t    = threadIdx.x;
    const int row0 = blockIdx.x * 128;
    const int c0   = blockIdx.y * 128;
    const bool isSkip = (outS != nullptr) && (c0 >= 256);
    const int cc0  = isSkip ? c0 - 256 : c0;
    const int wave = t >> 6, lane = t & 63;
    const int wr = wave >> 1, wc = wave & 1;
    const int l15 = lane & 15, quad = lane >> 4;
    const int KB = K >> 5;

    f32x4 acc[4][4];   // acc[j][i]: j = feature-col block, i = node-row block
#pragma unroll
    for (int j = 0; j < 4; ++j)
#pragma unroll
        for (int i = 0; i < 4; ++i) {
            acc[j][i][0] = 0.f; acc[j][i][1] = 0.f;
            acc[j][i][2] = 0.f; acc[j][i][3] = 0.f;
        }

    const int sm = t & 127;
    const int so = t >> 7;

    for (int k0 = 0; k0 < K; k0 += 32) {
        const int kb = k0 >> 5;
#pragma unroll
        for (int h = 0; h < 2; ++h) {
            int oct = so + 2 * h;
            int grow = row0 + sm;
            uint4 va = make_uint4(0, 0, 0, 0);
            if (grow < n) va = *(const uint4*)&A[(long)grow * K + k0 + 8 * oct];
            *(uint4*)&As[sm * LDK + 8 * oct] = va;
        }
        bf16x8 bfv[4];
#pragma unroll
        for (int j = 0; j < 4; ++j) {
            int cb = ((c0 + wc * 64) >> 4) + j;
            bfv[j] = *(const bf16x8*)&WS[(((long)cb * KB + kb) * 64 + lane) << 3];
        }
        __syncthreads();
        bf16x8 af[4];
#pragma unroll
        for (int i = 0; i < 4; ++i)
            af[i] = *(const bf16x8*)&As[(wr * 64 + i * 16 + l15) * LDK + quad * 8];
#pragma unroll
        for (int j = 0; j < 4; ++j)
#pragma unroll
            for (int i = 0; i < 4; ++i)
                acc[j][i] = __builtin_amdgcn_mfma_f32_16x16x32_bf16(
                    bfv[j], af[i], acc[j][i], 0, 0, 0);
        __syncthreads();
    }

    float4 bb[4];
#pragma unroll
    for (int j = 0; j < 4; ++j) {
        if (isSkip) bb[j] = *(const float4*)&bskip[cc0 + wc * 64 + j * 16 + quad * 4];
        else        bb[j] = make_float4(0.f, 0.f, 0.f, 0.f);
    }

    uint32* tgt = isSkip ? outS : outF;
#pragma unroll
    for (int i = 0; i < 4; ++i) {
        int row = row0 + wr * 64 + i * 16 + l15;
        if (row >= n) continue;
#pragma unroll
        for (int j = 0; j < 4; ++j) {
            int col = cc0 + wc * 64 + j * 16 + quad * 4;
            uint2 pk;
            pk.x = pack2(acc[j][i][0] + bb[j].x, acc[j][i][1] + bb[j].y);
            pk.y = pack2(acc[j][i][2] + bb[j].z, acc[j][i][3] + bb[j].w);
            *(uint2*)&tgt[(long)row * 128 + (col >> 1)] = pk;
        }
    }

    if (!isSkip && a_s != nullptr) {
        float4 asv[4], adv[4];
#pragma unroll
        for (int j = 0; j < 4; ++j) {
            int col = cc0 + wc * 64 + j * 16 + quad * 4;
            asv[j] = *(const float4*)&a_s[col];
            adv[j] = *(const float4*)&a_d[col];
        }
        const int part = (cc0 + wc * 64) >> 6;
#pragma unroll
        for (int i = 0; i < 4; ++i) {
            float ps = 0.f, pd = 0.f;
#pragma unroll
            for (int j = 0; j < 4; ++j) {
                ps += acc[j][i][0] * asv[j].x + acc[j][i][1] * asv[j].y
                    + acc[j][i][2] * asv[j].z + acc[j][i][3] * asv[j].w;
                pd += acc[j][i][0] * adv[j].x + acc[j][i][1] * adv[j].y
                    + acc[j][i][2] * adv[j].z + acc[j][i][3] * adv[j].w;
            }
            ps += __shfl_xor(ps, 16); ps += __shfl_xor(ps, 32);
            pd += __shfl_xor(pd, 16); pd += __shfl_xor(pd, 32);
            if (quad == 0) {
                int row = row0 + wr * 64 + i * 16 + l15;
                if (row < n) {
                    ssrc[row * 4 + part] = ps;
                    sdst[row * 4 + part] = pd;
                }
            }
        }
    }
}

// ---------------------------------------------------------------------------
// FUSED softmax + aggregation per dst node. Block = 128 threads (2 waves).
// Wave 0: single-pass edge softmax -> weights in LDS (deg<=256; global
// fallback for larger). Then all 128 threads: weighted gather + bconv + BN
// + ELU + residual(bf16). H==1 sums the 4 partial attn slots.
// ---------------------------------------------------------------------------
template <int H>
__global__ __launch_bounds__(128) void agg_kernel(
        const int* __restrict__ src_sorted, const int* __restrict__ row_start,
        const float* __restrict__ ea_sorted, const float* __restrict__ ssrc,
        const float* __restrict__ sdst, const float* __restrict__ M,
        float* __restrict__ wbig,
        const uint32* __restrict__ hbuf2, const float* __restrict__ bconv,
        const float* __restrict__ bn_g, const float* __restrict__ bn_b,
        const float* __restrict__ bn_m, const float* __restrict__ bn_v,
        const uint32* __restrict__ identity2, uint32* __restrict__ out2) {
    __shared__ float shw[256 * H];
    int node = blockIdx.x;
    int t = threadIdx.x;
    int beg = row_start[node], end = row_start[node + 1];
    int deg = end - beg;
    bool big = deg > 256;

    if (t < 64) {
        int lane = t;
        float sd[H], M0[H], M1[H], m[H], den[H];
        if (H == 4) {
#pragma unroll
            for (int h = 0; h < H; ++h) sd[h] = sdst[node * 4 + h];
        } else {
            float4 v = *(const float4*)&sdst[node * 4];
            sd[0] = v.x + v.y + v.z + v.w;
        }
#pragma unroll
        for (int h = 0; h < H; ++h) {
            M0[h] = M[h]; M1[h] = M[H + h];
            m[h] = -FLT_MAX; den[h] = 0.f;
        }
        auto ssval = [&](int s, int h) -> float {
            if (H == 4) return ssrc[s * 4 + h];
            float4 v = *(const float4*)&ssrc[s * 4];
            return v.x + v.y + v.z + v.w;
        };
        if (!big) {
            float lreg[4][H];
#pragma unroll
            for (int k = 0; k < 4; ++k) {
                int idx = beg + lane + (k << 6);
                if (idx < end) {
                    int s = src_sorted[idx];
                    float e0 = ea_sorted[2 * idx], e1 = ea_sorted[2 * idx + 1];
#pragma unroll
                    for (int h = 0; h < H; ++h) {
                        float l = ssval(s, h) + sd[h] + e0 * M0[h] + e1 * M1[h];
                        l = (l > 0.f) ? l : 0.2f * l;
                        lreg[k][h] = l;
                        if (l > m[h]) { den[h] = den[h] * __expf(m[h] - l) + 1.f; m[h] = l; }
                        else den[h] += __expf(l - m[h]);
                    }
                }
            }
#pragma unroll
            for (int h = 0; h < H; ++h) {
                for (int off = 32; off > 0; off >>= 1) {
                    float om = __shfl_down(m[h], off);
                    float od = __shfl_down(den[h], off);
                    float nm = fmaxf(m[h], om);
                    den[h] = den[h] * __expf(m[h] - nm) + od * __expf(om - nm);
                    m[h] = nm;
                }
                m[h]   = __shfl(m[h], 0);
                den[h] = __shfl(den[h], 0);
                den[h] = 1.f / (den[h] + 1e-16f);
            }
#pragma unroll
            for (int k = 0; k < 4; ++k) {
                int idx = beg + lane + (k << 6);
                if (idx < end) {
#pragma unroll
                    for (int h = 0; h < H; ++h)
                        shw[(idx - beg) * H + h] = __expf(lreg[k][h] - m[h]) * den[h];
                }
            }
        } else {
            for (int idx = beg + lane; idx < end; idx += 64) {
                int s = src_sorted[idx];
                float e0 = ea_sorted[2 * idx], e1 = ea_sorted[2 * idx + 1];
#pragma unroll
                for (int h = 0; h < H; ++h) {
                    float l = ssval(s, h) + sd[h] + e0 * M0[h] + e1 * M1[h];
                    l = (l > 0.f) ? l : 0.2f * l;
                    wbig[(long)idx * H + h] = l;
                    if (l > m[h]) { den[h] = den[h] * __expf(m[h] - l) + 1.f; m[h] = l; }
                    else den[h] += __expf(l - m[h]);
                }
            }
#pragma unroll
            for (int h = 0; h < H; ++h) {
                for (int off = 32; off > 0; off >>= 1) {
                    float om = __shfl_down(m[h], off);
                    float od = __shfl_down(den[h], off);
                    float nm = fmaxf(m[h], om);
                    den[h] = den[h] * __expf(m[h] - nm) + od * __expf(om - nm);
                    m[h] = nm;
                }
                m[h]   = __shfl(m[h], 0);
                den[h] = __shfl(den[h], 0);
                den[h] = 1.f / (den[h] + 1e-16f);
            }
            for (int idx = beg + lane; idx < end; idx += 64) {
#pragma unroll
                for (int h = 0; h < H; ++h) {
                    float l = wbig[(long)idx * H + h];
                    wbig[(long)idx * H + h] = __expf(l - m[h]) * den[h];
                }
            }
        }
    }
    __syncthreads();

    // gather phase (all 128 threads)
    int c2 = t;
    const int C2 = 128 / H;
    int hh = c2 / C2;
    float a0 = 0.f, a1 = 0.f;
    for (int idx = beg; idx < end; idx += 4) {
        int   s[4];
        float ww[4];
#pragma unroll
        for (int k = 0; k < 4; ++k) {
            int j = idx + k;
            bool ok = j < end;
            int jj = ok ? j : beg;
            s[k]  = src_sorted[jj];
            float wv = big ? wbig[(long)jj * H + hh] : shw[(jj - beg) * H + hh];
            ww[k] = ok ? wv : 0.f;
        }
#pragma unroll
        for (int k = 0; k < 4; ++k) {
            uint32 u = hbuf2[(long)s[k] * 128 + c2];
            float lo = __uint_as_float(u << 16);
            float hi = __uint_as_float(u & 0xffff0000u);
            a0 += ww[k] * lo;
            a1 += ww[k] * hi;
        }
    }
    int c = 2 * c2;
    float v0 = a0 + bconv[c];
    float v1 = a1 + bconv[c + 1];
    v0 = (v0 - bn_m[c])     * rsqrtf(bn_v[c]     + BN_EPS) * bn_g[c]     + bn_b[c];
    v1 = (v1 - bn_m[c + 1]) * rsqrtf(bn_v[c + 1] + BN_EPS) * bn_g[c + 1] + bn_b[c + 1];
    v0 = (v0 > 0.f) ? v0 : (expf(v0) - 1.f);
    v1 = (v1 > 0.f) ? v1 : (expf(v1) - 1.f);
    uint32 idu = identity2[(long)node * 128 + c2];
    v0 += __uint_as_float(idu << 16);
    v1 += __uint_as_float(idu & 0xffff0000u);
    out2[(long)node * 128 + c2] = pack2(v0, v1);
}

// ---------------------------------------------------------------------------
// pooling (bf16 input; pmax uses monotone-uint atomicMax, init by memset 0)
// ---------------------------------------------------------------------------
#define POOL_ROWS 32
__global__ __launch_bounds__(128) void pool_kernel(
        const uint32* __restrict__ x2, const int* __restrict__ batch,
        float* __restrict__ psum, uint32* __restrict__ pmax, float* __restrict__ pcnt) {
    int c2 = threadIdx.x;
    int n0 = blockIdx.x * POOL_ROWS;
    if (n0 >= Nn) return;
    int n1 = min(n0 + POOL_ROWS, Nn);
    int cur = batch[n0];
    float s0 = 0.f, s1 = 0.f, m0 = -FLT_MAX, m1 = -FLT_MAX;
    int cnt = 0;
    int c = 2 * c2;
    for (int i = n0; i < n1; ++i) {
        int g = batch[i];
        if (g != cur) {
            atomicAdd(&psum[cur * 256 + c], s0);
            atomicAdd(&psum[cur * 256 + c + 1], s1);
            atomicMax(&pmax[cur * 256 + c], fenc(m0));
            atomicMax(&pmax[cur * 256 + c + 1], fenc(m1));
            if (c2 == 0) atomicAdd(&pcnt[cur], (float)cnt);
            cur = g; s0 = s1 = 0.f; m0 = m1 = -FLT_MAX; cnt = 0;
        }
        uint32 u = x2[(long)i * 128 + c2];
        float lo = __uint_as_float(u << 16);
        float hi = __uint_as_float(u & 0xffff0000u);
        s0 += lo; s1 += hi;
        m0 = fmaxf(m0, lo); m1 = fmaxf(m1, hi);
        ++cnt;
    }
    atomicAdd(&psum[cur * 256 + c], s0);
    atomicAdd(&psum[cur * 256 + c + 1], s1);
    atomicMax(&pmax[cur * 256 + c], fenc(m0));
    atomicMax(&pmax[cur * 256 + c + 1], fenc(m1));
    if (c2 == 0) atomicAdd(&pcnt[cur], (float)cnt);
}

// ---------------------------------------------------------------------------
// head MLP: relu(emb @ Wp1 + bp1) @ Wp2 + bp2  -> out[g]
// ---------------------------------------------------------------------------
__global__ __launch_bounds__(256) void mlp_kernel(
        const float* __restrict__ psum, const uint32* __restrict__ pmax,
        const float* __restrict__ pcnt, const float* __restrict__ Wp1,
        const float* __restrict__ bp1, const float* __restrict__ Wp2,
        const float* __restrict__ bp2, float* __restrict__ out) {
    int g = blockIdx.x;
    int j = threadIdx.x;
    float inv = 1.f / fmaxf(pcnt[g], 1.f);
    float acc = bp1[j];
    for (int k = 0; k < 256; ++k)
        acc += (psum[g * 256 + k] * inv) * Wp1[k * 256 + j];
    for (int k = 0; k < 256; ++k)
        acc += fdec(pmax[g * 256 + k]) * Wp1[(256 + k) * 256 + j];
    float v = fmaxf(acc, 0.f) * Wp2[j];
    __shared__ float red[256];
    red[j] = v;
    __syncthreads();
    for (int off = 128; off > 0; off >>= 1) {
        if (j < off) red[j] += red[j + off];
        __syncthreads();
    }
    if (j == 0) out[g] = red[0] + bp2[0];
}

// ---------------------------------------------------------------------------
// launch
// ---------------------------------------------------------------------------
extern "C" void kernel_launch(void* const* d_in, const int* in_sizes, int n_in,
                              void* d_out, int out_size, void* d_ws, size_t ws_size,
                              hipStream_t stream) {
    const float* x   = (const float*)d_in[0];
    const int*   ei  = (const int*)d_in[1];
    const float* ea  = (const float*)d_in[2];
    const int*   bat = (const int*)d_in[3];
    auto LP = [&](int l, int j) { return (const float*)d_in[4 + l * 10 + j]; };
    const float* Wskip = (const float*)d_in[34];
    const float* bskip = (const float*)d_in[35];
    const float* Wp1   = (const float*)d_in[36];
    const float* bp1   = (const float*)d_in[37];
    const float* Wp2   = (const float*)d_in[38];
    const float* bp2   = (const float*)d_in[39];
    float* out = (float*)d_out;

    // workspace carve-up (256B aligned)
    char* p = (char*)d_ws;
    auto alloc = [&](size_t bytes) { void* r = (void*)p; p += (bytes + 255) & ~(size_t)255; return r; };
    uint32*   hbuf2  = (uint32*)alloc((size_t)Nn * 256 * 2);   // bf16 features [n][128] packed
    uint32*   skipbf = (uint32*)alloc((size_t)Nn * 128 * 4);   // bf16 skip residual
    uint32*   resA   = (uint32*)alloc((size_t)Nn * 128 * 4);   // bf16 residual streams
    uint32*   resB   = (uint32*)alloc((size_t)Nn * 128 * 4);
    ushort16* xbf    = (ushort16*)alloc((size_t)Nn * 128 * 2); // bf16 x [n][128]
    float*    wbuf   = (float*)alloc((size_t)Etot * 4 * 4);    // big-deg fallback weights
    float*    ea_sorted = (float*)alloc((size_t)Etot * 2 * 4);
    float*    ssrc   = (float*)alloc((size_t)Nn * 4 * 4);      // 4 partial slots
    float*    sdst   = (float*)alloc((size_t)Nn * 4 * 4);
    int*      counts = (int*)alloc((size_t)Nn * 4);
    int*      incb   = (int*)alloc((size_t)Nn * 4);
    int*      row_start = (int*)alloc((size_t)(Nn + 1) * 4);
    int*      cursor    = (int*)alloc((size_t)(Nn + 1) * 4);
    int*      src_sorted = (int*)alloc((size_t)Etot * 4);
    int*      bsums  = (int*)alloc(256 * 4);
    float*    ea_s   = (float*)alloc(2 * 4);
    float*    Mbuf   = (float*)alloc(32 * 4);
    ushort16* WtC    = (ushort16*)alloc((size_t)512 * 128 * 2); // W0 | Wskip swizzled
    ushort16* Wt1    = (ushort16*)alloc((size_t)256 * 256 * 2);
    ushort16* Wt2    = (ushort16*)alloc((size_t)256 * 256 * 2);
    float*    psum   = (float*)alloc((size_t)Gg * 256 * 4);    // psum|pmax|pcnt contiguous
    uint32*   pmax   = (uint32*)alloc((size_t)Gg * 256 * 4);
    float*    pcnt   = (float*)alloc((size_t)Gg * 4);

    const int nb = (Nn + 255) / 256;

    // zero init
    hipMemsetAsync(counts, 0, (size_t)Nn * 4, stream);
    hipMemsetAsync(ea_s, 0, 8, stream);
    hipMemsetAsync(psum, 0, (size_t)Gg * 256 * 4 * 2 + (size_t)Gg * 4, stream);

    // one prep dispatch: ea_sum + M + W swizzles + x->bf16 + histogram
    prep_kernel<<<1025 + CVT_BLKS + EBKS, 256, 0, stream>>>(
        ea, ea_s, LP(0,3), LP(0,4), LP(1,3), LP(1,4), LP(2,3), LP(2,4), Mbuf,
        LP(0,0), Wskip, LP(1,0), LP(2,0), WtC, Wt1, Wt2, x, xbf, ei, counts);

    // CSR
    scan1_kernel<<<nb, 256, 0, stream>>>(counts, incb, bsums);
    scan23_kernel<<<nb, 256, 0, stream>>>(incb, bsums, row_start, cursor, nb);
    scatter_kernel<<<EBKS, 256, 0, stream>>>(ei, ea, ea_s, cursor, src_sorted, ea_sorted);

    // fused layer-0 GEMM + skip projection + attn dots
    {
        dim3 g0((Nn + 127) / 128, 4);
        mfma_gemm_kernel<<<g0, 256, 0, stream>>>(
            xbf, WtC, hbuf2, skipbf, bskip,
            LP(0,1), LP(0,2), ssrc, sdst, Nn, 128);
    }

    // layers
    const uint32* lid[3] = { skipbf, resA, resB };
    uint32*       lou[3] = { resA, resB, resA };
    const int     Hh[3]  = { 4, 4, 1 };
    const ushort16* lain[3] = { nullptr, (ushort16*)resA, (ushort16*)resB };
    const ushort16* lwt[3]  = { nullptr, Wt1, Wt2 };
    for (int l = 0; l < 3; ++l) {
        const int H = Hh[l];
        if (l > 0) {
            dim3 gl((Nn + 127) / 128, 2);
            mfma_gemm_kernel<<<gl, 256, 0, stream>>>(
                lain[l], lwt[l], hbuf2, nullptr, nullptr,
                LP(l,1), LP(l,2), ssrc, sdst, Nn, 256);
        }
        if (H == 4)
            agg_kernel<4><<<Nn, 128, 0, stream>>>(
                src_sorted, row_start, ea_sorted, ssrc, sdst, Mbuf + l * 8, wbuf,
                hbuf2, LP(l,5), LP(l,6), LP(l,7), LP(l,8), LP(l,9), lid[l], lou[l]);
        else
            agg_kernel<1><<<Nn, 128, 0, stream>>>(
                src_sorted, row_start, ea_sorted, ssrc, sdst, Mbuf + l * 8, wbuf,
                hbuf2, LP(l,5), LP(l,6), LP(l,7), LP(l,8), LP(l,9), lid[l], lou[l]);
    }

    // pooling + head (final x = resA, bf16-packed)
    pool_kernel<<<(Nn + POOL_ROWS - 1) / POOL_ROWS, 128, 0, stream>>>(resA, bat, psum, pmax, pcnt);
    mlp_kernel<<<Gg, 256, 0, stream>>>(psum, pmax, pcnt, Wp1, bp1, Wp2, bp2, out);
}

// Round 12
// 705.044 us; speedup vs baseline: 3.8542x; 1.0056x over previous
//
#include <hip/hip_runtime.h>
#include <cfloat>

// Problem constants (match reference setup_inputs)
#define Nn 50000
#define Ee 800000
#define Etot (Ee + Nn)   // edges + self loops = 850000
#define Gg 64
#define HIDc 256
#define BN_EPS 1e-5f

typedef unsigned int   uint32;
typedef unsigned short ushort16;
typedef short  bf16x8 __attribute__((ext_vector_type(8)));
typedef float  f32x4  __attribute__((ext_vector_type(4)));

// ---------------------------------------------------------------------------
// helpers
// ---------------------------------------------------------------------------
__device__ inline ushort16 f2bf(float f) {            // RNE fp32 -> bf16
    uint32 u = __float_as_uint(f);
    u = (u + 0x7fffu + ((u >> 16) & 1u)) >> 16;
    return (ushort16)u;
}
__device__ inline uint32 pack2(float a, float b) {
    return (uint32)f2bf(a) | ((uint32)f2bf(b) << 16);
}
// monotone float<->uint encoding for atomicMax-based float max
__device__ inline uint32 fenc(float f) {
    uint32 b = __float_as_uint(f);
    return (b & 0x80000000u) ? ~b : (b | 0x80000000u);
}
__device__ inline float fdec(uint32 u) {
    uint32 b = (u & 0x80000000u) ? (u & 0x7fffffffu) : ~u;
    return __uint_as_float(b);
}

// W swizzle to MFMA A-operand fragment order:
// WS[((cb*KB + kb)*64 + q*16 + m)*8 + e]  where cb=c>>4, m=c&15,
// kb=k>>5, q=(k>>3)&3, e=k&7.  A wave then reads 64 lanes x 16B contiguous.
__device__ inline long ws_index(int c, int k, int KB) {
    int cb = c >> 4, m = c & 15, kb = k >> 5, q = (k >> 3) & 3, e = k & 7;
    return (((long)(cb * KB + kb) * 64 + q * 16 + m) << 3) + e;
}

// ---------------------------------------------------------------------------
// prep kernel: ea_sum | M | W swizzles | x->bf16 | hist   (one dispatch)
// ---------------------------------------------------------------------------
#define CVT4 (Nn * 128 / 4)
#define CVT_BLKS ((CVT4 + 255) / 256)
#define EBKS ((Etot + 255) / 256)
__global__ __launch_bounds__(256) void prep_kernel(
        const float* __restrict__ ea, float* __restrict__ ea_s,
        const float* __restrict__ We0, const float* __restrict__ ae0,
        const float* __restrict__ We1, const float* __restrict__ ae1,
        const float* __restrict__ We2, const float* __restrict__ ae2,
        float* __restrict__ M,
        const float* __restrict__ W0, const float* __restrict__ Wskip,
        const float* __restrict__ W1, const float* __restrict__ W2,
        ushort16* __restrict__ WtC, ushort16* __restrict__ Wt1,
        ushort16* __restrict__ Wt2,
        const float* __restrict__ x, ushort16* __restrict__ xbf,
        const int* __restrict__ ei, int* __restrict__ counts) {
    int bid = blockIdx.x, t = threadIdx.x;
    if (bid < 256) {
        __shared__ float sh0[256], sh1[256];
        float s0 = 0.f, s1 = 0.f;
        for (int e = bid * 256 + t; e < Ee; e += 256 * 256) {
            s0 += ea[2 * e];
            s1 += ea[2 * e + 1];
        }
        sh0[t] = s0; sh1[t] = s1;
        __syncthreads();
        for (int off = 128; off > 0; off >>= 1) {
            if (t < off) { sh0[t] += sh0[t + off]; sh1[t] += sh1[t + off]; }
            __syncthreads();
        }
        if (t == 0) { atomicAdd(&ea_s[0], sh0[0]); atomicAdd(&ea_s[1], sh1[0]); }
    } else if (bid == 256) {
        if (t >= 18) return;
        int l = t < 8 ? 0 : (t < 16 ? 1 : 2);
        int r = t - l * 8;
        const float* We = (l == 0) ? We0 : (l == 1 ? We1 : We2);
        const float* ae = (l == 0) ? ae0 : (l == 1 ? ae1 : ae2);
        int Hl = (l < 2) ? 4 : 1;
        int Cl = 256 / Hl;
        int d = r / Hl, hh = r % Hl;
        float s = 0.f;
        for (int c = 0; c < Cl; ++c)
            s += We[d * 256 + hh * Cl + c] * ae[hh * Cl + c];
        M[l * 8 + r] = s;
    } else if (bid < 385) {          // W0: cols 0..255, K=128 (KB=4)
        int k = bid - 257;
        WtC[ws_index(t, k, 4)] = f2bf(W0[(long)k * 256 + t]);
    } else if (bid < 513) {          // Wskip: cols 256..511, K=128
        int k = bid - 385;
        WtC[ws_index(256 + t, k, 4)] = f2bf(Wskip[(long)k * 256 + t]);
    } else if (bid < 769) {          // W1: K=256 (KB=8)
        int k = bid - 513;
        Wt1[ws_index(t, k, 8)] = f2bf(W1[(long)k * 256 + t]);
    } else if (bid < 1025) {         // W2
        int k = bid - 769;
        Wt2[ws_index(t, k, 8)] = f2bf(W2[(long)k * 256 + t]);
    } else if (bid < 1025 + CVT_BLKS) {
        int i = (bid - 1025) * 256 + t;
        if (i < CVT4) {
            float4 v = *(const float4*)&x[i * 4];
            ushort4 o;
            o.x = f2bf(v.x); o.y = f2bf(v.y); o.z = f2bf(v.z); o.w = f2bf(v.w);
            *(ushort4*)&xbf[i * 4] = o;
        }
    } else {                         // histogram
        int e = (bid - 1025 - CVT_BLKS) * 256 + t;
        if (e < Etot) {
            int d = (e < Ee) ? ei[Ee + e] : (e - Ee);
            atomicAdd(&counts[d], 1);
        }
    }
}

// ---------------------------------------------------------------------------
// CSR build: scan1 -> scan23 -> scatter
// ---------------------------------------------------------------------------
__global__ void scan1_kernel(const int* __restrict__ in, int* __restrict__ inc,
                             int* __restrict__ bsums) {
    __shared__ int sh[256];
    int i = blockIdx.x * 256 + threadIdx.x;
    int v = (i < Nn) ? in[i] : 0;
    sh[threadIdx.x] = v;
    __syncthreads();
    for (int off = 1; off < 256; off <<= 1) {
        int t = ((int)threadIdx.x >= off) ? sh[threadIdx.x - off] : 0;
        __syncthreads();
        sh[threadIdx.x] += t;
        __syncthreads();
    }
    if (i < Nn) inc[i] = sh[threadIdx.x];
    if (threadIdx.x == 255) bsums[blockIdx.x] = sh[255];
}

__global__ void scan23_kernel(const int* __restrict__ inc, const int* __restrict__ bsums,
                              int* __restrict__ row_start, int* __restrict__ cursor, int nb) {
    __shared__ int sh[256];
    int b = blockIdx.x, t = threadIdx.x;
    sh[t] = (t < b && t < nb) ? bsums[t] : 0;
    __syncthreads();
    for (int off = 128; off > 0; off >>= 1) {
        if (t < off) sh[t] += sh[t + off];
        __syncthreads();
    }
    int base = sh[0];
    int i = b * 256 + t;
    if (i < Nn) {
        int v = inc[i] + base;
        row_start[i + 1] = v;
        cursor[i + 1] = v;
    }
    if (i == 0) { row_start[0] = 0; cursor[0] = 0; }
}

__global__ void scatter_kernel(const int* __restrict__ ei, const float* __restrict__ ea,
                               const float* __restrict__ ea_sum, int* __restrict__ cursor,
                               int* __restrict__ src_sorted, float* __restrict__ ea_sorted) {
    int e = blockIdx.x * blockDim.x + threadIdx.x;
    if (e >= Etot) return;
    int s, d; float e0, e1;
    if (e < Ee) {
        s = ei[e]; d = ei[Ee + e];
        e0 = ea[2 * e]; e1 = ea[2 * e + 1];
    } else {
        s = d = e - Ee;
        const float invE = 1.f / (float)Ee;
        e0 = ea_sum[0] * invE; e1 = ea_sum[1] * invE;
    }
    int pos = atomicAdd(&cursor[d], 1);
    src_sorted[pos] = s;
    ea_sorted[2 * pos]     = e0;
    ea_sorted[2 * pos + 1] = e1;
}

// ---------------------------------------------------------------------------
// MFMA bf16 GEMM, operand-swapped; B read directly from global in
// fragment-swizzled order (L2-resident weights) -> only A goes through LDS.
// Fused attention dots into ssrc/sdst[row*4+part].
// If outS != null: grid.y=4, col blocks 256..511 route to outS (+bskip).
// ---------------------------------------------------------------------------
#define LDK 40
__global__ __launch_bounds__(256) void mfma_gemm_kernel(
        const ushort16* __restrict__ A,   // [n][K] bf16
        const ushort16* __restrict__ WS,  // swizzled weights
        uint32* __restrict__ outF,        // feature out [n][128] packed bf16x2
        uint32* __restrict__ outS,        // skip out (or null)
        const float* __restrict__ bskip,
        const float* __restrict__ a_s, const float* __restrict__ a_d,
        float* __restrict__ ssrc, float* __restrict__ sdst,
        int n, int K) {
    __shared__ ushort16 As[128 * LDK];
    const int t    = threadIdx.x;
    const int row0 = blockIdx.x * 128;
    const int c0   = blockIdx.y * 128;
    const bool isSkip = (outS != nullptr) && (c0 >= 256);
    const int cc0  = isSkip ? c0 - 256 : c0;
    const int wave = t >> 6, lane = t & 63;
    const int wr = wave >> 1, wc = wave & 1;
    const int l15 = lane & 15, quad = lane >> 4;
    const int KB = K >> 5;

    f32x4 acc[4][4];   // acc[j][i]: j = feature-col block, i = node-row block
#pragma unroll
    for (int j = 0; j < 4; ++j)
#pragma unroll
        for (int i = 0; i < 4; ++i) {
            acc[j][i][0] = 0.f; acc[j][i][1] = 0.f;
            acc[j][i][2] = 0.f; acc[j][i][3] = 0.f;
        }

    const int sm = t & 127;
    const int so = t >> 7;

    for (int k0 = 0; k0 < K; k0 += 32) {
        const int kb = k0 >> 5;
#pragma unroll
        for (int h = 0; h < 2; ++h) {
            int oct = so + 2 * h;
            int grow = row0 + sm;
            uint4 va = make_uint4(0, 0, 0, 0);
            if (grow < n) va = *(const uint4*)&A[(long)grow * K + k0 + 8 * oct];
            *(uint4*)&As[sm * LDK + 8 * oct] = va;
        }
        bf16x8 bfv[4];
#pragma unroll
        for (int j = 0; j < 4; ++j) {
            int cb = ((c0 + wc * 64) >> 4) + j;
            bfv[j] = *(const bf16x8*)&WS[(((long)cb * KB + kb) * 64 + lane) << 3];
        }
        __syncthreads();
        bf16x8 af[4];
#pragma unroll
        for (int i = 0; i < 4; ++i)
            af[i] = *(const bf16x8*)&As[(wr * 64 + i * 16 + l15) * LDK + quad * 8];
#pragma unroll
        for (int j = 0; j < 4; ++j)
#pragma unroll
            for (int i = 0; i < 4; ++i)
                acc[j][i] = __builtin_amdgcn_mfma_f32_16x16x32_bf16(
                    bfv[j], af[i], acc[j][i], 0, 0, 0);
        __syncthreads();
    }

    float4 bb[4];
#pragma unroll
    for (int j = 0; j < 4; ++j) {
        if (isSkip) bb[j] = *(const float4*)&bskip[cc0 + wc * 64 + j * 16 + quad * 4];
        else        bb[j] = make_float4(0.f, 0.f, 0.f, 0.f);
    }

    uint32* tgt = isSkip ? outS : outF;
#pragma unroll
    for (int i = 0; i < 4; ++i) {
        int row = row0 + wr * 64 + i * 16 + l15;
        if (row >= n) continue;
#pragma unroll
        for (int j = 0; j < 4; ++j) {
            int col = cc0 + wc * 64 + j * 16 + quad * 4;
            uint2 pk;
            pk.x = pack2(acc[j][i][0] + bb[j].x, acc[j][i][1] + bb[j].y);
            pk.y = pack2(acc[j][i][2] + bb[j].z, acc[j][i][3] + bb[j].w);
            *(uint2*)&tgt[(long)row * 128 + (col >> 1)] = pk;
        }
    }

    if (!isSkip && a_s != nullptr) {
        float4 asv[4], adv[4];
#pragma unroll
        for (int j = 0; j < 4; ++j) {
            int col = cc0 + wc * 64 + j * 16 + quad * 4;
            asv[j] = *(const float4*)&a_s[col];
            adv[j] = *(const float4*)&a_d[col];
        }
        const int part = (cc0 + wc * 64) >> 6;
#pragma unroll
        for (int i = 0; i < 4; ++i) {
            float ps = 0.f, pd = 0.f;
#pragma unroll
            for (int j = 0; j < 4; ++j) {
                ps += acc[j][i][0] * asv[j].x + acc[j][i][1] * asv[j].y
                    + acc[j][i][2] * asv[j].z + acc[j][i][3] * asv[j].w;
                pd += acc[j][i][0] * adv[j].x + acc[j][i][1] * adv[j].y
                    + acc[j][i][2] * adv[j].z + acc[j][i][3] * adv[j].w;
            }
            ps += __shfl_xor(ps, 16); ps += __shfl_xor(ps, 32);
            pd += __shfl_xor(pd, 16); pd += __shfl_xor(pd, 32);
            if (quad == 0) {
                int row = row0 + wr * 64 + i * 16 + l15;
                if (row < n) {
                    ssrc[row * 4 + part] = ps;
                    sdst[row * 4 + part] = pd;
                }
            }
        }
    }
}

// ---------------------------------------------------------------------------
// fused edge logits + segment softmax, one wave per dst node, CSR order.
// Single-pass: logits cached in registers (deg<=256), one write of w.
// H==1 sums the 4 partial slots of ssrc/sdst.
// ---------------------------------------------------------------------------
template <int H>
__global__ __launch_bounds__(256) void edge_softmax_kernel(
        const int* __restrict__ src_sorted, const int* __restrict__ row_start,
        const float* __restrict__ ea_sorted, const float* __restrict__ ssrc,
        const float* __restrict__ sdst, const float* __restrict__ M,
        float* __restrict__ w) {
    int node = (blockIdx.x * blockDim.x + threadIdx.x) >> 6;
    int lane = threadIdx.x & 63;
    if (node >= Nn) return;
    int beg = row_start[node], end = row_start[node + 1];
    int deg = end - beg;
    float sd[H], M0[H], M1[H], m[H], den[H];
    if (H == 4) {
#pragma unroll
        for (int h = 0; h < H; ++h) sd[h] = sdst[node * 4 + h];
    } else {
        float4 v = *(const float4*)&sdst[node * 4];
        sd[0] = v.x + v.y + v.z + v.w;
    }
#pragma unroll
    for (int h = 0; h < H; ++h) {
        M0[h] = M[h]; M1[h] = M[H + h];
        m[h] = -FLT_MAX; den[h] = 0.f;
    }
    auto ssval = [&](int s, int h) -> float {
        if (H == 4) return ssrc[s * 4 + h];
        float4 v = *(const float4*)&ssrc[s * 4];
        return v.x + v.y + v.z + v.w;
    };
    if (deg <= 256) {
        float lreg[4][H];
#pragma unroll
        for (int k = 0; k < 4; ++k) {
            int idx = beg + lane + (k << 6);
            if (idx < end) {
                int s = src_sorted[idx];
                float e0 = ea_sorted[2 * idx], e1 = ea_sorted[2 * idx + 1];
#pragma unroll
                for (int h = 0; h < H; ++h) {
                    float l = ssval(s, h) + sd[h] + e0 * M0[h] + e1 * M1[h];
                    l = (l > 0.f) ? l : 0.2f * l;
                    lreg[k][h] = l;
                    if (l > m[h]) { den[h] = den[h] * __expf(m[h] - l) + 1.f; m[h] = l; }
                    else den[h] += __expf(l - m[h]);
                }
            }
        }
#pragma unroll
        for (int h = 0; h < H; ++h) {
            for (int off = 32; off > 0; off >>= 1) {
                float om = __shfl_down(m[h], off);
                float od = __shfl_down(den[h], off);
                float nm = fmaxf(m[h], om);
                den[h] = den[h] * __expf(m[h] - nm) + od * __expf(om - nm);
                m[h] = nm;
            }
            m[h]   = __shfl(m[h], 0);
            den[h] = __shfl(den[h], 0);
            den[h] = 1.f / (den[h] + 1e-16f);
        }
#pragma unroll
        for (int k = 0; k < 4; ++k) {
            int idx = beg + lane + (k << 6);
            if (idx < end) {
#pragma unroll
                for (int h = 0; h < H; ++h)
                    w[(long)idx * H + h] = __expf(lreg[k][h] - m[h]) * den[h];
            }
        }
    } else {
        // 2-pass fallback
        for (int idx = beg + lane; idx < end; idx += 64) {
            int s = src_sorted[idx];
            float e0 = ea_sorted[2 * idx], e1 = ea_sorted[2 * idx + 1];
#pragma unroll
            for (int h = 0; h < H; ++h) {
                float l = ssval(s, h) + sd[h] + e0 * M0[h] + e1 * M1[h];
                l = (l > 0.f) ? l : 0.2f * l;
                w[(long)idx * H + h] = l;
                if (l > m[h]) { den[h] = den[h] * __expf(m[h] - l) + 1.f; m[h] = l; }
                else den[h] += __expf(l - m[h]);
            }
        }
#pragma unroll
        for (int h = 0; h < H; ++h) {
            for (int off = 32; off > 0; off >>= 1) {
                float om = __shfl_down(m[h], off);
                float od = __shfl_down(den[h], off);
                float nm = fmaxf(m[h], om);
                den[h] = den[h] * __expf(m[h] - nm) + od * __expf(om - nm);
                m[h] = nm;
            }
            m[h]   = __shfl(m[h], 0);
            den[h] = __shfl(den[h], 0);
            den[h] = 1.f / (den[h] + 1e-16f);
        }
        for (int idx = beg + lane; idx < end; idx += 64) {
#pragma unroll
            for (int h = 0; h < H; ++h) {
                float l = w[(long)idx * H + h];
                w[(long)idx * H + h] = __expf(l - m[h]) * den[h];
            }
        }
    }
}

// ---------------------------------------------------------------------------
// weighted gather (bf16 features) + bconv + BN + ELU + residual(bf16).
// 128 threads/node; thread c2 handles channels 2c2,2c2+1 (packed bf16x2).
// ---------------------------------------------------------------------------
__global__ __launch_bounds__(128) void agg_kernel(
        const int* __restrict__ src_sorted, const int* __restrict__ row_start,
        const uint32* __restrict__ hbuf2, const float* __restrict__ w,
        const float* __restrict__ bconv,
        const float* __restrict__ bn_g, const float* __restrict__ bn_b,
        const float* __restrict__ bn_m, const float* __restrict__ bn_v,
        const uint32* __restrict__ identity2, uint32* __restrict__ out2, int H) {
    int node = blockIdx.x;
    int c2 = threadIdx.x;            // 0..127
    int C2 = 128 / H;
    int hh = c2 / C2;
    int beg = row_start[node], end = row_start[node + 1];
    float a0 = 0.f, a1 = 0.f;
    for (int idx = beg; idx < end; idx += 4) {
        int   s[4];
        float ww[4];
#pragma unroll
        for (int k = 0; k < 4; ++k) {
            int j = idx + k;
            bool ok = j < end;
            int jj = ok ? j : beg;
            s[k]  = src_sorted[jj];
            ww[k] = ok ? w[(long)jj * H + hh] : 0.f;
        }
#pragma unroll
        for (int k = 0; k < 4; ++k) {
            uint32 u = hbuf2[(long)s[k] * 128 + c2];
            float lo = __uint_as_float(u << 16);
            float hi = __uint_as_float(u & 0xffff0000u);
            a0 += ww[k] * lo;
            a1 += ww[k] * hi;
        }
    }
    int c = 2 * c2;
    float v0 = a0 + bconv[c];
    float v1 = a1 + bconv[c + 1];
    v0 = (v0 - bn_m[c])     * rsqrtf(bn_v[c]     + BN_EPS) * bn_g[c]     + bn_b[c];
    v1 = (v1 - bn_m[c + 1]) * rsqrtf(bn_v[c + 1] + BN_EPS) * bn_g[c + 1] + bn_b[c + 1];
    v0 = (v0 > 0.f) ? v0 : (expf(v0) - 1.f);
    v1 = (v1 > 0.f) ? v1 : (expf(v1) - 1.f);
    uint32 idu = identity2[(long)node * 128 + c2];
    v0 += __uint_as_float(idu << 16);
    v1 += __uint_as_float(idu & 0xffff0000u);
    out2[(long)node * 128 + c2] = pack2(v0, v1);
}

// ---------------------------------------------------------------------------
// pooling (bf16 input; pmax uses monotone-uint atomicMax, init by memset 0)
// ---------------------------------------------------------------------------
#define POOL_ROWS 32
__global__ __launch_bounds__(128) void pool_kernel(
        const uint32* __restrict__ x2, const int* __restrict__ batch,
        float* __restrict__ psum, uint32* __restrict__ pmax, float* __restrict__ pcnt) {
    int c2 = threadIdx.x;
    int n0 = blockIdx.x * POOL_ROWS;
    if (n0 >= Nn) return;
    int n1 = min(n0 + POOL_ROWS, Nn);
    int cur = batch[n0];
    float s0 = 0.f, s1 = 0.f, m0 = -FLT_MAX, m1 = -FLT_MAX;
    int cnt = 0;
    int c = 2 * c2;
    for (int i = n0; i < n1; ++i) {
        int g = batch[i];
        if (g != cur) {
            atomicAdd(&psum[cur * 256 + c], s0);
            atomicAdd(&psum[cur * 256 + c + 1], s1);
            atomicMax(&pmax[cur * 256 + c], fenc(m0));
            atomicMax(&pmax[cur * 256 + c + 1], fenc(m1));
            if (c2 == 0) atomicAdd(&pcnt[cur], (float)cnt);
            cur = g; s0 = s1 = 0.f; m0 = m1 = -FLT_MAX; cnt = 0;
        }
        uint32 u = x2[(long)i * 128 + c2];
        float lo = __uint_as_float(u << 16);
        float hi = __uint_as_float(u & 0xffff0000u);
        s0 += lo; s1 += hi;
        m0 = fmaxf(m0, lo); m1 = fmaxf(m1, hi);
        ++cnt;
    }
    atomicAdd(&psum[cur * 256 + c], s0);
    atomicAdd(&psum[cur * 256 + c + 1], s1);
    atomicMax(&pmax[cur * 256 + c], fenc(m0));
    atomicMax(&pmax[cur * 256 + c + 1], fenc(m1));
    if (c2 == 0) atomicAdd(&pcnt[cur], (float)cnt);
}

// ---------------------------------------------------------------------------
// head MLP: relu(emb @ Wp1 + bp1) @ Wp2 + bp2  -> out[g]
// ---------------------------------------------------------------------------
__global__ __launch_bounds__(256) void mlp_kernel(
        const float* __restrict__ psum, const uint32* __restrict__ pmax,
        const float* __restrict__ pcnt, const float* __restrict__ Wp1,
        const float* __restrict__ bp1, const float* __restrict__ Wp2,
        const float* __restrict__ bp2, float* __restrict__ out) {
    int g = blockIdx.x;
    int j = threadIdx.x;
    float inv = 1.f / fmaxf(pcnt[g], 1.f);
    float acc = bp1[j];
    for (int k = 0; k < 256; ++k)
        acc += (psum[g * 256 + k] * inv) * Wp1[k * 256 + j];
    for (int k = 0; k < 256; ++k)
        acc += fdec(pmax[g * 256 + k]) * Wp1[(256 + k) * 256 + j];
    float v = fmaxf(acc, 0.f) * Wp2[j];
    __shared__ float red[256];
    red[j] = v;
    __syncthreads();
    for (int off = 128; off > 0; off >>= 1) {
        if (j < off) red[j] += red[j + off];
        __syncthreads();
    }
    if (j == 0) out[g] = red[0] + bp2[0];
}

// ---------------------------------------------------------------------------
// launch
// ---------------------------------------------------------------------------
extern "C" void kernel_launch(void* const* d_in, const int* in_sizes, int n_in,
                              void* d_out, int out_size, void* d_ws, size_t ws_size,
                              hipStream_t stream) {
    const float* x   = (const float*)d_in[0];
    const int*   ei  = (const int*)d_in[1];
    const float* ea  = (const float*)d_in[2];
    const int*   bat = (const int*)d_in[3];
    auto LP = [&](int l, int j) { return (const float*)d_in[4 + l * 10 + j]; };
    const float* Wskip = (const float*)d_in[34];
    const float* bskip = (const float*)d_in[35];
    const float* Wp1   = (const float*)d_in[36];
    const float* bp1   = (const float*)d_in[37];
    const float* Wp2   = (const float*)d_in[38];
    const float* bp2   = (const float*)d_in[39];
    float* out = (float*)d_out;

    // workspace carve-up (256B aligned)
    char* p = (char*)d_ws;
    auto alloc = [&](size_t bytes) { void* r = (void*)p; p += (bytes + 255) & ~(size_t)255; return r; };
    uint32*   hbuf2  = (uint32*)alloc((size_t)Nn * 256 * 2);   // bf16 features [n][128] packed
    uint32*   skipbf = (uint32*)alloc((size_t)Nn * 128 * 4);   // bf16 skip residual
    uint32*   resA   = (uint32*)alloc((size_t)Nn * 128 * 4);   // bf16 residual streams
    uint32*   resB   = (uint32*)alloc((size_t)Nn * 128 * 4);
    ushort16* xbf    = (ushort16*)alloc((size_t)Nn * 128 * 2); // bf16 x [n][128]
    float*    wbuf   = (float*)alloc((size_t)Etot * 4 * 4);    // CSR softmax weights
    float*    ea_sorted = (float*)alloc((size_t)Etot * 2 * 4);
    float*    ssrc   = (float*)alloc((size_t)Nn * 4 * 4);      // 4 partial slots
    float*    sdst   = (float*)alloc((size_t)Nn * 4 * 4);
    int*      counts = (int*)alloc((size_t)Nn * 4);
    int*      incb   = (int*)alloc((size_t)Nn * 4);
    int*      row_start = (int*)alloc((size_t)(Nn + 1) * 4);
    int*      cursor    = (int*)alloc((size_t)(Nn + 1) * 4);
    int*      src_sorted = (int*)alloc((size_t)Etot * 4);
    int*      bsums  = (int*)alloc(256 * 4);
    float*    ea_s   = (float*)alloc(2 * 4);
    float*    Mbuf   = (float*)alloc(32 * 4);
    ushort16* WtC    = (ushort16*)alloc((size_t)512 * 128 * 2); // W0 | Wskip swizzled
    ushort16* Wt1    = (ushort16*)alloc((size_t)256 * 256 * 2);
    ushort16* Wt2    = (ushort16*)alloc((size_t)256 * 256 * 2);
    float*    psum   = (float*)alloc((size_t)Gg * 256 * 4);    // psum|pmax|pcnt contiguous
    uint32*   pmax   = (uint32*)alloc((size_t)Gg * 256 * 4);
    float*    pcnt   = (float*)alloc((size_t)Gg * 4);

    const int nb = (Nn + 255) / 256;
    const int wgrid = (Nn * 64 + 255) / 256;

    // zero init
    hipMemsetAsync(counts, 0, (size_t)Nn * 4, stream);
    hipMemsetAsync(ea_s, 0, 8, stream);
    hipMemsetAsync(psum, 0, (size_t)Gg * 256 * 4 * 2 + (size_t)Gg * 4, stream);

    // one prep dispatch: ea_sum + M + W swizzles + x->bf16 + histogram
    prep_kernel<<<1025 + CVT_BLKS + EBKS, 256, 0, stream>>>(
        ea, ea_s, LP(0,3), LP(0,4), LP(1,3), LP(1,4), LP(2,3), LP(2,4), Mbuf,
        LP(0,0), Wskip, LP(1,0), LP(2,0), WtC, Wt1, Wt2, x, xbf, ei, counts);

    // CSR
    scan1_kernel<<<nb, 256, 0, stream>>>(counts, incb, bsums);
    scan23_kernel<<<nb, 256, 0, stream>>>(incb, bsums, row_start, cursor, nb);
    scatter_kernel<<<EBKS, 256, 0, stream>>>(ei, ea, ea_s, cursor, src_sorted, ea_sorted);

    // fused layer-0 GEMM + skip projection + attn dots
    {
        dim3 g0((Nn + 127) / 128, 4);
        mfma_gemm_kernel<<<g0, 256, 0, stream>>>(
            xbf, WtC, hbuf2, skipbf, bskip,
            LP(0,1), LP(0,2), ssrc, sdst, Nn, 128);
    }

    // layers
    const uint32* lid[3] = { skipbf, resA, resB };
    uint32*       lou[3] = { resA, resB, resA };
    const int     Hh[3]  = { 4, 4, 1 };
    const ushort16* lain[3] = { nullptr, (ushort16*)resA, (ushort16*)resB };
    const ushort16* lwt[3]  = { nullptr, Wt1, Wt2 };
    for (int l = 0; l < 3; ++l) {
        const int H = Hh[l];
        if (l > 0) {
            dim3 gl((Nn + 127) / 128, 2);
            mfma_gemm_kernel<<<gl, 256, 0, stream>>>(
                lain[l], lwt[l], hbuf2, nullptr, nullptr,
                LP(l,1), LP(l,2), ssrc, sdst, Nn, 256);
        }
        if (H == 4)
            edge_softmax_kernel<4><<<wgrid, 256, 0, stream>>>(
                src_sorted, row_start, ea_sorted, ssrc, sdst, Mbuf + l * 8, wbuf);
        else
            edge_softmax_kernel<1><<<wgrid, 256, 0, stream>>>(
                src_sorted, row_start, ea_sorted, ssrc, sdst, Mbuf + l * 8, wbuf);
        agg_kernel<<<Nn, 128, 0, stream>>>(src_sorted, row_start, hbuf2, wbuf,
            LP(l,5), LP(l,6), LP(l,7), LP(l,8), LP(l,9), lid[l], lou[l], H);
    }

    // pooling + head (final x = resA, bf16-packed)
    pool_kernel<<<(Nn + POOL_ROWS - 1) / POOL_ROWS, 128, 0, stream>>>(resA, bat, psum, pmax, pcnt);
    mlp_kernel<<<Gg, 256, 0, stream>>>(psum, pmax, pcnt, Wp1, bp1, Wp2, bp2, out);
}